// Round 6
// baseline (3620.683 us; speedup 1.0000x reference)
//
#include <hip/hip_runtime.h>
#include <math.h>

#define NN 50000
#define EE 800000

typedef float f32x4  __attribute__((ext_vector_type(4)));
typedef float f32x8  __attribute__((ext_vector_type(8)));
typedef float f32x16 __attribute__((ext_vector_type(16)));
typedef float f32x32 __attribute__((ext_vector_type(32)));
typedef float f32x64 __attribute__((ext_vector_type(64)));

__device__ __forceinline__ float silu_f(float x) {
    return x / (1.f + __expf(-x));
}

// ---------------- node embedding: h_s = embed_w[sp]/sqrt(5), h_v = 0 ----------------
__global__ void k_embed(const int* __restrict__ species, const float* __restrict__ embed_w,
                        float* __restrict__ h_s, float* __restrict__ h_v) {
    int n = blockIdx.x * 256 + threadIdx.x;
    if (n >= NN) return;
    int sp = species[n];
    const float rs5 = 0.4472135954999579f; // 1/sqrt(5)
#pragma unroll
    for (int u = 0; u < 32; ++u) h_s[n * 32 + u] = embed_w[sp * 32 + u] * rs5;
#pragma unroll
    for (int t = 0; t < 96; ++t) h_v[n * 96 + t] = 0.f;
}

// ---------------- weight transposes ----------------
__global__ void k_wtrans(const float* __restrict__ mlp_w0, const float* __restrict__ mlp_w2,
                         float* __restrict__ w0T, float* __restrict__ w2T) {
    int idx = blockIdx.x * 256 + threadIdx.x;
    if (idx < 1024) {
        int l = idx >> 9, rem = idx & 511, h = rem >> 3, k = rem & 7;
        w0T[idx] = mlp_w0[l * 512 + k * 64 + h];
    }
    if (idx < 16384) {
        int l = idx >> 13, rem = idx & 8191, m = rem >> 6, j = rem & 63;
        w2T[idx] = mlp_w2[l * 8192 + j * 128 + m];
    }
}

// ---------------- CSR build ----------------
__global__ void k_hist(const int* __restrict__ recv, int* __restrict__ deg) {
    int e = blockIdx.x * 256 + threadIdx.x;
    if (e < EE) atomicAdd(&deg[recv[e]], 1);
}

__global__ void k_scan(const int* __restrict__ deg, int* __restrict__ row_start,
                       int* __restrict__ cursor) {
    __shared__ int part[256];
    int t = threadIdx.x;
    int lo = t * 196, hi = lo + 196 > NN ? NN : lo + 196;
    int s = 0;
    for (int i = lo; i < hi; ++i) s += deg[i];
    part[t] = s;
    __syncthreads();
    int acc = 0;
    for (int i = 0; i < t; ++i) acc += part[i];
    int run = acc;
    for (int i = lo; i < hi; ++i) {
        row_start[i] = run;
        cursor[i] = run;
        run += deg[i];
    }
    if (t == 255) row_start[NN] = run;
}

__global__ void k_fill(const int* __restrict__ recv, int* __restrict__ cursor,
                       int* __restrict__ csr_edge) {
    int e = blockIdx.x * 256 + threadIdx.x;
    if (e >= EE) return;
    int p = atomicAdd(&cursor[recv[e]], 1);
    csr_edge[p] = e;
}

// ---------------- one-time gather into CSR order ----------------
__global__ void k_gather(const int* __restrict__ csr_edge, const int* __restrict__ senders,
                         const int* __restrict__ receivers, const float* __restrict__ evec,
                         int* __restrict__ csr_send, int* __restrict__ csr_recv,
                         float* __restrict__ ev3) {
    int p = blockIdx.x * 256 + threadIdx.x;
    if (p >= EE) return;
    int e = csr_edge[p];
    csr_send[p] = senders[e];
    csr_recv[p] = receivers[e];
    ev3[p * 3 + 0] = evec[e * 3 + 0];
    ev3[p * 3 + 1] = evec[e * 3 + 1];
    ev3[p * 3 + 2] = evec[e * 3 + 2];
}

// ---------------- per-layer self-interaction linear -> interleaved feat ----------------
// feat[n][c][0..3]=hs[4c..4c+3], [4..7]=hv_x, [8..11]=hv_y, [12..15]=hv_z  (c=0..7)
__global__ __launch_bounds__(256, 2) void k_node_prep2(
        const float* __restrict__ h_s, const float* __restrict__ h_v,
        const float* __restrict__ w_lin1_s, const float* __restrict__ w_lin1_v,
        float* __restrict__ feat) {
    int n = blockIdx.x * 256 + threadIdx.x;
    if (n >= NN) return;
    const float rs32 = 0.17677669529663687f; // 1/sqrt(32)
    float* fb = feat + (size_t)n * 128;
    f32x32 S = (f32x32)0.f, X = (f32x32)0.f, Y = (f32x32)0.f, Z = (f32x32)0.f;
    for (int u = 0; u < 32; ++u) {
        float xs = h_s[n * 32 + u];
        float xx = h_v[n * 96 + u];
        float xy = h_v[n * 96 + 32 + u];
        float xz = h_v[n * 96 + 64 + u];
        const float* Ws = w_lin1_s + u * 32;
        const float* Wv = w_lin1_v + u * 32;
#pragma unroll
        for (int v = 0; v < 32; ++v) {
            float ws = Ws[v], wv = Wv[v];
            S[v] += xs * ws;
            X[v] += xx * wv;
            Y[v] += xy * wv;
            Z[v] += xz * wv;
        }
    }
#pragma unroll
    for (int c = 0; c < 8; ++c)
#pragma unroll
        for (int q = 0; q < 4; ++q) {
            fb[c * 16 + q]      = S[c * 4 + q] * rs32;
            fb[c * 16 + 4 + q]  = X[c * 4 + q] * rs32;
            fb[c * 16 + 8 + q]  = Y[c * 4 + q] * rs32;
            fb[c * 16 + 12 + q] = Z[c * 4 + q] * rs32;
        }
}

// ---------------- fused edge kernel: 1 thread/edge, wave-uniform weights ----------------
#define WROWS 32
#define WSTRIDE 257
__global__ __launch_bounds__(256, 2) void k_fused2(
    const int* __restrict__ csr_send, const int* __restrict__ csr_recv,
    const float* __restrict__ ev3, const int* __restrict__ row_start,
    const float* __restrict__ feat,
    const float* __restrict__ w0T, const float* __restrict__ w1,
    const float* __restrict__ w2T,
    float* __restrict__ n0, float* __restrict__ n1) {
    __shared__ float acc[WROWS * WSTRIDE];
    __shared__ int sh_base, sh_last;
    int tid = threadIdx.x;
    int p0 = blockIdx.x * 256;
    int pos = p0 + tid;                 // EE == 3125*256, always valid

    for (int i = tid; i < WROWS * WSTRIDE; i += 256) acc[i] = 0.f;

    int s = csr_send[pos];
    int rv = csr_recv[pos];
    if (tid == 0)   sh_base = rv;
    if (tid == 255) sh_last = rv;
    __syncthreads();
    int node_base = sh_base;

    // ---- geometry ----
    float x = ev3[pos * 3 + 0], y = ev3[pos * 3 + 1], z = ev3[pos * 3 + 2];
    float r = sqrtf(x * x + y * y + z * z + 1e-12f);
    float ir = 1.f / r;
    const float s3 = 1.7320508075688772f;
    float shx = s3 * x * ir, shy = s3 * y * ir, shz = s3 * z * ir;
    float xx = r * 0.2f;
    float env = 0.f;
    if (xx < 1.f) {
        float x2 = xx * xx, x3 = x2 * xx, x6 = x3 * x3, x7 = x6 * xx, x8 = x7 * xx;
        env = 1.f - 28.f * x6 + 48.f * x7 - 21.f * x8;
    }
    float coef = 0.6324555320336759f * env * ir; // sqrt(2/5) * env / r
    const float w5 = 0.6283185307179586f;        // pi/5
    f32x8 eeR;
#pragma unroll
    for (int k = 0; k < 8; ++k) eeR[k] = coef * __sinf(w5 * (float)(k + 1) * r);

    // ---- radial MLP; a2 is a single SSA vector -> guaranteed VGPRs ----
    f32x64 a2 = (f32x64)0.f;
    const float rs8 = 0.35355339059327373f; // 1/sqrt(8)
    for (int j = 0; j < 64; ++j) {
        const float* w0r = w0T + j * 8;
        float p = 0.f;
#pragma unroll
        for (int k = 0; k < 8; ++k) p += eeR[k] * w0r[k];
        float a1j = silu_f(p * rs8);
        const float* w1r = w1 + j * 64;
#pragma unroll
        for (int h = 0; h < 64; ++h) a2[h] += a1j * w1r[h];
    }
#pragma unroll
    for (int h = 0; h < 64; ++h) a2[h] = silu_f(a2[h] * 0.125f);

    // ---- TP + scatter, u in chunks of 4; features: one 64B block per chunk ----
    int w = rv - node_base;
    bool inwin = (w < WROWS);
    float* arow = acc + w * WSTRIDE;
    const float rs3 = 0.5773502691896258f; // 1/sqrt(3)
    float* n0r = n0 + rv * 64;
    float* n1r = n1 + rv * 192;
    const float* fb = feat + (size_t)s * 128;

    for (int c = 0; c < 8; ++c) {
        f32x4 fS = *(const f32x4*)(fb + c * 16);
        f32x4 fX = *(const f32x4*)(fb + c * 16 + 4);
        f32x4 fY = *(const f32x4*)(fb + c * 16 + 8);
        f32x4 fZ = *(const f32x4*)(fb + c * 16 + 12);
#pragma unroll
        for (int uu = 0; uu < 4; ++uu) {
            int u = c * 4 + uu;
            const float* c1 = w2T + u * 64;
            const float* c2 = w2T + (32 + u) * 64;
            const float* c3 = w2T + (64 + u) * 64;
            const float* c4 = w2T + (96 + u) * 64;
            float d1 = 0.f, d2 = 0.f, d3 = 0.f, d4 = 0.f;
#pragma unroll
            for (int j = 0; j < 64; ++j) {
                float aj = a2[j];
                d1 += aj * c1[j];
                d2 += aj * c2[j];
                d3 += aj * c3[j];
                d4 += aj * c4[j];
            }
            float es = fS[uu];
            float ev0 = fX[uu], ev1 = fY[uu], ev2 = fZ[uu];
            float dot = ev0 * shx + ev1 * shy + ev2 * shz;
            float o0a = d1 * es;
            float o0b = d2 * dot * rs3;
            float t3 = d3 * es;
            float v2 = t3 * shx, v3 = d4 * ev0;
            float v4 = t3 * shy, v5 = d4 * ev1;
            float v6 = t3 * shz, v7 = d4 * ev2;
            if (inwin) {
                atomicAdd(arow + u, o0a);
                atomicAdd(arow + 32 + u, o0b);
                atomicAdd(arow + 64 + u, v2);
                atomicAdd(arow + 96 + u, v3);
                atomicAdd(arow + 128 + u, v4);
                atomicAdd(arow + 160 + u, v5);
                atomicAdd(arow + 192 + u, v6);
                atomicAdd(arow + 224 + u, v7);
            } else { // rare window overflow
                atomicAdd(n0r + u, o0a);
                atomicAdd(n0r + 32 + u, o0b);
                atomicAdd(n1r + u, v2);
                atomicAdd(n1r + 32 + u, v3);
                atomicAdd(n1r + 64 + u, v4);
                atomicAdd(n1r + 96 + u, v5);
                atomicAdd(n1r + 128 + u, v6);
                atomicAdd(n1r + 160 + u, v7);
            }
        }
    }
    __syncthreads();

    // flush window: plain store for block-owned nodes, atomicAdd for boundary
    int span = sh_last - node_base;
    if (span > WROWS - 1) span = WROWS - 1;
    for (int wl = 0; wl <= span; ++wl) {
        int n = node_base + wl;
        float v = acc[wl * WSTRIDE + tid];
        bool interior = (row_start[n] >= p0) && (row_start[n + 1] <= p0 + 256);
        float* dest = (tid < 64) ? (n0 + n * 64 + tid) : (n1 + n * 192 + (tid - 64));
        if (interior) *dest = v;
        else if (v != 0.f) atomicAdd(dest, v);
    }
}

// ---------------- node update: lin2 + residual + gated nonlinearity ----------------
__global__ __launch_bounds__(256, 2) void k_node_update(
        const int* __restrict__ species,
        const float* __restrict__ n0, const float* __restrict__ n1,
        const float* __restrict__ w_lin2_s, const float* __restrict__ w_lin2_v,
        const float* __restrict__ w_res_s, const float* __restrict__ w_res_v,
        float* __restrict__ h_s, float* __restrict__ h_v) {
    int n = blockIdx.x * 256 + threadIdx.x;
    if (n >= NN) return;
    int sp = species[n];
    const float sc_l2 = 1.f / 128.f;              // (1/16 neigh) * (1/sqrt(64) lin2)
    const float rs160 = 0.07905694150420949f;     // 1/sqrt(160)

    f32x64 sout = (f32x64)0.f;
    const float* n0r = n0 + n * 64;
    for (int j = 0; j < 64; ++j) {
        float xv = n0r[j] * sc_l2;
        const float* Wr = w_lin2_s + j * 64;
#pragma unroll
        for (int k = 0; k < 64; ++k) sout[k] += xv * Wr[k];
    }
    const float* hsr = h_s + n * 32;
    for (int u = 0; u < 32; ++u) {
        float xv = hsr[u] * rs160;
        const float* Wr = w_res_s + (u * 5 + sp) * 64;
#pragma unroll
        for (int k = 0; k < 64; ++k) sout[k] += xv * Wr[k];
    }
    f32x32 g, hsnew;
#pragma unroll
    for (int v = 0; v < 32; ++v) g[v] = silu_f(sout[32 + v]);
#pragma unroll
    for (int v = 0; v < 32; ++v) hsnew[v] = silu_f(sout[v]);

    for (int i = 0; i < 3; ++i) {
        f32x32 vacc = (f32x32)0.f;
        const float* n1r = n1 + n * 192 + i * 64;
        for (int u = 0; u < 64; ++u) {
            float xv = n1r[u] * sc_l2;
            const float* Wr = w_lin2_v + u * 32;
#pragma unroll
            for (int v = 0; v < 32; ++v) vacc[v] += xv * Wr[v];
        }
        const float* hvr = h_v + n * 96 + i * 32;
        for (int u = 0; u < 32; ++u) {
            float xv = hvr[u] * rs160;
            const float* Wr = w_res_v + (u * 5 + sp) * 32;
#pragma unroll
            for (int v = 0; v < 32; ++v) vacc[v] += xv * Wr[v];
        }
        float* outp = h_v + n * 96 + i * 32;
#pragma unroll
        for (int v = 0; v < 32; ++v) outp[v] = vacc[v] * g[v];
    }
#pragma unroll
    for (int v = 0; v < 32; ++v) h_s[n * 32 + v] = hsnew[v];
}

// ---------------- readout ----------------
__global__ void k_readout(const float* __restrict__ h_s, const float* __restrict__ w_out1,
                          const float* __restrict__ w_out2, float* __restrict__ out) {
    int n = blockIdx.x * 256 + threadIdx.x;
    if (n >= NN) return;
    f32x16 zacc = (f32x16)0.f;
    const float* hsr = h_s + n * 32;
    for (int u = 0; u < 32; ++u) {
        float xv = hsr[u];
        const float* Wr = w_out1 + u * 16;
#pragma unroll
        for (int j = 0; j < 16; ++j) zacc[j] += xv * Wr[j];
    }
    float ev = 0.f;
#pragma unroll
    for (int j = 0; j < 16; ++j) ev += zacc[j] * w_out2[j];
    out[n] = ev * 0.17677669529663687f * 0.25f; // 1/sqrt(32) * 1/sqrt(16)
}

extern "C" void kernel_launch(void* const* d_in, const int* in_sizes, int n_in,
                              void* d_out, int out_size, void* d_ws, size_t ws_size,
                              hipStream_t stream) {
    const float* evec     = (const float*)d_in[0];
    const int*   species  = (const int*)d_in[1];
    const int*   senders  = (const int*)d_in[2];
    const int*   receivers= (const int*)d_in[3];
    const float* embed_w  = (const float*)d_in[4];
    const float* w_res_s  = (const float*)d_in[5];
    const float* w_res_v  = (const float*)d_in[6];
    const float* w_lin1_s = (const float*)d_in[7];
    const float* w_lin1_v = (const float*)d_in[8];
    const float* mlp_w0   = (const float*)d_in[9];
    const float* mlp_w1   = (const float*)d_in[10];
    const float* mlp_w2   = (const float*)d_in[11];
    const float* w_lin2_s = (const float*)d_in[12];
    const float* w_lin2_v = (const float*)d_in[13];
    const float* w_out1   = (const float*)d_in[14];
    const float* w_out2   = (const float*)d_in[15];

    float* ws = (float*)d_ws;
    size_t off = 0;
    auto alloc = [&](size_t n) { float* p = ws + off; off += (n + 3) & ~(size_t)3; return p; };

    float* h_s  = alloc(NN * 32);
    float* h_v  = alloc(NN * 96);
    float* feat = alloc((size_t)NN * 128);
    float* n0b  = alloc(NN * 64);
    float* n1b  = alloc(NN * 192);
    float* w0T  = alloc(1024);
    float* w2T  = alloc(16384);
    int*   deg       = (int*)alloc(NN);
    int*   row_start = (int*)alloc(NN + 1);
    int*   cursor    = (int*)alloc(NN);
    int*   csr_edge  = (int*)alloc(EE);
    int*   csr_send  = (int*)alloc(EE);
    int*   csr_recv  = (int*)alloc(EE);
    float* ev3       = alloc((size_t)EE * 3);
    // total ~30.6M floats ~= 122 MB

    k_embed<<<(NN + 255) / 256, 256, 0, stream>>>(species, embed_w, h_s, h_v);
    k_wtrans<<<64, 256, 0, stream>>>(mlp_w0, mlp_w2, w0T, w2T);

    hipMemsetAsync(deg, 0, NN * 4, stream);
    k_hist<<<(EE + 255) / 256, 256, 0, stream>>>(receivers, deg);
    k_scan<<<1, 256, 0, stream>>>(deg, row_start, cursor);
    k_fill<<<(EE + 255) / 256, 256, 0, stream>>>(receivers, cursor, csr_edge);
    k_gather<<<(EE + 255) / 256, 256, 0, stream>>>(csr_edge, senders, receivers, evec,
                                                   csr_send, csr_recv, ev3);

    for (int l = 0; l < 2; ++l) {
        k_node_prep2<<<(NN + 255) / 256, 256, 0, stream>>>(
            h_s, h_v, w_lin1_s + l * 1024, w_lin1_v + l * 1024, feat);
        hipMemsetAsync(n0b, 0, (size_t)NN * 64 * 4, stream);
        hipMemsetAsync(n1b, 0, (size_t)NN * 192 * 4, stream);
        k_fused2<<<EE / 256, 256, 0, stream>>>(
            csr_send, csr_recv, ev3, row_start, feat,
            w0T + l * 512, mlp_w1 + l * 4096, w2T + l * 8192, n0b, n1b);
        k_node_update<<<(NN + 255) / 256, 256, 0, stream>>>(
            species, n0b, n1b,
            w_lin2_s + l * 4096, w_lin2_v + l * 2048,
            w_res_s + l * 10240, w_res_v + l * 5120, h_s, h_v);
    }
    k_readout<<<(NN + 255) / 256, 256, 0, stream>>>(h_s, w_out1, w_out2, (float*)d_out);
}

// Round 7
// 3569.410 us; speedup vs baseline: 1.0144x; 1.0144x over previous
//
#include <hip/hip_runtime.h>
#include <math.h>

#define NN 50000
#define EE 800000

typedef float f32x4  __attribute__((ext_vector_type(4)));
typedef float f32x8  __attribute__((ext_vector_type(8)));
typedef float f32x16 __attribute__((ext_vector_type(16)));

__device__ __forceinline__ float silu_f(float x) {
    return x / (1.f + __expf(-x));
}

// ---------------- node embedding: h_s = embed_w[sp]/sqrt(5), h_v = 0 ----------------
__global__ void k_embed(const int* __restrict__ species, const float* __restrict__ embed_w,
                        float* __restrict__ h_s, float* __restrict__ h_v) {
    int n = blockIdx.x * 256 + threadIdx.x;
    if (n >= NN) return;
    int sp = species[n];
    const float rs5 = 0.4472135954999579f; // 1/sqrt(5)
#pragma unroll
    for (int u = 0; u < 32; ++u) h_s[n * 32 + u] = embed_w[sp * 32 + u] * rs5;
#pragma unroll
    for (int t = 0; t < 96; ++t) h_v[n * 96 + t] = 0.f;
}

// ---------------- weight transposes ----------------
__global__ void k_wtrans(const float* __restrict__ mlp_w0, const float* __restrict__ mlp_w2,
                         float* __restrict__ w0T, float* __restrict__ w2T) {
    int idx = blockIdx.x * 256 + threadIdx.x;
    if (idx < 1024) {
        int l = idx >> 9, rem = idx & 511, h = rem >> 3, k = rem & 7;
        w0T[idx] = mlp_w0[l * 512 + k * 64 + h];
    }
    if (idx < 16384) {
        int l = idx >> 13, rem = idx & 8191, m = rem >> 6, j = rem & 63;
        w2T[idx] = mlp_w2[l * 8192 + j * 128 + m];
    }
}

// ---------------- CSR build ----------------
__global__ void k_hist(const int* __restrict__ recv, int* __restrict__ deg) {
    int e = blockIdx.x * 256 + threadIdx.x;
    if (e < EE) atomicAdd(&deg[recv[e]], 1);
}

__global__ void k_scan(const int* __restrict__ deg, int* __restrict__ row_start,
                       int* __restrict__ cursor) {
    __shared__ int part[256];
    int t = threadIdx.x;
    int lo = t * 196, hi = lo + 196 > NN ? NN : lo + 196;
    int s = 0;
    for (int i = lo; i < hi; ++i) s += deg[i];
    part[t] = s;
    __syncthreads();
    int acc = 0;
    for (int i = 0; i < t; ++i) acc += part[i];
    int run = acc;
    for (int i = lo; i < hi; ++i) {
        row_start[i] = run;
        cursor[i] = run;
        run += deg[i];
    }
    if (t == 255) row_start[NN] = run;
}

__global__ void k_fill(const int* __restrict__ recv, int* __restrict__ cursor,
                       int* __restrict__ csr_edge) {
    int e = blockIdx.x * 256 + threadIdx.x;
    if (e >= EE) return;
    int p = atomicAdd(&cursor[recv[e]], 1);
    csr_edge[p] = e;
}

// ---------------- one-time gather into CSR order ----------------
__global__ void k_gather(const int* __restrict__ csr_edge, const int* __restrict__ senders,
                         const int* __restrict__ receivers, const float* __restrict__ evec,
                         int* __restrict__ csr_send, int* __restrict__ csr_recv,
                         float* __restrict__ ev3) {
    int p = blockIdx.x * 256 + threadIdx.x;
    if (p >= EE) return;
    int e = csr_edge[p];
    csr_send[p] = senders[e];
    csr_recv[p] = receivers[e];
    ev3[p * 3 + 0] = evec[e * 3 + 0];
    ev3[p * 3 + 1] = evec[e * 3 + 1];
    ev3[p * 3 + 2] = evec[e * 3 + 2];
}

// ---------------- per-layer self-interaction linear -> interleaved feat ----------------
// feat[n][c][0..3]=hs[4c..4c+3], [4..7]=hv_x, [8..11]=hv_y, [12..15]=hv_z  (c=0..7)
__global__ __attribute__((amdgpu_waves_per_eu(2, 3))) __launch_bounds__(256)
void k_node_prep2(const float* __restrict__ h_s, const float* __restrict__ h_v,
                  const float* __restrict__ w_lin1_s, const float* __restrict__ w_lin1_v,
                  float* __restrict__ feat) {
    int n = blockIdx.x * 256 + threadIdx.x;
    if (n >= NN) return;
    const float rs32 = 0.17677669529663687f; // 1/sqrt(32)
    float* fb = feat + (size_t)n * 128;
    { // half 1: scalars S and vector-x X
        f32x16 Sa = (f32x16)0.f, Sb = (f32x16)0.f, Xa = (f32x16)0.f, Xb = (f32x16)0.f;
        for (int u = 0; u < 32; ++u) {
            float xs = h_s[n * 32 + u];
            float xx = h_v[n * 96 + u];
            const float* Ws = w_lin1_s + u * 32;
            const float* Wv = w_lin1_v + u * 32;
#pragma unroll
            for (int v = 0; v < 16; ++v) {
                Sa[v] += xs * Ws[v];
                Sb[v] += xs * Ws[16 + v];
                Xa[v] += xx * Wv[v];
                Xb[v] += xx * Wv[16 + v];
            }
        }
#pragma unroll
        for (int c = 0; c < 8; ++c)
#pragma unroll
            for (int q = 0; q < 4; ++q) {
                int idx = c * 4 + q;
                float sv = (idx < 16) ? Sa[idx & 15] : Sb[idx & 15];
                float xv = (idx < 16) ? Xa[idx & 15] : Xb[idx & 15];
                fb[c * 16 + q]     = sv * rs32;
                fb[c * 16 + 4 + q] = xv * rs32;
            }
    }
    { // half 2: vector-y Y and vector-z Z
        f32x16 Ya = (f32x16)0.f, Yb = (f32x16)0.f, Za = (f32x16)0.f, Zb = (f32x16)0.f;
        for (int u = 0; u < 32; ++u) {
            float xy = h_v[n * 96 + 32 + u];
            float xz = h_v[n * 96 + 64 + u];
            const float* Wv = w_lin1_v + u * 32;
#pragma unroll
            for (int v = 0; v < 16; ++v) {
                Ya[v] += xy * Wv[v];
                Yb[v] += xy * Wv[16 + v];
                Za[v] += xz * Wv[v];
                Zb[v] += xz * Wv[16 + v];
            }
        }
#pragma unroll
        for (int c = 0; c < 8; ++c)
#pragma unroll
            for (int q = 0; q < 4; ++q) {
                int idx = c * 4 + q;
                float yv = (idx < 16) ? Ya[idx & 15] : Yb[idx & 15];
                float zv = (idx < 16) ? Za[idx & 15] : Zb[idx & 15];
                fb[c * 16 + 8 + q]  = yv * rs32;
                fb[c * 16 + 12 + q] = zv * rs32;
            }
    }
}

// ---------------- fused edge kernel: 1 thread/edge, wave-uniform weights ----------------
#define WROWS 32
#define WSTRIDE 257
__global__ __attribute__((amdgpu_waves_per_eu(2, 3))) __launch_bounds__(256)
void k_fused2(
    const int* __restrict__ csr_send, const int* __restrict__ csr_recv,
    const float* __restrict__ ev3, const int* __restrict__ row_start,
    const float* __restrict__ feat,
    const float* __restrict__ w0T, const float* __restrict__ w1,
    const float* __restrict__ w2T,
    float* __restrict__ n0, float* __restrict__ n1) {
    __shared__ float acc[WROWS * WSTRIDE];
    __shared__ int sh_base, sh_last;
    int tid = threadIdx.x;
    int p0 = blockIdx.x * 256;
    int pos = p0 + tid;                 // EE == 3125*256, always valid

    for (int i = tid; i < WROWS * WSTRIDE; i += 256) acc[i] = 0.f;

    int s = csr_send[pos];
    int rv = csr_recv[pos];
    if (tid == 0)   sh_base = rv;
    if (tid == 255) sh_last = rv;
    __syncthreads();
    int node_base = sh_base;

    // ---- geometry ----
    float x = ev3[pos * 3 + 0], y = ev3[pos * 3 + 1], z = ev3[pos * 3 + 2];
    float r = sqrtf(x * x + y * y + z * z + 1e-12f);
    float ir = 1.f / r;
    const float s3 = 1.7320508075688772f;
    float shx = s3 * x * ir, shy = s3 * y * ir, shz = s3 * z * ir;
    float xx = r * 0.2f;
    float env = 0.f;
    if (xx < 1.f) {
        float x2 = xx * xx, x3 = x2 * xx, x6 = x3 * x3, x7 = x6 * xx, x8 = x7 * xx;
        env = 1.f - 28.f * x6 + 48.f * x7 - 21.f * x8;
    }
    float coef = 0.6324555320336759f * env * ir; // sqrt(2/5) * env / r
    const float w5 = 0.6283185307179586f;        // pi/5
    f32x8 eeR;
#pragma unroll
    for (int k = 0; k < 8; ++k) eeR[k] = coef * __sinf(w5 * (float)(k + 1) * r);

    // ---- radial MLP; a2 held as 4 named f32x16 (literal indices only) ----
    f32x16 a2a = (f32x16)0.f, a2b = (f32x16)0.f, a2c = (f32x16)0.f, a2d = (f32x16)0.f;
    const float rs8 = 0.35355339059327373f; // 1/sqrt(8)
#pragma unroll 2
    for (int j = 0; j < 64; ++j) {
        const float* w0r = w0T + j * 8;
        float p = 0.f;
#pragma unroll
        for (int k = 0; k < 8; ++k) p += eeR[k] * w0r[k];
        float a1j = silu_f(p * rs8);
        const float* w1r = w1 + j * 64;
#pragma unroll
        for (int h = 0; h < 16; ++h) {
            a2a[h] += a1j * w1r[h];
            a2b[h] += a1j * w1r[16 + h];
            a2c[h] += a1j * w1r[32 + h];
            a2d[h] += a1j * w1r[48 + h];
        }
    }
#pragma unroll
    for (int h = 0; h < 16; ++h) {
        a2a[h] = silu_f(a2a[h] * 0.125f);
        a2b[h] = silu_f(a2b[h] * 0.125f);
        a2c[h] = silu_f(a2c[h] * 0.125f);
        a2d[h] = silu_f(a2d[h] * 0.125f);
    }

    // ---- TP + scatter, u in chunks of 4; features: one 64B block per chunk ----
    int w = rv - node_base;
    bool inwin = (w < WROWS);
    float* arow = acc + w * WSTRIDE;
    const float rs3 = 0.5773502691896258f; // 1/sqrt(3)
    float* n0r = n0 + rv * 64;
    float* n1r = n1 + rv * 192;
    const float* fb = feat + (size_t)s * 128;

    for (int c = 0; c < 8; ++c) {
        f32x4 fS = *(const f32x4*)(fb + c * 16);
        f32x4 fX = *(const f32x4*)(fb + c * 16 + 4);
        f32x4 fY = *(const f32x4*)(fb + c * 16 + 8);
        f32x4 fZ = *(const f32x4*)(fb + c * 16 + 12);
#pragma unroll
        for (int uu = 0; uu < 4; ++uu) {
            int u = c * 4 + uu;
            const float* c1 = w2T + u * 64;
            const float* c2 = w2T + (32 + u) * 64;
            const float* c3 = w2T + (64 + u) * 64;
            const float* c4 = w2T + (96 + u) * 64;
            float d1 = 0.f, d2 = 0.f, d3 = 0.f, d4 = 0.f;
#pragma unroll
            for (int j = 0; j < 16; ++j) {
                float aj = a2a[j];
                d1 += aj * c1[j]; d2 += aj * c2[j]; d3 += aj * c3[j]; d4 += aj * c4[j];
            }
#pragma unroll
            for (int j = 0; j < 16; ++j) {
                float aj = a2b[j];
                d1 += aj * c1[16 + j]; d2 += aj * c2[16 + j]; d3 += aj * c3[16 + j]; d4 += aj * c4[16 + j];
            }
#pragma unroll
            for (int j = 0; j < 16; ++j) {
                float aj = a2c[j];
                d1 += aj * c1[32 + j]; d2 += aj * c2[32 + j]; d3 += aj * c3[32 + j]; d4 += aj * c4[32 + j];
            }
#pragma unroll
            for (int j = 0; j < 16; ++j) {
                float aj = a2d[j];
                d1 += aj * c1[48 + j]; d2 += aj * c2[48 + j]; d3 += aj * c3[48 + j]; d4 += aj * c4[48 + j];
            }
            float es = fS[uu];
            float ev0 = fX[uu], ev1 = fY[uu], ev2 = fZ[uu];
            float dot = ev0 * shx + ev1 * shy + ev2 * shz;
            float o0a = d1 * es;
            float o0b = d2 * dot * rs3;
            float t3 = d3 * es;
            float v2 = t3 * shx, v3 = d4 * ev0;
            float v4 = t3 * shy, v5 = d4 * ev1;
            float v6 = t3 * shz, v7 = d4 * ev2;
            if (inwin) {
                atomicAdd(arow + u, o0a);
                atomicAdd(arow + 32 + u, o0b);
                atomicAdd(arow + 64 + u, v2);
                atomicAdd(arow + 96 + u, v3);
                atomicAdd(arow + 128 + u, v4);
                atomicAdd(arow + 160 + u, v5);
                atomicAdd(arow + 192 + u, v6);
                atomicAdd(arow + 224 + u, v7);
            } else { // rare window overflow
                atomicAdd(n0r + u, o0a);
                atomicAdd(n0r + 32 + u, o0b);
                atomicAdd(n1r + u, v2);
                atomicAdd(n1r + 32 + u, v3);
                atomicAdd(n1r + 64 + u, v4);
                atomicAdd(n1r + 96 + u, v5);
                atomicAdd(n1r + 128 + u, v6);
                atomicAdd(n1r + 160 + u, v7);
            }
        }
    }
    __syncthreads();

    // flush window: plain store for block-owned nodes, atomicAdd for boundary
    int span = sh_last - node_base;
    if (span > WROWS - 1) span = WROWS - 1;
    for (int wl = 0; wl <= span; ++wl) {
        int n = node_base + wl;
        float v = acc[wl * WSTRIDE + tid];
        bool interior = (row_start[n] >= p0) && (row_start[n + 1] <= p0 + 256);
        float* dest = (tid < 64) ? (n0 + n * 64 + tid) : (n1 + n * 192 + (tid - 64));
        if (interior) *dest = v;
        else if (v != 0.f) atomicAdd(dest, v);
    }
}

// ---------------- node update: lin2 + residual + gated nonlinearity ----------------
__global__ __attribute__((amdgpu_waves_per_eu(2, 3))) __launch_bounds__(256)
void k_node_update(
        const int* __restrict__ species,
        const float* __restrict__ n0, const float* __restrict__ n1,
        const float* __restrict__ w_lin2_s, const float* __restrict__ w_lin2_v,
        const float* __restrict__ w_res_s, const float* __restrict__ w_res_v,
        float* __restrict__ h_s, float* __restrict__ h_v) {
    int n = blockIdx.x * 256 + threadIdx.x;
    if (n >= NN) return;
    int sp = species[n];
    const float sc_l2 = 1.f / 128.f;              // (1/16 neigh) * (1/sqrt(64) lin2)
    const float rs160 = 0.07905694150420949f;     // 1/sqrt(160)

    f32x16 s0 = (f32x16)0.f, s1 = (f32x16)0.f, s2 = (f32x16)0.f, s3 = (f32x16)0.f;
    const float* n0r = n0 + n * 64;
    for (int j = 0; j < 64; ++j) {
        float xv = n0r[j] * sc_l2;
        const float* Wr = w_lin2_s + j * 64;
#pragma unroll
        for (int k = 0; k < 16; ++k) {
            s0[k] += xv * Wr[k];
            s1[k] += xv * Wr[16 + k];
            s2[k] += xv * Wr[32 + k];
            s3[k] += xv * Wr[48 + k];
        }
    }
    const float* hsr = h_s + n * 32;
    for (int u = 0; u < 32; ++u) {
        float xv = hsr[u] * rs160;
        const float* Wr = w_res_s + (u * 5 + sp) * 64;
#pragma unroll
        for (int k = 0; k < 16; ++k) {
            s0[k] += xv * Wr[k];
            s1[k] += xv * Wr[16 + k];
            s2[k] += xv * Wr[32 + k];
            s3[k] += xv * Wr[48 + k];
        }
    }
    f32x16 g0, g1, h0, h1;
#pragma unroll
    for (int k = 0; k < 16; ++k) {
        h0[k] = silu_f(s0[k]);
        h1[k] = silu_f(s1[k]);
        g0[k] = silu_f(s2[k]);
        g1[k] = silu_f(s3[k]);
    }

    for (int i = 0; i < 3; ++i) {
        f32x16 v0 = (f32x16)0.f, v1 = (f32x16)0.f;
        const float* n1r = n1 + n * 192 + i * 64;
        for (int u = 0; u < 64; ++u) {
            float xv = n1r[u] * sc_l2;
            const float* Wr = w_lin2_v + u * 32;
#pragma unroll
            for (int v = 0; v < 16; ++v) {
                v0[v] += xv * Wr[v];
                v1[v] += xv * Wr[16 + v];
            }
        }
        const float* hvr = h_v + n * 96 + i * 32;
        for (int u = 0; u < 32; ++u) {
            float xv = hvr[u] * rs160;
            const float* Wr = w_res_v + (u * 5 + sp) * 32;
#pragma unroll
            for (int v = 0; v < 16; ++v) {
                v0[v] += xv * Wr[v];
                v1[v] += xv * Wr[16 + v];
            }
        }
        float* outp = h_v + n * 96 + i * 32;
#pragma unroll
        for (int v = 0; v < 16; ++v) {
            outp[v]      = v0[v] * g0[v];
            outp[16 + v] = v1[v] * g1[v];
        }
    }
#pragma unroll
    for (int v = 0; v < 16; ++v) {
        h_s[n * 32 + v]      = h0[v];
        h_s[n * 32 + 16 + v] = h1[v];
    }
}

// ---------------- readout ----------------
__global__ void k_readout(const float* __restrict__ h_s, const float* __restrict__ w_out1,
                          const float* __restrict__ w_out2, float* __restrict__ out) {
    int n = blockIdx.x * 256 + threadIdx.x;
    if (n >= NN) return;
    f32x16 zacc = (f32x16)0.f;
    const float* hsr = h_s + n * 32;
    for (int u = 0; u < 32; ++u) {
        float xv = hsr[u];
        const float* Wr = w_out1 + u * 16;
#pragma unroll
        for (int j = 0; j < 16; ++j) zacc[j] += xv * Wr[j];
    }
    float ev = 0.f;
#pragma unroll
    for (int j = 0; j < 16; ++j) ev += zacc[j] * w_out2[j];
    out[n] = ev * 0.17677669529663687f * 0.25f; // 1/sqrt(32) * 1/sqrt(16)
}

extern "C" void kernel_launch(void* const* d_in, const int* in_sizes, int n_in,
                              void* d_out, int out_size, void* d_ws, size_t ws_size,
                              hipStream_t stream) {
    const float* evec     = (const float*)d_in[0];
    const int*   species  = (const int*)d_in[1];
    const int*   senders  = (const int*)d_in[2];
    const int*   receivers= (const int*)d_in[3];
    const float* embed_w  = (const float*)d_in[4];
    const float* w_res_s  = (const float*)d_in[5];
    const float* w_res_v  = (const float*)d_in[6];
    const float* w_lin1_s = (const float*)d_in[7];
    const float* w_lin1_v = (const float*)d_in[8];
    const float* mlp_w0   = (const float*)d_in[9];
    const float* mlp_w1   = (const float*)d_in[10];
    const float* mlp_w2   = (const float*)d_in[11];
    const float* w_lin2_s = (const float*)d_in[12];
    const float* w_lin2_v = (const float*)d_in[13];
    const float* w_out1   = (const float*)d_in[14];
    const float* w_out2   = (const float*)d_in[15];

    float* ws = (float*)d_ws;
    size_t off = 0;
    auto alloc = [&](size_t n) { float* p = ws + off; off += (n + 3) & ~(size_t)3; return p; };

    float* h_s  = alloc(NN * 32);
    float* h_v  = alloc(NN * 96);
    float* feat = alloc((size_t)NN * 128);
    float* n0b  = alloc(NN * 64);
    float* n1b  = alloc(NN * 192);
    float* w0T  = alloc(1024);
    float* w2T  = alloc(16384);
    int*   deg       = (int*)alloc(NN);
    int*   row_start = (int*)alloc(NN + 1);
    int*   cursor    = (int*)alloc(NN);
    int*   csr_edge  = (int*)alloc(EE);
    int*   csr_send  = (int*)alloc(EE);
    int*   csr_recv  = (int*)alloc(EE);
    float* ev3       = alloc((size_t)EE * 3);
    // total ~30.6M floats ~= 122 MB

    k_embed<<<(NN + 255) / 256, 256, 0, stream>>>(species, embed_w, h_s, h_v);
    k_wtrans<<<64, 256, 0, stream>>>(mlp_w0, mlp_w2, w0T, w2T);

    hipMemsetAsync(deg, 0, NN * 4, stream);
    k_hist<<<(EE + 255) / 256, 256, 0, stream>>>(receivers, deg);
    k_scan<<<1, 256, 0, stream>>>(deg, row_start, cursor);
    k_fill<<<(EE + 255) / 256, 256, 0, stream>>>(receivers, cursor, csr_edge);
    k_gather<<<(EE + 255) / 256, 256, 0, stream>>>(csr_edge, senders, receivers, evec,
                                                   csr_send, csr_recv, ev3);

    for (int l = 0; l < 2; ++l) {
        k_node_prep2<<<(NN + 255) / 256, 256, 0, stream>>>(
            h_s, h_v, w_lin1_s + l * 1024, w_lin1_v + l * 1024, feat);
        hipMemsetAsync(n0b, 0, (size_t)NN * 64 * 4, stream);
        hipMemsetAsync(n1b, 0, (size_t)NN * 192 * 4, stream);
        k_fused2<<<EE / 256, 256, 0, stream>>>(
            csr_send, csr_recv, ev3, row_start, feat,
            w0T + l * 512, mlp_w1 + l * 4096, w2T + l * 8192, n0b, n1b);
        k_node_update<<<(NN + 255) / 256, 256, 0, stream>>>(
            species, n0b, n1b,
            w_lin2_s + l * 4096, w_lin2_v + l * 2048,
            w_res_s + l * 10240, w_res_v + l * 5120, h_s, h_v);
    }
    k_readout<<<(NN + 255) / 256, 256, 0, stream>>>(h_s, w_out1, w_out2, (float*)d_out);
}

// Round 8
// 2964.424 us; speedup vs baseline: 1.2214x; 1.2041x over previous
//
#include <hip/hip_runtime.h>
#include <math.h>

#define NN 50000
#define EE 800000

typedef float f32x4  __attribute__((ext_vector_type(4)));
typedef float f32x16 __attribute__((ext_vector_type(16)));
typedef short bf16x8 __attribute__((ext_vector_type(8)));

__device__ __forceinline__ float silu_f(float x) {
    return x / (1.f + __expf(-x));
}
__device__ __forceinline__ unsigned short f2bf(float f) {
    unsigned int u = __float_as_uint(f);
    unsigned int r = (u + 0x7fffu + ((u >> 16) & 1u)) >> 16;
    return (unsigned short)r;
}

// ---------------- node embedding ----------------
__global__ void k_embed(const int* __restrict__ species, const float* __restrict__ embed_w,
                        float* __restrict__ h_s, float* __restrict__ h_v) {
    int n = blockIdx.x * 256 + threadIdx.x;
    if (n >= NN) return;
    int sp = species[n];
    const float rs5 = 0.4472135954999579f;
#pragma unroll
    for (int u = 0; u < 32; ++u) h_s[n * 32 + u] = embed_w[sp * 32 + u] * rs5;
#pragma unroll
    for (int t = 0; t < 96; ++t) h_v[n * 96 + t] = 0.f;
}

// ---------------- weights -> bf16 B-fragment layout ----------------
// B-frag map (16x16x32): lane l supplies B[k = kt*32 + (l>>4)*8 + i][n = ct*16 + (l&15)]
// w0B[l][ (ct*16+c)*8+i ]            : W0[k=i][n]*rs8       (512/layer,  k<8 only)
// w1B[l][ ((ct*2+kt)*64+lane)*8+i ]  : W1[k][n]*0.125       (4096/layer, ct<4)
// w2B[l][ ((ct*2+kt)*64+lane)*8+i ]  : W2[k][n]             (8192/layer, ct<8)
__global__ void k_wtransB(const float* __restrict__ mlp_w0, const float* __restrict__ mlp_w1,
                          const float* __restrict__ mlp_w2,
                          unsigned short* __restrict__ w0B, unsigned short* __restrict__ w1B,
                          unsigned short* __restrict__ w2B) {
    int t = blockIdx.x * 256 + threadIdx.x;
    if (t >= 25600) return;
    int l = t / 12800, r = t % 12800;
    const float rs8 = 0.35355339059327373f;
    if (r < 512) {
        int ct = r >> 7, c = (r >> 3) & 15, i = r & 7;
        w0B[l * 512 + r] = f2bf(mlp_w0[l * 512 + i * 64 + ct * 16 + c] * rs8);
    } else if (r < 4608) {
        int q = r - 512;
        int i = q & 7, lane = (q >> 3) & 63, kt = (q >> 9) & 1, ct = q >> 10;
        int k = kt * 32 + (lane >> 4) * 8 + i;
        int n = ct * 16 + (lane & 15);
        w1B[l * 4096 + q] = f2bf(mlp_w1[l * 4096 + k * 64 + n] * 0.125f);
    } else {
        int q = r - 4608;
        int i = q & 7, lane = (q >> 3) & 63, kt = (q >> 9) & 1, ct = q >> 10;
        int k = kt * 32 + (lane >> 4) * 8 + i;
        int n = ct * 16 + (lane & 15);
        w2B[l * 8192 + q] = f2bf(mlp_w2[l * 8192 + k * 128 + n]);
    }
}

// ---------------- CSR build ----------------
__global__ void k_hist(const int* __restrict__ recv, int* __restrict__ deg) {
    int e = blockIdx.x * 256 + threadIdx.x;
    if (e < EE) atomicAdd(&deg[recv[e]], 1);
}

__global__ void k_scan(const int* __restrict__ deg, int* __restrict__ row_start,
                       int* __restrict__ cursor) {
    __shared__ int part[256];
    int t = threadIdx.x;
    int lo = t * 196, hi = lo + 196 > NN ? NN : lo + 196;
    int s = 0;
    for (int i = lo; i < hi; ++i) s += deg[i];
    part[t] = s;
    __syncthreads();
    int acc = 0;
    for (int i = 0; i < t; ++i) acc += part[i];
    int run = acc;
    for (int i = lo; i < hi; ++i) {
        row_start[i] = run;
        cursor[i] = run;
        run += deg[i];
    }
    if (t == 255) row_start[NN] = run;
}

__global__ void k_fill(const int* __restrict__ recv, int* __restrict__ cursor,
                       int* __restrict__ csr_edge) {
    int e = blockIdx.x * 256 + threadIdx.x;
    if (e >= EE) return;
    int p = atomicAdd(&cursor[recv[e]], 1);
    csr_edge[p] = e;
}

// ---------------- one-time gather into CSR order ----------------
__global__ void k_gather(const int* __restrict__ csr_edge, const int* __restrict__ senders,
                         const int* __restrict__ receivers, const float* __restrict__ evec,
                         int* __restrict__ csr_send, int* __restrict__ csr_recv,
                         float* __restrict__ ev3) {
    int p = blockIdx.x * 256 + threadIdx.x;
    if (p >= EE) return;
    int e = csr_edge[p];
    csr_send[p] = senders[e];
    csr_recv[p] = receivers[e];
    ev3[p * 3 + 0] = evec[e * 3 + 0];
    ev3[p * 3 + 1] = evec[e * 3 + 1];
    ev3[p * 3 + 2] = evec[e * 3 + 2];
}

// ---------------- lin1 -> feat[n][u][4] = {es, evx, evy, evz} ----------------
__global__ __attribute__((amdgpu_waves_per_eu(2, 3))) __launch_bounds__(256)
void k_node_prep2(const float* __restrict__ h_s, const float* __restrict__ h_v,
                  const float* __restrict__ w_lin1_s, const float* __restrict__ w_lin1_v,
                  float* __restrict__ feat) {
    int n = blockIdx.x * 256 + threadIdx.x;
    if (n >= NN) return;
    const float rs32 = 0.17677669529663687f;
    float* fb = feat + (size_t)n * 128;
    { // pass 1: scalars S and vector-x X
        f32x16 Sa = (f32x16)0.f, Sb = (f32x16)0.f, Xa = (f32x16)0.f, Xb = (f32x16)0.f;
        for (int u = 0; u < 32; ++u) {
            float xs = h_s[n * 32 + u];
            float xx = h_v[n * 96 + u];
            const float* Ws = w_lin1_s + u * 32;
            const float* Wv = w_lin1_v + u * 32;
#pragma unroll
            for (int v = 0; v < 16; ++v) {
                Sa[v] += xs * Ws[v];
                Sb[v] += xs * Ws[16 + v];
                Xa[v] += xx * Wv[v];
                Xb[v] += xx * Wv[16 + v];
            }
        }
#pragma unroll
        for (int q = 0; q < 16; ++q) {
            fb[q * 4 + 0]        = Sa[q] * rs32;
            fb[q * 4 + 1]        = Xa[q] * rs32;
            fb[(16 + q) * 4 + 0] = Sb[q] * rs32;
            fb[(16 + q) * 4 + 1] = Xb[q] * rs32;
        }
    }
    { // pass 2: vector-y Y and vector-z Z
        f32x16 Ya = (f32x16)0.f, Yb = (f32x16)0.f, Za = (f32x16)0.f, Zb = (f32x16)0.f;
        for (int u = 0; u < 32; ++u) {
            float xy = h_v[n * 96 + 32 + u];
            float xz = h_v[n * 96 + 64 + u];
            const float* Wv = w_lin1_v + u * 32;
#pragma unroll
            for (int v = 0; v < 16; ++v) {
                Ya[v] += xy * Wv[v];
                Yb[v] += xy * Wv[16 + v];
                Za[v] += xz * Wv[v];
                Zb[v] += xz * Wv[16 + v];
            }
        }
#pragma unroll
        for (int q = 0; q < 16; ++q) {
            fb[q * 4 + 2]        = Ya[q] * rs32;
            fb[q * 4 + 3]        = Za[q] * rs32;
            fb[(16 + q) * 4 + 2] = Yb[q] * rs32;
            fb[(16 + q) * 4 + 3] = Zb[q] * rs32;
        }
    }
}

// ---------------- fused MFMA edge kernel ----------------
// block = 256 threads = 4 waves = 256 CSR positions; wave handles 4 tiles of 16 edges.
// gemm1: EE[16x8,pad32] @ W0[8x64]   -> A1 (4 mfma)
// gemm2: A1[16x64]      @ W1[64x64]  -> A2 (8 mfma)
// gemm3: A2[16x64]      @ W2[64x128] -> D  (16 mfma)
// TP: lane owns (col=l&15, rows (l>>4)*4+j) of D; gathers feat4, scatters to LDS window.
#define WROWS 32
#define WSTRIDE 257
__global__ __launch_bounds__(256) void k_mega(
    const int* __restrict__ csr_send, const int* __restrict__ csr_recv,
    const float* __restrict__ ev3, const int* __restrict__ row_start,
    const float* __restrict__ feat,
    const unsigned short* __restrict__ w0B, const unsigned short* __restrict__ w1B,
    const unsigned short* __restrict__ w2B,
    float* __restrict__ n0, float* __restrict__ n1) {
    __shared__ float accw[WROWS * WSTRIDE];          // 32.9 KB scatter window
    __shared__ unsigned short lds_ee[256 * 8];        // 4 KB bessel bf16
    __shared__ float lds_sh[256 * 4];                 // 4 KB sh1 per edge
    __shared__ int lds_snd[256];
    __shared__ int lds_wd[256];
    __shared__ unsigned short abuf[4][16 * 72];       // 9.2 KB per-wave act tile (pad 72)
    __shared__ int sh_base, sh_last;

    int tid = threadIdx.x;
    int p0 = blockIdx.x * 256;
    int lane = tid & 63;
    int wv = tid >> 6;
    int c0 = lane & 15;
    int rg = lane >> 4;

    for (int i = tid; i < WROWS * WSTRIDE; i += 256) accw[i] = 0.f;

    // ---- phase 0: per-edge geometry -> LDS ----
    int snd0 = csr_send[p0 + tid];
    int rv = csr_recv[p0 + tid];
    if (tid == 0)   sh_base = rv;
    if (tid == 255) sh_last = rv;
    {
        float x = ev3[(p0 + tid) * 3 + 0], y = ev3[(p0 + tid) * 3 + 1], z = ev3[(p0 + tid) * 3 + 2];
        float r = sqrtf(x * x + y * y + z * z + 1e-12f);
        float ir = 1.f / r;
        const float s3 = 1.7320508075688772f;
        float shx = s3 * x * ir, shy = s3 * y * ir, shz = s3 * z * ir;
        float xx = r * 0.2f;
        float env = 0.f;
        if (xx < 1.f) {
            float x2 = xx * xx, x3 = x2 * xx, x6 = x3 * x3, x7 = x6 * xx, x8 = x7 * xx;
            env = 1.f - 28.f * x6 + 48.f * x7 - 21.f * x8;
        }
        float coef = 0.6324555320336759f * env * ir;
        const float w5 = 0.6283185307179586f;
        bf16x8 ee;
#pragma unroll
        for (int k = 0; k < 8; ++k)
            ee[k] = (short)f2bf(coef * __sinf(w5 * (float)(k + 1) * r));
        *(bf16x8*)(lds_ee + tid * 8) = ee;
        lds_sh[tid * 4 + 0] = shx;
        lds_sh[tid * 4 + 1] = shy;
        lds_sh[tid * 4 + 2] = shz;
        lds_sh[tid * 4 + 3] = 0.f;
        lds_snd[tid] = snd0;
    }
    __syncthreads();
    int node_base = sh_base;
    lds_wd[tid] = rv - node_base;   // consumed only by same wave's lanes

    // ---- preload W0 B-frags (zeros for k-chunks >= 1) ----
    bf16x8 w0f[4];
#pragma unroll
    for (int ct = 0; ct < 4; ++ct)
        w0f[ct] = (rg == 0) ? *(const bf16x8*)(w0B + (ct * 16 + c0) * 8) : (bf16x8)(short)0;
    const bf16x8* w1f = (const bf16x8*)w1B;   // index (ct*2+kt)*64 + lane
    const bf16x8* w2f = (const bf16x8*)w2B;

    const f32x4* feat4 = (const f32x4*)feat;
    const float rs3 = 0.5773502691896258f;
    unsigned short* ab = abuf[wv];
    const f32x4 cz = (f32x4)0.f;

    for (int t = 0; t < 4; ++t) {
        int tOff = wv * 64 + t * 16;

        // ---- gemm1: EE @ W0 ----
        bf16x8 aee = (rg == 0) ? *(const bf16x8*)(lds_ee + (tOff + c0) * 8) : (bf16x8)(short)0;
        f32x4 C1[4];
#pragma unroll
        for (int ct = 0; ct < 4; ++ct)
            C1[ct] = __builtin_amdgcn_mfma_f32_16x16x32_bf16(aee, w0f[ct], cz, 0, 0, 0);
        // write A1 bf16 to abuf[row][ch]
#pragma unroll
        for (int ct = 0; ct < 4; ++ct)
#pragma unroll
            for (int j = 0; j < 4; ++j)
                ab[(rg * 4 + j) * 72 + ct * 16 + c0] = f2bf(silu_f(C1[ct][j]));

        // ---- gemm2: A1 @ W1 (read both A-frags before overwriting abuf) ----
        bf16x8 A10 = *(const bf16x8*)(ab + c0 * 72 + rg * 8);
        bf16x8 A11 = *(const bf16x8*)(ab + c0 * 72 + 32 + rg * 8);
        f32x4 C2[4];
#pragma unroll
        for (int ct = 0; ct < 4; ++ct) {
            f32x4 c = __builtin_amdgcn_mfma_f32_16x16x32_bf16(A10, w1f[(ct * 2 + 0) * 64 + lane], cz, 0, 0, 0);
            C2[ct]  = __builtin_amdgcn_mfma_f32_16x16x32_bf16(A11, w1f[(ct * 2 + 1) * 64 + lane], c, 0, 0, 0);
        }
#pragma unroll
        for (int ct = 0; ct < 4; ++ct)
#pragma unroll
            for (int j = 0; j < 4; ++j)
                ab[(rg * 4 + j) * 72 + ct * 16 + c0] = f2bf(silu_f(C2[ct][j]));

        // ---- gemm3: A2 @ W2 -> D ----
        bf16x8 A20 = *(const bf16x8*)(ab + c0 * 72 + rg * 8);
        bf16x8 A21 = *(const bf16x8*)(ab + c0 * 72 + 32 + rg * 8);
        f32x4 C3[8];
#pragma unroll
        for (int ct = 0; ct < 8; ++ct) {
            f32x4 c = __builtin_amdgcn_mfma_f32_16x16x32_bf16(A20, w2f[(ct * 2 + 0) * 64 + lane], cz, 0, 0, 0);
            C3[ct]  = __builtin_amdgcn_mfma_f32_16x16x32_bf16(A21, w2f[(ct * 2 + 1) * 64 + lane], c, 0, 0, 0);
        }

        // ---- TP + scatter ----
#pragma unroll
        for (int j = 0; j < 4; ++j) {
            int idx = tOff + rg * 4 + j;
            int s = lds_snd[idx];
            float shx = lds_sh[idx * 4 + 0];
            float shy = lds_sh[idx * 4 + 1];
            float shz = lds_sh[idx * 4 + 2];
            int wrow = lds_wd[idx];
#pragma unroll
            for (int b = 0; b < 2; ++b) {
                int u = b * 16 + c0;
                f32x4 f4 = feat4[(size_t)s * 32 + u];
                float d1 = C3[0 + b][j], d2 = C3[2 + b][j];
                float d3 = C3[4 + b][j], d4 = C3[6 + b][j];
                float es = f4[0], ev0 = f4[1], ev1 = f4[2], ev2 = f4[3];
                float dot = ev0 * shx + ev1 * shy + ev2 * shz;
                float o0a = d1 * es;
                float o0b = d2 * dot * rs3;
                float t3 = d3 * es;
                float v2 = t3 * shx, v3 = d4 * ev0;
                float v4 = t3 * shy, v5 = d4 * ev1;
                float v6 = t3 * shz, v7 = d4 * ev2;
                if (wrow < WROWS) {
                    float* arow = accw + wrow * WSTRIDE;
                    atomicAdd(arow + u, o0a);
                    atomicAdd(arow + 32 + u, o0b);
                    atomicAdd(arow + 64 + u, v2);
                    atomicAdd(arow + 96 + u, v3);
                    atomicAdd(arow + 128 + u, v4);
                    atomicAdd(arow + 160 + u, v5);
                    atomicAdd(arow + 192 + u, v6);
                    atomicAdd(arow + 224 + u, v7);
                } else { // rare window overflow
                    int rvn = node_base + wrow;
                    float* n0r = n0 + (size_t)rvn * 64;
                    float* n1r = n1 + (size_t)rvn * 192;
                    atomicAdd(n0r + u, o0a);
                    atomicAdd(n0r + 32 + u, o0b);
                    atomicAdd(n1r + u, v2);
                    atomicAdd(n1r + 32 + u, v3);
                    atomicAdd(n1r + 64 + u, v4);
                    atomicAdd(n1r + 96 + u, v5);
                    atomicAdd(n1r + 128 + u, v6);
                    atomicAdd(n1r + 160 + u, v7);
                }
            }
        }
    }
    __syncthreads();

    // ---- flush window ----
    int span = sh_last - node_base;
    if (span > WROWS - 1) span = WROWS - 1;
    for (int wl = 0; wl <= span; ++wl) {
        int n = node_base + wl;
        float v = accw[wl * WSTRIDE + tid];
        bool interior = (row_start[n] >= p0) && (row_start[n + 1] <= p0 + 256);
        float* dest = (tid < 64) ? (n0 + (size_t)n * 64 + tid) : (n1 + (size_t)n * 192 + (tid - 64));
        if (interior) *dest = v;
        else if (v != 0.f) atomicAdd(dest, v);
    }
}

// ---------------- node update ----------------
__global__ __attribute__((amdgpu_waves_per_eu(2, 3))) __launch_bounds__(256)
void k_node_update(
        const int* __restrict__ species,
        const float* __restrict__ n0, const float* __restrict__ n1,
        const float* __restrict__ w_lin2_s, const float* __restrict__ w_lin2_v,
        const float* __restrict__ w_res_s, const float* __restrict__ w_res_v,
        float* __restrict__ h_s, float* __restrict__ h_v) {
    int n = blockIdx.x * 256 + threadIdx.x;
    if (n >= NN) return;
    int sp = species[n];
    const float sc_l2 = 1.f / 128.f;
    const float rs160 = 0.07905694150420949f;

    f32x16 s0 = (f32x16)0.f, s1 = (f32x16)0.f, s2 = (f32x16)0.f, s3 = (f32x16)0.f;
    const float* n0r = n0 + (size_t)n * 64;
    for (int j = 0; j < 64; ++j) {
        float xv = n0r[j] * sc_l2;
        const float* Wr = w_lin2_s + j * 64;
#pragma unroll
        for (int k = 0; k < 16; ++k) {
            s0[k] += xv * Wr[k];
            s1[k] += xv * Wr[16 + k];
            s2[k] += xv * Wr[32 + k];
            s3[k] += xv * Wr[48 + k];
        }
    }
    const float* hsr = h_s + n * 32;
    for (int u = 0; u < 32; ++u) {
        float xv = hsr[u] * rs160;
        const float* Wr = w_res_s + (u * 5 + sp) * 64;
#pragma unroll
        for (int k = 0; k < 16; ++k) {
            s0[k] += xv * Wr[k];
            s1[k] += xv * Wr[16 + k];
            s2[k] += xv * Wr[32 + k];
            s3[k] += xv * Wr[48 + k];
        }
    }
    f32x16 g0, g1, h0, h1;
#pragma unroll
    for (int k = 0; k < 16; ++k) {
        h0[k] = silu_f(s0[k]);
        h1[k] = silu_f(s1[k]);
        g0[k] = silu_f(s2[k]);
        g1[k] = silu_f(s3[k]);
    }

    for (int i = 0; i < 3; ++i) {
        f32x16 v0 = (f32x16)0.f, v1 = (f32x16)0.f;
        const float* n1r = n1 + (size_t)n * 192 + i * 64;
        for (int u = 0; u < 64; ++u) {
            float xv = n1r[u] * sc_l2;
            const float* Wr = w_lin2_v + u * 32;
#pragma unroll
            for (int v = 0; v < 16; ++v) {
                v0[v] += xv * Wr[v];
                v1[v] += xv * Wr[16 + v];
            }
        }
        const float* hvr = h_v + n * 96 + i * 32;
        for (int u = 0; u < 32; ++u) {
            float xv = hvr[u] * rs160;
            const float* Wr = w_res_v + (u * 5 + sp) * 32;
#pragma unroll
            for (int v = 0; v < 16; ++v) {
                v0[v] += xv * Wr[v];
                v1[v] += xv * Wr[16 + v];
            }
        }
        float* outp = h_v + n * 96 + i * 32;
#pragma unroll
        for (int v = 0; v < 16; ++v) {
            outp[v]      = v0[v] * g0[v];
            outp[16 + v] = v1[v] * g1[v];
        }
    }
#pragma unroll
    for (int v = 0; v < 16; ++v) {
        h_s[n * 32 + v]      = h0[v];
        h_s[n * 32 + 16 + v] = h1[v];
    }
}

// ---------------- readout ----------------
__global__ void k_readout(const float* __restrict__ h_s, const float* __restrict__ w_out1,
                          const float* __restrict__ w_out2, float* __restrict__ out) {
    int n = blockIdx.x * 256 + threadIdx.x;
    if (n >= NN) return;
    f32x16 zacc = (f32x16)0.f;
    const float* hsr = h_s + n * 32;
    for (int u = 0; u < 32; ++u) {
        float xv = hsr[u];
        const float* Wr = w_out1 + u * 16;
#pragma unroll
        for (int j = 0; j < 16; ++j) zacc[j] += xv * Wr[j];
    }
    float ev = 0.f;
#pragma unroll
    for (int j = 0; j < 16; ++j) ev += zacc[j] * w_out2[j];
    out[n] = ev * 0.17677669529663687f * 0.25f;
}

extern "C" void kernel_launch(void* const* d_in, const int* in_sizes, int n_in,
                              void* d_out, int out_size, void* d_ws, size_t ws_size,
                              hipStream_t stream) {
    const float* evec     = (const float*)d_in[0];
    const int*   species  = (const int*)d_in[1];
    const int*   senders  = (const int*)d_in[2];
    const int*   receivers= (const int*)d_in[3];
    const float* embed_w  = (const float*)d_in[4];
    const float* w_res_s  = (const float*)d_in[5];
    const float* w_res_v  = (const float*)d_in[6];
    const float* w_lin1_s = (const float*)d_in[7];
    const float* w_lin1_v = (const float*)d_in[8];
    const float* mlp_w0   = (const float*)d_in[9];
    const float* mlp_w1   = (const float*)d_in[10];
    const float* mlp_w2   = (const float*)d_in[11];
    const float* w_lin2_s = (const float*)d_in[12];
    const float* w_lin2_v = (const float*)d_in[13];
    const float* w_out1   = (const float*)d_in[14];
    const float* w_out2   = (const float*)d_in[15];

    float* ws = (float*)d_ws;
    size_t off = 0;
    auto alloc = [&](size_t n) { float* p = ws + off; off += (n + 3) & ~(size_t)3; return p; };

    float* h_s  = alloc(NN * 32);
    float* h_v  = alloc(NN * 96);
    float* feat = alloc((size_t)NN * 128);
    float* n0b  = alloc(NN * 64);
    float* n1b  = alloc(NN * 192);
    unsigned short* w0B = (unsigned short*)alloc(512);    // 1024 bf16
    unsigned short* w1B = (unsigned short*)alloc(4096);   // 8192 bf16
    unsigned short* w2B = (unsigned short*)alloc(8192);   // 16384 bf16
    int*   deg       = (int*)alloc(NN);
    int*   row_start = (int*)alloc(NN + 1);
    int*   cursor    = (int*)alloc(NN);
    int*   csr_edge  = (int*)alloc(EE);
    int*   csr_send  = (int*)alloc(EE);
    int*   csr_recv  = (int*)alloc(EE);
    float* ev3       = alloc((size_t)EE * 3);
    // total ~30.6M floats ~= 122 MB

    k_embed<<<(NN + 255) / 256, 256, 0, stream>>>(species, embed_w, h_s, h_v);
    k_wtransB<<<100, 256, 0, stream>>>(mlp_w0, mlp_w1, mlp_w2, w0B, w1B, w2B);

    hipMemsetAsync(deg, 0, NN * 4, stream);
    k_hist<<<(EE + 255) / 256, 256, 0, stream>>>(receivers, deg);
    k_scan<<<1, 256, 0, stream>>>(deg, row_start, cursor);
    k_fill<<<(EE + 255) / 256, 256, 0, stream>>>(receivers, cursor, csr_edge);
    k_gather<<<(EE + 255) / 256, 256, 0, stream>>>(csr_edge, senders, receivers, evec,
                                                   csr_send, csr_recv, ev3);

    for (int l = 0; l < 2; ++l) {
        k_node_prep2<<<(NN + 255) / 256, 256, 0, stream>>>(
            h_s, h_v, w_lin1_s + l * 1024, w_lin1_v + l * 1024, feat);
        hipMemsetAsync(n0b, 0, (size_t)NN * 64 * 4, stream);
        hipMemsetAsync(n1b, 0, (size_t)NN * 192 * 4, stream);
        k_mega<<<EE / 256, 256, 0, stream>>>(
            csr_send, csr_recv, ev3, row_start, feat,
            w0B + l * 512, w1B + l * 4096, w2B + l * 8192, n0b, n1b);
        k_node_update<<<(NN + 255) / 256, 256, 0, stream>>>(
            species, n0b, n1b,
            w_lin2_s + l * 4096, w_lin2_v + l * 2048,
            w_res_s + l * 10240, w_res_v + l * 5120, h_s, h_v);
    }
    k_readout<<<(NN + 255) / 256, 256, 0, stream>>>(h_s, w_out1, w_out2, (float*)d_out);
}

// Round 9
// 1497.397 us; speedup vs baseline: 2.4180x; 1.9797x over previous
//
#include <hip/hip_runtime.h>
#include <math.h>

#define NN 50000
#define EE 800000

typedef float f32x4  __attribute__((ext_vector_type(4)));
typedef float f32x16 __attribute__((ext_vector_type(16)));
typedef short bf16x8 __attribute__((ext_vector_type(8)));

__device__ __forceinline__ float silu_f(float x) {
    return x / (1.f + __expf(-x));
}
__device__ __forceinline__ unsigned short f2bf(float f) {
    unsigned int u = __float_as_uint(f);
    unsigned int r = (u + 0x7fffu + ((u >> 16) & 1u)) >> 16;
    return (unsigned short)r;
}

// ---------------- node embedding ----------------
__global__ void k_embed(const int* __restrict__ species, const float* __restrict__ embed_w,
                        float* __restrict__ h_s, float* __restrict__ h_v) {
    int n = blockIdx.x * 256 + threadIdx.x;
    if (n >= NN) return;
    int sp = species[n];
    const float rs5 = 0.4472135954999579f;
#pragma unroll
    for (int u = 0; u < 32; ++u) h_s[n * 32 + u] = embed_w[sp * 32 + u] * rs5;
#pragma unroll
    for (int t = 0; t < 96; ++t) h_v[n * 96 + t] = 0.f;
}

// ---------------- weights -> bf16 B-fragment layout ----------------
__global__ void k_wtransB(const float* __restrict__ mlp_w0, const float* __restrict__ mlp_w1,
                          const float* __restrict__ mlp_w2,
                          unsigned short* __restrict__ w0B, unsigned short* __restrict__ w1B,
                          unsigned short* __restrict__ w2B) {
    int t = blockIdx.x * 256 + threadIdx.x;
    if (t >= 25600) return;
    int l = t / 12800, r = t % 12800;
    const float rs8 = 0.35355339059327373f;
    if (r < 512) {
        int ct = r >> 7, c = (r >> 3) & 15, i = r & 7;
        w0B[l * 512 + r] = f2bf(mlp_w0[l * 512 + i * 64 + ct * 16 + c] * rs8);
    } else if (r < 4608) {
        int q = r - 512;
        int i = q & 7, lane = (q >> 3) & 63, kt = (q >> 9) & 1, ct = q >> 10;
        int k = kt * 32 + (lane >> 4) * 8 + i;
        int n = ct * 16 + (lane & 15);
        w1B[l * 4096 + q] = f2bf(mlp_w1[l * 4096 + k * 64 + n] * 0.125f);
    } else {
        int q = r - 4608;
        int i = q & 7, lane = (q >> 3) & 63, kt = (q >> 9) & 1, ct = q >> 10;
        int k = kt * 32 + (lane >> 4) * 8 + i;
        int n = ct * 16 + (lane & 15);
        w2B[l * 8192 + q] = f2bf(mlp_w2[l * 8192 + k * 128 + n]);
    }
}

// ---------------- CSR build ----------------
__global__ void k_hist(const int* __restrict__ recv, int* __restrict__ deg) {
    int e = blockIdx.x * 256 + threadIdx.x;
    if (e < EE) atomicAdd(&deg[recv[e]], 1);
}

__global__ void k_scan(const int* __restrict__ deg, int* __restrict__ row_start,
                       int* __restrict__ cursor) {
    __shared__ int part[256];
    int t = threadIdx.x;
    int lo = t * 196, hi = lo + 196 > NN ? NN : lo + 196;
    int s = 0;
    for (int i = lo; i < hi; ++i) s += deg[i];
    part[t] = s;
    __syncthreads();
    int acc = 0;
    for (int i = 0; i < t; ++i) acc += part[i];
    int run = acc;
    for (int i = lo; i < hi; ++i) {
        row_start[i] = run;
        cursor[i] = run;
        run += deg[i];
    }
    if (t == 255) row_start[NN] = run;
}

__global__ void k_fill(const int* __restrict__ recv, int* __restrict__ cursor,
                       int* __restrict__ csr_edge) {
    int e = blockIdx.x * 256 + threadIdx.x;
    if (e >= EE) return;
    int p = atomicAdd(&cursor[recv[e]], 1);
    csr_edge[p] = e;
}

// ---------------- one-time gather into CSR order ----------------
__global__ void k_gather(const int* __restrict__ csr_edge, const int* __restrict__ senders,
                         const int* __restrict__ receivers, const float* __restrict__ evec,
                         int* __restrict__ csr_send, int* __restrict__ csr_recv,
                         float* __restrict__ ev3) {
    int p = blockIdx.x * 256 + threadIdx.x;
    if (p >= EE) return;
    int e = csr_edge[p];
    csr_send[p] = senders[e];
    csr_recv[p] = receivers[e];
    ev3[p * 3 + 0] = evec[e * 3 + 0];
    ev3[p * 3 + 1] = evec[e * 3 + 1];
    ev3[p * 3 + 2] = evec[e * 3 + 2];
}

// ---------------- lin1 -> feat[n][u][4] = {es, evx, evy, evz} ----------------
__global__ __attribute__((amdgpu_waves_per_eu(2, 3))) __launch_bounds__(256)
void k_node_prep2(const float* __restrict__ h_s, const float* __restrict__ h_v,
                  const float* __restrict__ w_lin1_s, const float* __restrict__ w_lin1_v,
                  float* __restrict__ feat) {
    int n = blockIdx.x * 256 + threadIdx.x;
    if (n >= NN) return;
    const float rs32 = 0.17677669529663687f;
    float* fb = feat + (size_t)n * 128;
    { // pass 1: scalars S and vector-x X
        f32x16 Sa = (f32x16)0.f, Sb = (f32x16)0.f, Xa = (f32x16)0.f, Xb = (f32x16)0.f;
        for (int u = 0; u < 32; ++u) {
            float xs = h_s[n * 32 + u];
            float xx = h_v[n * 96 + u];
            const float* Ws = w_lin1_s + u * 32;
            const float* Wv = w_lin1_v + u * 32;
#pragma unroll
            for (int v = 0; v < 16; ++v) {
                Sa[v] += xs * Ws[v];
                Sb[v] += xs * Ws[16 + v];
                Xa[v] += xx * Wv[v];
                Xb[v] += xx * Wv[16 + v];
            }
        }
#pragma unroll
        for (int q = 0; q < 16; ++q) {
            fb[q * 4 + 0]        = Sa[q] * rs32;
            fb[q * 4 + 1]        = Xa[q] * rs32;
            fb[(16 + q) * 4 + 0] = Sb[q] * rs32;
            fb[(16 + q) * 4 + 1] = Xb[q] * rs32;
        }
    }
    { // pass 2: vector-y Y and vector-z Z
        f32x16 Ya = (f32x16)0.f, Yb = (f32x16)0.f, Za = (f32x16)0.f, Zb = (f32x16)0.f;
        for (int u = 0; u < 32; ++u) {
            float xy = h_v[n * 96 + 32 + u];
            float xz = h_v[n * 96 + 64 + u];
            const float* Wv = w_lin1_v + u * 32;
#pragma unroll
            for (int v = 0; v < 16; ++v) {
                Ya[v] += xy * Wv[v];
                Yb[v] += xy * Wv[16 + v];
                Za[v] += xz * Wv[v];
                Zb[v] += xz * Wv[16 + v];
            }
        }
#pragma unroll
        for (int q = 0; q < 16; ++q) {
            fb[q * 4 + 2]        = Ya[q] * rs32;
            fb[q * 4 + 3]        = Za[q] * rs32;
            fb[(16 + q) * 4 + 2] = Yb[q] * rs32;
            fb[(16 + q) * 4 + 3] = Zb[q] * rs32;
        }
    }
}

// ---------------- fused MFMA edge kernel with run-length pre-reduced scatter ----------------
#define WROWS 32
#define WSTRIDE 260
__global__ __launch_bounds__(256) void k_mega(
    const int* __restrict__ csr_send, const int* __restrict__ csr_recv,
    const float* __restrict__ ev3, const int* __restrict__ row_start,
    const float* __restrict__ feat,
    const unsigned short* __restrict__ w0B, const unsigned short* __restrict__ w1B,
    const unsigned short* __restrict__ w2B,
    float* __restrict__ n0, float* __restrict__ n1) {
    __shared__ f32x4 accw4[WROWS * WSTRIDE / 4];      // 33.3 KB scatter window
    __shared__ unsigned short lds_ee[256 * 8];        // 4 KB bessel bf16
    __shared__ f32x4 lds_esh[256];                    // 4 KB {shx,shy,shz,as_float(snd)}
    __shared__ int lds_wd[256];
    __shared__ unsigned short abuf[4][16 * 72];       // 9.2 KB per-wave act tile
    __shared__ int sh_base, sh_last;
    float* accw = (float*)accw4;

    int tid = threadIdx.x;
    int p0 = blockIdx.x * 256;
    int lane = tid & 63;
    int wv = tid >> 6;
    int c0 = lane & 15;
    int rg = lane >> 4;

    for (int i = tid; i < WROWS * WSTRIDE / 4; i += 256) accw4[i] = (f32x4)0.f;

    // ---- phase 0: per-edge geometry -> LDS ----
    int snd0 = csr_send[p0 + tid];
    int rv = csr_recv[p0 + tid];
    if (tid == 0)   sh_base = rv;
    if (tid == 255) sh_last = rv;
    {
        float x = ev3[(p0 + tid) * 3 + 0], y = ev3[(p0 + tid) * 3 + 1], z = ev3[(p0 + tid) * 3 + 2];
        float r = sqrtf(x * x + y * y + z * z + 1e-12f);
        float ir = 1.f / r;
        const float s3 = 1.7320508075688772f;
        float xx = r * 0.2f;
        float env = 0.f;
        if (xx < 1.f) {
            float x2 = xx * xx, x3 = x2 * xx, x6 = x3 * x3, x7 = x6 * xx, x8 = x7 * xx;
            env = 1.f - 28.f * x6 + 48.f * x7 - 21.f * x8;
        }
        float coef = 0.6324555320336759f * env * ir;
        const float w5 = 0.6283185307179586f;
        bf16x8 ee;
#pragma unroll
        for (int k = 0; k < 8; ++k)
            ee[k] = (short)f2bf(coef * __sinf(w5 * (float)(k + 1) * r));
        *(bf16x8*)(lds_ee + tid * 8) = ee;
        f32x4 esh;
        esh[0] = s3 * x * ir;
        esh[1] = s3 * y * ir;
        esh[2] = s3 * z * ir;
        esh[3] = __int_as_float(snd0);
        lds_esh[tid] = esh;
    }
    __syncthreads();
    int node_base = sh_base;
    lds_wd[tid] = rv - node_base;   // consumed only by same wave's lanes

    // ---- preload W0 B-frags (zeros for k-chunks >= 1) ----
    bf16x8 w0f[4];
#pragma unroll
    for (int ct = 0; ct < 4; ++ct)
        w0f[ct] = (rg == 0) ? *(const bf16x8*)(w0B + (ct * 16 + c0) * 8) : (bf16x8)(short)0;
    const bf16x8* w1f = (const bf16x8*)w1B;
    const bf16x8* w2f = (const bf16x8*)w2B;

    const f32x4* feat4 = (const f32x4*)feat;
    const float rs3 = 0.5773502691896258f;
    unsigned short* ab = abuf[wv];
    const f32x4 cz = (f32x4)0.f;

    for (int t = 0; t < 4; ++t) {
        int tOff = wv * 64 + t * 16;

        // ---- gemm1: EE @ W0 ----
        bf16x8 aee = (rg == 0) ? *(const bf16x8*)(lds_ee + (tOff + c0) * 8) : (bf16x8)(short)0;
        f32x4 C1[4];
#pragma unroll
        for (int ct = 0; ct < 4; ++ct)
            C1[ct] = __builtin_amdgcn_mfma_f32_16x16x32_bf16(aee, w0f[ct], cz, 0, 0, 0);
#pragma unroll
        for (int ct = 0; ct < 4; ++ct)
#pragma unroll
            for (int j = 0; j < 4; ++j)
                ab[(rg * 4 + j) * 72 + ct * 16 + c0] = f2bf(silu_f(C1[ct][j]));

        // ---- gemm2: A1 @ W1 ----
        bf16x8 A10 = *(const bf16x8*)(ab + c0 * 72 + rg * 8);
        bf16x8 A11 = *(const bf16x8*)(ab + c0 * 72 + 32 + rg * 8);
        f32x4 C2[4];
#pragma unroll
        for (int ct = 0; ct < 4; ++ct) {
            f32x4 c = __builtin_amdgcn_mfma_f32_16x16x32_bf16(A10, w1f[(ct * 2 + 0) * 64 + lane], cz, 0, 0, 0);
            C2[ct]  = __builtin_amdgcn_mfma_f32_16x16x32_bf16(A11, w1f[(ct * 2 + 1) * 64 + lane], c, 0, 0, 0);
        }
#pragma unroll
        for (int ct = 0; ct < 4; ++ct)
#pragma unroll
            for (int j = 0; j < 4; ++j)
                ab[(rg * 4 + j) * 72 + ct * 16 + c0] = f2bf(silu_f(C2[ct][j]));

        // ---- gemm3: A2 @ W2 -> D ----
        bf16x8 A20 = *(const bf16x8*)(ab + c0 * 72 + rg * 8);
        bf16x8 A21 = *(const bf16x8*)(ab + c0 * 72 + 32 + rg * 8);
        f32x4 C3[8];
#pragma unroll
        for (int ct = 0; ct < 8; ++ct) {
            f32x4 c = __builtin_amdgcn_mfma_f32_16x16x32_bf16(A20, w2f[(ct * 2 + 0) * 64 + lane], cz, 0, 0, 0);
            C3[ct]  = __builtin_amdgcn_mfma_f32_16x16x32_bf16(A21, w2f[(ct * 2 + 1) * 64 + lane], c, 0, 0, 0);
        }

        // ---- TP + run-length pre-reduced scatter ----
#pragma unroll
        for (int b = 0; b < 2; ++b) {
            int u = b * 16 + c0;
            float s0 = 0.f, s1 = 0.f, s2 = 0.f, s3v = 0.f;
            float s4 = 0.f, s5 = 0.f, s6 = 0.f, s7 = 0.f;
            int curw = 0;
            auto emit = [&](int wrow) {
                if (wrow < WROWS) {
                    float* arow = accw + wrow * WSTRIDE;
                    atomicAdd(arow + u, s0);
                    atomicAdd(arow + 32 + u, s1);
                    atomicAdd(arow + 64 + u, s2);
                    atomicAdd(arow + 96 + u, s3v);
                    atomicAdd(arow + 128 + u, s4);
                    atomicAdd(arow + 160 + u, s5);
                    atomicAdd(arow + 192 + u, s6);
                    atomicAdd(arow + 224 + u, s7);
                } else { // rare window overflow
                    int rvn = node_base + wrow;
                    float* n0r = n0 + (size_t)rvn * 64;
                    float* n1r = n1 + (size_t)rvn * 192;
                    atomicAdd(n0r + u, s0);
                    atomicAdd(n0r + 32 + u, s1);
                    atomicAdd(n1r + u, s2);
                    atomicAdd(n1r + 32 + u, s3v);
                    atomicAdd(n1r + 64 + u, s4);
                    atomicAdd(n1r + 96 + u, s5);
                    atomicAdd(n1r + 128 + u, s6);
                    atomicAdd(n1r + 160 + u, s7);
                }
            };
#pragma unroll
            for (int j = 0; j < 4; ++j) {
                int idx = tOff + rg * 4 + j;
                f32x4 esh = lds_esh[idx];
                int s = __float_as_int(esh[3]);
                int wrow = lds_wd[idx];
                f32x4 f4 = feat4[(size_t)s * 32 + u];
                float d1 = C3[0 + b][j], d2 = C3[2 + b][j];
                float d3 = C3[4 + b][j], d4 = C3[6 + b][j];
                float es = f4[0], ev0 = f4[1], ev1 = f4[2], ev2 = f4[3];
                float dot = ev0 * esh[0] + ev1 * esh[1] + ev2 * esh[2];
                float t3 = d3 * es;
                if (j == 0) {
                    curw = wrow;
                } else if (wrow != curw) {
                    emit(curw);
                    s0 = s1 = s2 = s3v = s4 = s5 = s6 = s7 = 0.f;
                    curw = wrow;
                }
                s0  += d1 * es;
                s1  += d2 * dot * rs3;
                s2  += t3 * esh[0];
                s3v += d4 * ev0;
                s4  += t3 * esh[1];
                s5  += d4 * ev1;
                s6  += t3 * esh[2];
                s7  += d4 * ev2;
            }
            emit(curw);
        }
    }
    __syncthreads();

    // ---- flush window ----
    int span = sh_last - node_base;
    if (span > WROWS - 1) span = WROWS - 1;
    for (int wl = 0; wl <= span; ++wl) {
        int n = node_base + wl;
        float v = accw[wl * WSTRIDE + tid];
        bool interior = (row_start[n] >= p0) && (row_start[n + 1] <= p0 + 256);
        float* dest = (tid < 64) ? (n0 + (size_t)n * 64 + tid) : (n1 + (size_t)n * 192 + (tid - 64));
        if (interior) *dest = v;
        else if (v != 0.f) atomicAdd(dest, v);
    }
}

// ---------------- node update ----------------
__global__ __attribute__((amdgpu_waves_per_eu(2, 3))) __launch_bounds__(256)
void k_node_update(
        const int* __restrict__ species,
        const float* __restrict__ n0, const float* __restrict__ n1,
        const float* __restrict__ w_lin2_s, const float* __restrict__ w_lin2_v,
        const float* __restrict__ w_res_s, const float* __restrict__ w_res_v,
        float* __restrict__ h_s, float* __restrict__ h_v) {
    int n = blockIdx.x * 256 + threadIdx.x;
    if (n >= NN) return;
    int sp = species[n];
    const float sc_l2 = 1.f / 128.f;
    const float rs160 = 0.07905694150420949f;

    f32x16 s0 = (f32x16)0.f, s1 = (f32x16)0.f, s2 = (f32x16)0.f, s3 = (f32x16)0.f;
    const float* n0r = n0 + (size_t)n * 64;
    for (int j = 0; j < 64; ++j) {
        float xv = n0r[j] * sc_l2;
        const float* Wr = w_lin2_s + j * 64;
#pragma unroll
        for (int k = 0; k < 16; ++k) {
            s0[k] += xv * Wr[k];
            s1[k] += xv * Wr[16 + k];
            s2[k] += xv * Wr[32 + k];
            s3[k] += xv * Wr[48 + k];
        }
    }
    const float* hsr = h_s + n * 32;
    for (int u = 0; u < 32; ++u) {
        float xv = hsr[u] * rs160;
        const float* Wr = w_res_s + (u * 5 + sp) * 64;
#pragma unroll
        for (int k = 0; k < 16; ++k) {
            s0[k] += xv * Wr[k];
            s1[k] += xv * Wr[16 + k];
            s2[k] += xv * Wr[32 + k];
            s3[k] += xv * Wr[48 + k];
        }
    }
    f32x16 g0, g1, h0, h1;
#pragma unroll
    for (int k = 0; k < 16; ++k) {
        h0[k] = silu_f(s0[k]);
        h1[k] = silu_f(s1[k]);
        g0[k] = silu_f(s2[k]);
        g1[k] = silu_f(s3[k]);
    }

    for (int i = 0; i < 3; ++i) {
        f32x16 v0 = (f32x16)0.f, v1 = (f32x16)0.f;
        const float* n1r = n1 + (size_t)n * 192 + i * 64;
        for (int u = 0; u < 64; ++u) {
            float xv = n1r[u] * sc_l2;
            const float* Wr = w_lin2_v + u * 32;
#pragma unroll
            for (int v = 0; v < 16; ++v) {
                v0[v] += xv * Wr[v];
                v1[v] += xv * Wr[16 + v];
            }
        }
        const float* hvr = h_v + n * 96 + i * 32;
        for (int u = 0; u < 32; ++u) {
            float xv = hvr[u] * rs160;
            const float* Wr = w_res_v + (u * 5 + sp) * 32;
#pragma unroll
            for (int v = 0; v < 16; ++v) {
                v0[v] += xv * Wr[v];
                v1[v] += xv * Wr[16 + v];
            }
        }
        float* outp = h_v + n * 96 + i * 32;
#pragma unroll
        for (int v = 0; v < 16; ++v) {
            outp[v]      = v0[v] * g0[v];
            outp[16 + v] = v1[v] * g1[v];
        }
    }
#pragma unroll
    for (int v = 0; v < 16; ++v) {
        h_s[n * 32 + v]      = h0[v];
        h_s[n * 32 + 16 + v] = h1[v];
    }
}

// ---------------- readout ----------------
__global__ void k_readout(const float* __restrict__ h_s, const float* __restrict__ w_out1,
                          const float* __restrict__ w_out2, float* __restrict__ out) {
    int n = blockIdx.x * 256 + threadIdx.x;
    if (n >= NN) return;
    f32x16 zacc = (f32x16)0.f;
    const float* hsr = h_s + n * 32;
    for (int u = 0; u < 32; ++u) {
        float xv = hsr[u];
        const float* Wr = w_out1 + u * 16;
#pragma unroll
        for (int j = 0; j < 16; ++j) zacc[j] += xv * Wr[j];
    }
    float ev = 0.f;
#pragma unroll
    for (int j = 0; j < 16; ++j) ev += zacc[j] * w_out2[j];
    out[n] = ev * 0.17677669529663687f * 0.25f;
}

extern "C" void kernel_launch(void* const* d_in, const int* in_sizes, int n_in,
                              void* d_out, int out_size, void* d_ws, size_t ws_size,
                              hipStream_t stream) {
    const float* evec     = (const float*)d_in[0];
    const int*   species  = (const int*)d_in[1];
    const int*   senders  = (const int*)d_in[2];
    const int*   receivers= (const int*)d_in[3];
    const float* embed_w  = (const float*)d_in[4];
    const float* w_res_s  = (const float*)d_in[5];
    const float* w_res_v  = (const float*)d_in[6];
    const float* w_lin1_s = (const float*)d_in[7];
    const float* w_lin1_v = (const float*)d_in[8];
    const float* mlp_w0   = (const float*)d_in[9];
    const float* mlp_w1   = (const float*)d_in[10];
    const float* mlp_w2   = (const float*)d_in[11];
    const float* w_lin2_s = (const float*)d_in[12];
    const float* w_lin2_v = (const float*)d_in[13];
    const float* w_out1   = (const float*)d_in[14];
    const float* w_out2   = (const float*)d_in[15];

    float* ws = (float*)d_ws;
    size_t off = 0;
    auto alloc = [&](size_t n) { float* p = ws + off; off += (n + 3) & ~(size_t)3; return p; };

    float* h_s  = alloc(NN * 32);
    float* h_v  = alloc(NN * 96);
    float* feat = alloc((size_t)NN * 128);
    float* n0b  = alloc(NN * 64);
    float* n1b  = alloc(NN * 192);
    unsigned short* w0B = (unsigned short*)alloc(512);
    unsigned short* w1B = (unsigned short*)alloc(4096);
    unsigned short* w2B = (unsigned short*)alloc(8192);
    int*   deg       = (int*)alloc(NN);
    int*   row_start = (int*)alloc(NN + 1);
    int*   cursor    = (int*)alloc(NN);
    int*   csr_edge  = (int*)alloc(EE);
    int*   csr_send  = (int*)alloc(EE);
    int*   csr_recv  = (int*)alloc(EE);
    float* ev3       = alloc((size_t)EE * 3);

    k_embed<<<(NN + 255) / 256, 256, 0, stream>>>(species, embed_w, h_s, h_v);
    k_wtransB<<<100, 256, 0, stream>>>(mlp_w0, mlp_w1, mlp_w2, w0B, w1B, w2B);

    hipMemsetAsync(deg, 0, NN * 4, stream);
    k_hist<<<(EE + 255) / 256, 256, 0, stream>>>(receivers, deg);
    k_scan<<<1, 256, 0, stream>>>(deg, row_start, cursor);
    k_fill<<<(EE + 255) / 256, 256, 0, stream>>>(receivers, cursor, csr_edge);
    k_gather<<<(EE + 255) / 256, 256, 0, stream>>>(csr_edge, senders, receivers, evec,
                                                   csr_send, csr_recv, ev3);

    for (int l = 0; l < 2; ++l) {
        k_node_prep2<<<(NN + 255) / 256, 256, 0, stream>>>(
            h_s, h_v, w_lin1_s + l * 1024, w_lin1_v + l * 1024, feat);
        hipMemsetAsync(n0b, 0, (size_t)NN * 64 * 4, stream);
        hipMemsetAsync(n1b, 0, (size_t)NN * 192 * 4, stream);
        k_mega<<<EE / 256, 256, 0, stream>>>(
            csr_send, csr_recv, ev3, row_start, feat,
            w0B + l * 512, w1B + l * 4096, w2B + l * 8192, n0b, n1b);
        k_node_update<<<(NN + 255) / 256, 256, 0, stream>>>(
            species, n0b, n1b,
            w_lin2_s + l * 4096, w_lin2_v + l * 2048,
            w_res_s + l * 10240, w_res_v + l * 5120, h_s, h_v);
    }
    k_readout<<<(NN + 255) / 256, 256, 0, stream>>>(h_s, w_out1, w_out2, (float*)d_out);
}

// Round 10
// 1100.281 us; speedup vs baseline: 3.2907x; 1.3609x over previous
//
#include <hip/hip_runtime.h>
#include <math.h>

#define NN 50000
#define EE 800000

typedef float f32x2 __attribute__((ext_vector_type(2)));
typedef float f32x4  __attribute__((ext_vector_type(4)));
typedef float f32x16 __attribute__((ext_vector_type(16)));
typedef short bf16x8 __attribute__((ext_vector_type(8)));

__device__ __forceinline__ float silu_f(float x) {
    return x / (1.f + __expf(-x));
}
__device__ __forceinline__ unsigned short f2bf(float f) {
    unsigned int u = __float_as_uint(f);
    unsigned int r = (u + 0x7fffu + ((u >> 16) & 1u)) >> 16;
    return (unsigned short)r;
}

// ---------------- node embedding ----------------
__global__ void k_embed(const int* __restrict__ species, const float* __restrict__ embed_w,
                        float* __restrict__ h_s, float* __restrict__ h_v) {
    int n = blockIdx.x * 256 + threadIdx.x;
    if (n >= NN) return;
    int sp = species[n];
    const float rs5 = 0.4472135954999579f;
#pragma unroll
    for (int u = 0; u < 32; ++u) h_s[n * 32 + u] = embed_w[sp * 32 + u] * rs5;
#pragma unroll
    for (int t = 0; t < 96; ++t) h_v[n * 96 + t] = 0.f;
}

// ---------------- weights -> bf16 B-fragment layout ----------------
__global__ void k_wtransB(const float* __restrict__ mlp_w0, const float* __restrict__ mlp_w1,
                          const float* __restrict__ mlp_w2,
                          unsigned short* __restrict__ w0B, unsigned short* __restrict__ w1B,
                          unsigned short* __restrict__ w2B) {
    int t = blockIdx.x * 256 + threadIdx.x;
    if (t >= 25600) return;
    int l = t / 12800, r = t % 12800;
    const float rs8 = 0.35355339059327373f;
    if (r < 512) {
        int ct = r >> 7, c = (r >> 3) & 15, i = r & 7;
        w0B[l * 512 + r] = f2bf(mlp_w0[l * 512 + i * 64 + ct * 16 + c] * rs8);
    } else if (r < 4608) {
        int q = r - 512;
        int i = q & 7, lane = (q >> 3) & 63, kt = (q >> 9) & 1, ct = q >> 10;
        int k = kt * 32 + (lane >> 4) * 8 + i;
        int n = ct * 16 + (lane & 15);
        w1B[l * 4096 + q] = f2bf(mlp_w1[l * 4096 + k * 64 + n] * 0.125f);
    } else {
        int q = r - 4608;
        int i = q & 7, lane = (q >> 3) & 63, kt = (q >> 9) & 1, ct = q >> 10;
        int k = kt * 32 + (lane >> 4) * 8 + i;
        int n = ct * 16 + (lane & 15);
        w2B[l * 8192 + q] = f2bf(mlp_w2[l * 8192 + k * 128 + n]);
    }
}

// ---------------- CSR build ----------------
__global__ void k_hist(const int* __restrict__ recv, int* __restrict__ deg) {
    int e = blockIdx.x * 256 + threadIdx.x;
    if (e < EE) atomicAdd(&deg[recv[e]], 1);
}

__global__ void k_scan(const int* __restrict__ deg, int* __restrict__ row_start,
                       int* __restrict__ cursor) {
    __shared__ int part[256];
    int t = threadIdx.x;
    int lo = t * 196, hi = lo + 196 > NN ? NN : lo + 196;
    int s = 0;
#pragma unroll 4
    for (int i = lo; i < hi; ++i) s += deg[i];
    part[t] = s;
    __syncthreads();
    int acc = 0;
    for (int i = 0; i < t; ++i) acc += part[i];
    int run = acc;
    for (int i = lo; i < hi; ++i) {
        row_start[i] = run;
        cursor[i] = run;
        run += deg[i];
    }
    if (t == 255) row_start[NN] = run;
}

__global__ void k_fill(const int* __restrict__ recv, int* __restrict__ cursor,
                       int* __restrict__ csr_edge) {
    int e = blockIdx.x * 256 + threadIdx.x;
    if (e >= EE) return;
    int p = atomicAdd(&cursor[recv[e]], 1);
    csr_edge[p] = e;
}

// ---------------- one-time gather into CSR order ----------------
__global__ void k_gather(const int* __restrict__ csr_edge, const int* __restrict__ senders,
                         const int* __restrict__ receivers, const float* __restrict__ evec,
                         int* __restrict__ csr_send, int* __restrict__ csr_recv,
                         float* __restrict__ ev3) {
    int p = blockIdx.x * 256 + threadIdx.x;
    if (p >= EE) return;
    int e = csr_edge[p];
    csr_send[p] = senders[e];
    csr_recv[p] = receivers[e];
    ev3[p * 3 + 0] = evec[e * 3 + 0];
    ev3[p * 3 + 1] = evec[e * 3 + 1];
    ev3[p * 3 + 2] = evec[e * 3 + 2];
}

// ---------------- lin1 -> feat[n][u][4] = {es, evx, evy, evz}; wave-per-node ----------------
__global__ __launch_bounds__(256) void k_node_prep2(
        const float* __restrict__ h_s, const float* __restrict__ h_v,
        const float* __restrict__ w_lin1_s, const float* __restrict__ w_lin1_v,
        float* __restrict__ feat) {
    int lane = threadIdx.x & 63;
    int n = blockIdx.x * 4 + (threadIdx.x >> 6);
    n = __builtin_amdgcn_readfirstlane(n);
    if (n >= NN) return;
    const float rs32 = 0.17677669529663687f;
    int half = lane >> 5, q = lane & 31;
    const float* hsr = h_s + (size_t)n * 32;
    const float* hvr = h_v + (size_t)n * 96;
    float accA = 0.f, accB = 0.f;
#pragma unroll 8
    for (int u = 0; u < 32; ++u) {
        float ws = w_lin1_s[u * 32 + q];   // coalesced per half-wave
        float wv = w_lin1_v[u * 32 + q];
        float xs = hsr[u];                 // uniform -> s_load
        float xx = hvr[u];
        float xy = hvr[32 + u];
        float xz = hvr[64 + u];
        float inA = half ? xy : xs;
        float wA  = half ? wv : ws;
        float inB = half ? xz : xx;
        accA += inA * wA;
        accB += inB * wv;
    }
    f32x2 o;
    o[0] = accA * rs32;   // half0: S -> +0 ; half1: Y -> +2
    o[1] = accB * rs32;   // half0: X -> +1 ; half1: Z -> +3
    *(f32x2*)(feat + (size_t)n * 128 + q * 4 + half * 2) = o;
}

// ---------------- fused MFMA edge kernel, tree-merged scatter ----------------
#define WROWS 32
#define WSTRIDE 260
__global__ __launch_bounds__(256) void k_mega(
    const int* __restrict__ csr_send, const int* __restrict__ csr_recv,
    const float* __restrict__ ev3, const int* __restrict__ row_start,
    const float* __restrict__ feat,
    const unsigned short* __restrict__ w0B, const unsigned short* __restrict__ w1B,
    const unsigned short* __restrict__ w2B,
    float* __restrict__ n0, float* __restrict__ n1) {
    __shared__ f32x4 accw4[WROWS * WSTRIDE / 4];
    __shared__ unsigned short lds_ee[256 * 8];
    __shared__ f32x4 lds_esh[256];      // {shx,shy,shz,bitcast(snd)}
    __shared__ int lds_wd[256];
    __shared__ unsigned short abuf[4][16 * 72];
    __shared__ int sh_base, sh_last;
    float* accw = (float*)accw4;

    int tid = threadIdx.x;
    int p0 = blockIdx.x * 256;
    int lane = tid & 63;
    int wv = tid >> 6;
    int c0 = lane & 15;
    int rg = lane >> 4;

    for (int i = tid; i < WROWS * WSTRIDE / 4; i += 256) accw4[i] = (f32x4)0.f;

    // ---- phase 0: per-edge geometry -> LDS ----
    int snd0 = csr_send[p0 + tid];
    int rv = csr_recv[p0 + tid];
    if (tid == 0)   sh_base = rv;
    if (tid == 255) sh_last = rv;
    {
        float x = ev3[(p0 + tid) * 3 + 0], y = ev3[(p0 + tid) * 3 + 1], z = ev3[(p0 + tid) * 3 + 2];
        float r = sqrtf(x * x + y * y + z * z + 1e-12f);
        float ir = 1.f / r;
        const float s3 = 1.7320508075688772f;
        float xx = r * 0.2f;
        float env = 0.f;
        if (xx < 1.f) {
            float x2 = xx * xx, x3 = x2 * xx, x6 = x3 * x3, x7 = x6 * xx, x8 = x7 * xx;
            env = 1.f - 28.f * x6 + 48.f * x7 - 21.f * x8;
        }
        float coef = 0.6324555320336759f * env * ir;
        const float w5 = 0.6283185307179586f;
        bf16x8 ee;
#pragma unroll
        for (int k = 0; k < 8; ++k)
            ee[k] = (short)f2bf(coef * __sinf(w5 * (float)(k + 1) * r));
        *(bf16x8*)(lds_ee + tid * 8) = ee;
        f32x4 esh;
        esh[0] = s3 * x * ir;
        esh[1] = s3 * y * ir;
        esh[2] = s3 * z * ir;
        esh[3] = __int_as_float(snd0);
        lds_esh[tid] = esh;
    }
    __syncthreads();
    int node_base = sh_base;
    lds_wd[tid] = rv - node_base;   // consumed only by same wave's lanes

    bf16x8 w0f[4];
#pragma unroll
    for (int ct = 0; ct < 4; ++ct)
        w0f[ct] = (rg == 0) ? *(const bf16x8*)(w0B + (ct * 16 + c0) * 8) : (bf16x8)(short)0;
    const bf16x8* w1f = (const bf16x8*)w1B;
    const bf16x8* w2f = (const bf16x8*)w2B;

    const f32x4* feat4 = (const f32x4*)feat;
    const float rs3 = 0.5773502691896258f;
    unsigned short* ab = abuf[wv];
    const f32x4 cz = (f32x4)0.f;

    for (int t = 0; t < 4; ++t) {
        int tOff = wv * 64 + t * 16;

        // ---- gemm1: EE @ W0 ----
        bf16x8 aee = (rg == 0) ? *(const bf16x8*)(lds_ee + (tOff + c0) * 8) : (bf16x8)(short)0;
        f32x4 C1[4];
#pragma unroll
        for (int ct = 0; ct < 4; ++ct)
            C1[ct] = __builtin_amdgcn_mfma_f32_16x16x32_bf16(aee, w0f[ct], cz, 0, 0, 0);
#pragma unroll
        for (int ct = 0; ct < 4; ++ct)
#pragma unroll
            for (int j = 0; j < 4; ++j)
                ab[(rg * 4 + j) * 72 + ct * 16 + c0] = f2bf(silu_f(C1[ct][j]));

        // ---- gemm2: A1 @ W1 ----
        bf16x8 A10 = *(const bf16x8*)(ab + c0 * 72 + rg * 8);
        bf16x8 A11 = *(const bf16x8*)(ab + c0 * 72 + 32 + rg * 8);
        f32x4 C2[4];
#pragma unroll
        for (int ct = 0; ct < 4; ++ct) {
            f32x4 c = __builtin_amdgcn_mfma_f32_16x16x32_bf16(A10, w1f[(ct * 2 + 0) * 64 + lane], cz, 0, 0, 0);
            C2[ct]  = __builtin_amdgcn_mfma_f32_16x16x32_bf16(A11, w1f[(ct * 2 + 1) * 64 + lane], c, 0, 0, 0);
        }
#pragma unroll
        for (int ct = 0; ct < 4; ++ct)
#pragma unroll
            for (int j = 0; j < 4; ++j)
                ab[(rg * 4 + j) * 72 + ct * 16 + c0] = f2bf(silu_f(C2[ct][j]));

        // ---- gemm3: A2 @ W2 -> D ----
        bf16x8 A20 = *(const bf16x8*)(ab + c0 * 72 + rg * 8);
        bf16x8 A21 = *(const bf16x8*)(ab + c0 * 72 + 32 + rg * 8);
        f32x4 C3[8];
#pragma unroll
        for (int ct = 0; ct < 8; ++ct) {
            f32x4 c = __builtin_amdgcn_mfma_f32_16x16x32_bf16(A20, w2f[(ct * 2 + 0) * 64 + lane], cz, 0, 0, 0);
            C3[ct]  = __builtin_amdgcn_mfma_f32_16x16x32_bf16(A21, w2f[(ct * 2 + 1) * 64 + lane], c, 0, 0, 0);
        }

        // ---- per-lane edge data for this tile (4 edges of my rg group) ----
        f32x4 eshv[4];
        int wr[4];
#pragma unroll
        for (int j = 0; j < 4; ++j) {
            int idx = tOff + rg * 4 + j;
            eshv[j] = lds_esh[idx];
            wr[j] = lds_wd[idx];
        }

        // ---- TP + run-length pre-reduced, cross-group-merged scatter ----
#pragma unroll
        for (int b = 0; b < 2; ++b) {
            int u = b * 16 + c0;
            float s0 = 0.f, s1 = 0.f, s2 = 0.f, s3v = 0.f;
            float s4 = 0.f, s5 = 0.f, s6 = 0.f, s7 = 0.f;
            int curw = wr[0];
            auto emit = [&](int wrow) {
                if (wrow < WROWS) {
                    float* arow = accw + wrow * WSTRIDE;
                    atomicAdd(arow + u, s0);
                    atomicAdd(arow + 32 + u, s1);
                    atomicAdd(arow + 64 + u, s2);
                    atomicAdd(arow + 96 + u, s3v);
                    atomicAdd(arow + 128 + u, s4);
                    atomicAdd(arow + 160 + u, s5);
                    atomicAdd(arow + 192 + u, s6);
                    atomicAdd(arow + 224 + u, s7);
                } else {
                    int rvn = node_base + wrow;
                    float* n0r = n0 + (size_t)rvn * 64;
                    float* n1r = n1 + (size_t)rvn * 192;
                    atomicAdd(n0r + u, s0);
                    atomicAdd(n0r + 32 + u, s1);
                    atomicAdd(n1r + u, s2);
                    atomicAdd(n1r + 32 + u, s3v);
                    atomicAdd(n1r + 64 + u, s4);
                    atomicAdd(n1r + 96 + u, s5);
                    atomicAdd(n1r + 128 + u, s6);
                    atomicAdd(n1r + 160 + u, s7);
                }
            };
#pragma unroll
            for (int j = 0; j < 4; ++j) {
                f32x4 esh = eshv[j];
                int s = __float_as_int(esh[3]);
                int wrow = wr[j];
                f32x4 f4 = feat4[(size_t)s * 32 + u];
                float d1 = C3[0 + b][j], d2 = C3[2 + b][j];
                float d3 = C3[4 + b][j], d4 = C3[6 + b][j];
                float es = f4[0], ev0 = f4[1], ev1 = f4[2], ev2 = f4[3];
                float dot = ev0 * esh[0] + ev1 * esh[1] + ev2 * esh[2];
                float t3 = d3 * es;
                if (j > 0 && wrow != curw) {
                    emit(curw);
                    s0 = s1 = s2 = s3v = s4 = s5 = s6 = s7 = 0.f;
                    curw = wrow;
                }
                s0  += d1 * es;
                s1  += d2 * dot * rs3;
                s2  += t3 * esh[0];
                s3v += d4 * ev0;
                s4  += t3 * esh[1];
                s5  += d4 * ev1;
                s6  += t3 * esh[2];
                s7  += d4 * ev2;
            }
            // tree-merge final runs across the 4 rg groups (receiver-sorted => exact)
            int alive = 1;
            {
                int pw = __shfl_xor(curw, 16);
                float t0 = __shfl_xor(s0, 16), t1 = __shfl_xor(s1, 16);
                float t2 = __shfl_xor(s2, 16), t3m = __shfl_xor(s3v, 16);
                float t4 = __shfl_xor(s4, 16), t5 = __shfl_xor(s5, 16);
                float t6 = __shfl_xor(s6, 16), t7 = __shfl_xor(s7, 16);
                if (pw == curw) {
                    s0 += t0; s1 += t1; s2 += t2; s3v += t3m;
                    s4 += t4; s5 += t5; s6 += t6; s7 += t7;
                    if (lane & 16) alive = 0;
                }
            }
            {
                int pw = __shfl_xor(curw, 32);
                int pal = __shfl_xor(alive, 32);
                float t0 = __shfl_xor(s0, 32), t1 = __shfl_xor(s1, 32);
                float t2 = __shfl_xor(s2, 32), t3m = __shfl_xor(s3v, 32);
                float t4 = __shfl_xor(s4, 32), t5 = __shfl_xor(s5, 32);
                float t6 = __shfl_xor(s6, 32), t7 = __shfl_xor(s7, 32);
                if (alive && pal && pw == curw) {
                    s0 += t0; s1 += t1; s2 += t2; s3v += t3m;
                    s4 += t4; s5 += t5; s6 += t6; s7 += t7;
                    if (lane & 32) alive = 0;
                }
            }
            if (alive) emit(curw);
        }
    }
    __syncthreads();

    // ---- flush window ----
    int span = sh_last - node_base;
    if (span > WROWS - 1) span = WROWS - 1;
    for (int wl = 0; wl <= span; ++wl) {
        int n = node_base + wl;
        float v = accw[wl * WSTRIDE + tid];
        bool interior = (row_start[n] >= p0) && (row_start[n + 1] <= p0 + 256);
        float* dest = (tid < 64) ? (n0 + (size_t)n * 64 + tid) : (n1 + (size_t)n * 192 + (tid - 64));
        if (interior) *dest = v;
        else if (v != 0.f) atomicAdd(dest, v);
    }
}

// ---------------- node update: wave-per-node, lane = channel ----------------
__global__ __launch_bounds__(256) void k_node_update(
        const int* __restrict__ species,
        const float* __restrict__ n0, const float* __restrict__ n1,
        const float* __restrict__ w_lin2_s, const float* __restrict__ w_lin2_v,
        const float* __restrict__ w_res_s, const float* __restrict__ w_res_v,
        float* __restrict__ h_s, float* __restrict__ h_v) {
    int lane = threadIdx.x & 63;
    int n = blockIdx.x * 4 + (threadIdx.x >> 6);
    n = __builtin_amdgcn_readfirstlane(n);
    if (n >= NN) return;
    int sp = __builtin_amdgcn_readfirstlane(species[n]);
    const float sc_l2 = 1.f / 128.f;
    const float rs160 = 0.07905694150420949f;

    // scalar path: lane owns output channel k = lane
    const float* n0r = n0 + (size_t)n * 64;
    float sk = 0.f;
#pragma unroll 8
    for (int j = 0; j < 64; ++j)
        sk += n0r[j] * w_lin2_s[j * 64 + lane];
    sk *= sc_l2;
    const float* hsr = h_s + (size_t)n * 32;
#pragma unroll 8
    for (int u = 0; u < 32; ++u)
        sk += (hsr[u] * rs160) * w_res_s[(u * 5 + sp) * 64 + lane];
    float act = silu_f(sk);
    float gmine = __shfl(act, 32 + (lane & 31));   // gate for channel v = lane&31

    // vector path: lanes cover components {0,1} (i0 = lane>>5) and all lanes also
    // compute component 2 (written by lanes < 32).
    const float* n1r = n1 + (size_t)n * 192;
    const float* hvr = h_v + (size_t)n * 96;
    int i0 = lane >> 5, v = lane & 31;
    float acc0 = 0.f, acc2 = 0.f;
#pragma unroll 8
    for (int u = 0; u < 64; ++u) {
        float wlv = w_lin2_v[u * 32 + v];
        acc0 += n1r[i0 * 64 + u] * wlv;
        acc2 += n1r[128 + u] * wlv;
    }
    acc0 *= sc_l2;
    acc2 *= sc_l2;
#pragma unroll 8
    for (int u = 0; u < 32; ++u) {
        float wrv = w_res_v[(u * 5 + sp) * 32 + v];
        acc0 += (hvr[i0 * 32 + u] * rs160) * wrv;
        acc2 += (hvr[64 + u] * rs160) * wrv;
    }
    // all h_v reads consumed above (register deps force waitcnt) -> safe to write
    h_v[(size_t)n * 96 + i0 * 32 + v] = acc0 * gmine;
    if (lane < 32) {
        h_v[(size_t)n * 96 + 64 + v] = acc2 * gmine;
        h_s[(size_t)n * 32 + v] = act;
    }
}

// ---------------- readout ----------------
__global__ void k_readout(const float* __restrict__ h_s, const float* __restrict__ w_out1,
                          const float* __restrict__ w_out2, float* __restrict__ out) {
    int n = blockIdx.x * 256 + threadIdx.x;
    if (n >= NN) return;
    f32x16 zacc = (f32x16)0.f;
    const float* hsr = h_s + n * 32;
    for (int u = 0; u < 32; ++u) {
        float xv = hsr[u];
        const float* Wr = w_out1 + u * 16;
#pragma unroll
        for (int j = 0; j < 16; ++j) zacc[j] += xv * Wr[j];
    }
    float ev = 0.f;
#pragma unroll
    for (int j = 0; j < 16; ++j) ev += zacc[j] * w_out2[j];
    out[n] = ev * 0.17677669529663687f * 0.25f;
}

extern "C" void kernel_launch(void* const* d_in, const int* in_sizes, int n_in,
                              void* d_out, int out_size, void* d_ws, size_t ws_size,
                              hipStream_t stream) {
    const float* evec     = (const float*)d_in[0];
    const int*   species  = (const int*)d_in[1];
    const int*   senders  = (const int*)d_in[2];
    const int*   receivers= (const int*)d_in[3];
    const float* embed_w  = (const float*)d_in[4];
    const float* w_res_s  = (const float*)d_in[5];
    const float* w_res_v  = (const float*)d_in[6];
    const float* w_lin1_s = (const float*)d_in[7];
    const float* w_lin1_v = (const float*)d_in[8];
    const float* mlp_w0   = (const float*)d_in[9];
    const float* mlp_w1   = (const float*)d_in[10];
    const float* mlp_w2   = (const float*)d_in[11];
    const float* w_lin2_s = (const float*)d_in[12];
    const float* w_lin2_v = (const float*)d_in[13];
    const float* w_out1   = (const float*)d_in[14];
    const float* w_out2   = (const float*)d_in[15];

    float* ws = (float*)d_ws;
    size_t off = 0;
    auto alloc = [&](size_t n) { float* p = ws + off; off += (n + 3) & ~(size_t)3; return p; };

    float* h_s  = alloc(NN * 32);
    float* h_v  = alloc(NN * 96);
    float* feat = alloc((size_t)NN * 128);
    float* n0b  = alloc(NN * 64);
    float* n1b  = alloc(NN * 192);
    unsigned short* w0B = (unsigned short*)alloc(512);
    unsigned short* w1B = (unsigned short*)alloc(4096);
    unsigned short* w2B = (unsigned short*)alloc(8192);
    int*   deg       = (int*)alloc(NN);
    int*   row_start = (int*)alloc(NN + 1);
    int*   cursor    = (int*)alloc(NN);
    int*   csr_edge  = (int*)alloc(EE);
    int*   csr_send  = (int*)alloc(EE);
    int*   csr_recv  = (int*)alloc(EE);
    float* ev3       = alloc((size_t)EE * 3);

    k_embed<<<(NN + 255) / 256, 256, 0, stream>>>(species, embed_w, h_s, h_v);
    k_wtransB<<<100, 256, 0, stream>>>(mlp_w0, mlp_w1, mlp_w2, w0B, w1B, w2B);

    hipMemsetAsync(deg, 0, NN * 4, stream);
    k_hist<<<(EE + 255) / 256, 256, 0, stream>>>(receivers, deg);
    k_scan<<<1, 256, 0, stream>>>(deg, row_start, cursor);
    k_fill<<<(EE + 255) / 256, 256, 0, stream>>>(receivers, cursor, csr_edge);
    k_gather<<<(EE + 255) / 256, 256, 0, stream>>>(csr_edge, senders, receivers, evec,
                                                   csr_send, csr_recv, ev3);

    for (int l = 0; l < 2; ++l) {
        k_node_prep2<<<12500, 256, 0, stream>>>(
            h_s, h_v, w_lin1_s + l * 1024, w_lin1_v + l * 1024, feat);
        hipMemsetAsync(n0b, 0, (size_t)NN * 64 * 4, stream);
        hipMemsetAsync(n1b, 0, (size_t)NN * 192 * 4, stream);
        k_mega<<<EE / 256, 256, 0, stream>>>(
            csr_send, csr_recv, ev3, row_start, feat,
            w0B + l * 512, w1B + l * 4096, w2B + l * 8192, n0b, n1b);
        k_node_update<<<12500, 256, 0, stream>>>(
            species, n0b, n1b,
            w_lin2_s + l * 4096, w_lin2_v + l * 2048,
            w_res_s + l * 10240, w_res_v + l * 5120, h_s, h_v);
    }
    k_readout<<<(NN + 255) / 256, 256, 0, stream>>>(h_s, w_out1, w_out2, (float*)d_out);
}

// Round 11
// 757.085 us; speedup vs baseline: 4.7824x; 1.4533x over previous
//
#include <hip/hip_runtime.h>
#include <math.h>

#define NN 50000
#define EE 800000

typedef float f32x2 __attribute__((ext_vector_type(2)));
typedef float f32x4  __attribute__((ext_vector_type(4)));
typedef float f32x16 __attribute__((ext_vector_type(16)));
typedef short bf16x8 __attribute__((ext_vector_type(8)));

__device__ __forceinline__ float silu_f(float x) {
    return x / (1.f + __expf(-x));
}
__device__ __forceinline__ unsigned short f2bf(float f) {
    unsigned int u = __float_as_uint(f);
    unsigned int r = (u + 0x7fffu + ((u >> 16) & 1u)) >> 16;
    return (unsigned short)r;
}

// ---------------- node embedding ----------------
__global__ void k_embed(const int* __restrict__ species, const float* __restrict__ embed_w,
                        float* __restrict__ h_s, float* __restrict__ h_v) {
    int n = blockIdx.x * 256 + threadIdx.x;
    if (n >= NN) return;
    int sp = species[n];
    const float rs5 = 0.4472135954999579f;
#pragma unroll
    for (int u = 0; u < 32; ++u) h_s[n * 32 + u] = embed_w[sp * 32 + u] * rs5;
#pragma unroll
    for (int t = 0; t < 96; ++t) h_v[n * 96 + t] = 0.f;
}

// ---------------- weights -> bf16 B-fragment layout ----------------
__global__ void k_wtransB(const float* __restrict__ mlp_w0, const float* __restrict__ mlp_w1,
                          const float* __restrict__ mlp_w2,
                          unsigned short* __restrict__ w0B, unsigned short* __restrict__ w1B,
                          unsigned short* __restrict__ w2B) {
    int t = blockIdx.x * 256 + threadIdx.x;
    if (t >= 25600) return;
    int l = t / 12800, r = t % 12800;
    const float rs8 = 0.35355339059327373f;
    if (r < 512) {
        int ct = r >> 7, c = (r >> 3) & 15, i = r & 7;
        w0B[l * 512 + r] = f2bf(mlp_w0[l * 512 + i * 64 + ct * 16 + c] * rs8);
    } else if (r < 4608) {
        int q = r - 512;
        int i = q & 7, lane = (q >> 3) & 63, kt = (q >> 9) & 1, ct = q >> 10;
        int k = kt * 32 + (lane >> 4) * 8 + i;
        int n = ct * 16 + (lane & 15);
        w1B[l * 4096 + q] = f2bf(mlp_w1[l * 4096 + k * 64 + n] * 0.125f);
    } else {
        int q = r - 4608;
        int i = q & 7, lane = (q >> 3) & 63, kt = (q >> 9) & 1, ct = q >> 10;
        int k = kt * 32 + (lane >> 4) * 8 + i;
        int n = ct * 16 + (lane & 15);
        w2B[l * 8192 + q] = f2bf(mlp_w2[l * 8192 + k * 128 + n]);
    }
}

// ---------------- CSR build ----------------
__global__ void k_hist(const int* __restrict__ recv, int* __restrict__ deg) {
    int e = blockIdx.x * 256 + threadIdx.x;
    if (e < EE) atomicAdd(&deg[recv[e]], 1);
}

__global__ void k_scan(const int* __restrict__ deg, int* __restrict__ row_start,
                       int* __restrict__ cursor) {
    __shared__ int part[256];
    int t = threadIdx.x;
    int lo = t * 196, hi = lo + 196 > NN ? NN : lo + 196;
    int s = 0;
#pragma unroll 4
    for (int i = lo; i < hi; ++i) s += deg[i];
    part[t] = s;
    __syncthreads();
    int acc = 0;
    for (int i = 0; i < t; ++i) acc += part[i];
    int run = acc;
    for (int i = lo; i < hi; ++i) {
        row_start[i] = run;
        cursor[i] = run;
        run += deg[i];
    }
    if (t == 255) row_start[NN] = run;
}

__global__ void k_fill(const int* __restrict__ recv, int* __restrict__ cursor,
                       int* __restrict__ csr_edge) {
    int e = blockIdx.x * 256 + threadIdx.x;
    if (e >= EE) return;
    int p = atomicAdd(&cursor[recv[e]], 1);
    csr_edge[p] = e;
}

// ---------------- one-time gather into CSR order ----------------
__global__ void k_gather(const int* __restrict__ csr_edge, const int* __restrict__ senders,
                         const int* __restrict__ receivers, const float* __restrict__ evec,
                         int* __restrict__ csr_send, int* __restrict__ csr_recv,
                         float* __restrict__ ev3) {
    int p = blockIdx.x * 256 + threadIdx.x;
    if (p >= EE) return;
    int e = csr_edge[p];
    csr_send[p] = senders[e];
    csr_recv[p] = receivers[e];
    ev3[p * 3 + 0] = evec[e * 3 + 0];
    ev3[p * 3 + 1] = evec[e * 3 + 1];
    ev3[p * 3 + 2] = evec[e * 3 + 2];
}

// ---------------- lin1 -> feat[n][u][4] = {es, evx, evy, evz}; wave-per-node ----------------
__global__ __launch_bounds__(256) void k_node_prep2(
        const float* __restrict__ h_s, const float* __restrict__ h_v,
        const float* __restrict__ w_lin1_s, const float* __restrict__ w_lin1_v,
        float* __restrict__ feat) {
    int lane = threadIdx.x & 63;
    int n = blockIdx.x * 4 + (threadIdx.x >> 6);
    n = __builtin_amdgcn_readfirstlane(n);
    if (n >= NN) return;
    const float rs32 = 0.17677669529663687f;
    int half = lane >> 5, q = lane & 31;
    const float* hsr = h_s + (size_t)n * 32;
    const float* hvr = h_v + (size_t)n * 96;
    float accA = 0.f, accB = 0.f;
#pragma unroll 8
    for (int u = 0; u < 32; ++u) {
        float ws = w_lin1_s[u * 32 + q];
        float wv = w_lin1_v[u * 32 + q];
        float xs = hsr[u];
        float xx = hvr[u];
        float xy = hvr[32 + u];
        float xz = hvr[64 + u];
        float inA = half ? xy : xs;
        float wA  = half ? wv : ws;
        float inB = half ? xz : xx;
        accA += inA * wA;
        accB += inB * wv;
    }
    f32x2 o;
    o[0] = accA * rs32;
    o[1] = accB * rs32;
    *(f32x2*)(feat + (size_t)n * 128 + q * 4 + half * 2) = o;
}

// ---------------- fused MFMA edge kernel, layer-specialized ----------------
// L=0: h_v==0 -> only channels {o0a -> n0[u], o1a(x,y,z) -> n1[u],[64+u],[128+u]}; d1,d3 only.
// L=1: last layer, 1o output dead -> only {o0a -> n0[u], o0b -> n0[32+u]}; d1,d2 only.
#define WROWS 20
#define WSTRIDE 260
template<int L>
__global__ __launch_bounds__(256) void k_mega(
    const int* __restrict__ csr_send, const int* __restrict__ csr_recv,
    const float* __restrict__ ev3, const int* __restrict__ row_start,
    const float* __restrict__ feat,
    const unsigned short* __restrict__ w0B, const unsigned short* __restrict__ w1B,
    const unsigned short* __restrict__ w2B,
    float* __restrict__ n0, float* __restrict__ n1) {
    __shared__ f32x4 accw4[WROWS * WSTRIDE / 4];      // 20.8 KB
    __shared__ unsigned short lds_ee[256 * 8];
    __shared__ f32x4 lds_esh[256];      // {shx,shy,shz,bitcast(snd)}
    __shared__ int lds_wd[256];
    __shared__ unsigned short abuf[4][16 * 72];
    __shared__ int sh_base, sh_last;
    float* accw = (float*)accw4;

    int tid = threadIdx.x;
    int p0 = blockIdx.x * 256;
    int lane = tid & 63;
    int wv = tid >> 6;
    int c0 = lane & 15;
    int rg = lane >> 4;

    for (int i = tid; i < WROWS * WSTRIDE / 4; i += 256) accw4[i] = (f32x4)0.f;

    // ---- phase 0: per-edge geometry -> LDS ----
    int snd0 = csr_send[p0 + tid];
    int rv = csr_recv[p0 + tid];
    if (tid == 0)   sh_base = rv;
    if (tid == 255) sh_last = rv;
    {
        float x = ev3[(p0 + tid) * 3 + 0], y = ev3[(p0 + tid) * 3 + 1], z = ev3[(p0 + tid) * 3 + 2];
        float r = sqrtf(x * x + y * y + z * z + 1e-12f);
        float ir = 1.f / r;
        const float s3 = 1.7320508075688772f;
        float xx = r * 0.2f;
        float env = 0.f;
        if (xx < 1.f) {
            float x2 = xx * xx, x3 = x2 * xx, x6 = x3 * x3, x7 = x6 * xx, x8 = x7 * xx;
            env = 1.f - 28.f * x6 + 48.f * x7 - 21.f * x8;
        }
        float coef = 0.6324555320336759f * env * ir;
        const float w5 = 0.6283185307179586f;
        bf16x8 ee;
#pragma unroll
        for (int k = 0; k < 8; ++k)
            ee[k] = (short)f2bf(coef * __sinf(w5 * (float)(k + 1) * r));
        *(bf16x8*)(lds_ee + tid * 8) = ee;
        f32x4 esh;
        esh[0] = s3 * x * ir;
        esh[1] = s3 * y * ir;
        esh[2] = s3 * z * ir;
        esh[3] = __int_as_float(snd0);
        lds_esh[tid] = esh;
    }
    __syncthreads();
    int node_base = sh_base;
    lds_wd[tid] = rv - node_base;

    bf16x8 w0f[4];
#pragma unroll
    for (int ct = 0; ct < 4; ++ct)
        w0f[ct] = (rg == 0) ? *(const bf16x8*)(w0B + (ct * 16 + c0) * 8) : (bf16x8)(short)0;
    const bf16x8* w1f = (const bf16x8*)w1B;
    const bf16x8* w2f = (const bf16x8*)w2B;

    const float rs3 = 0.5773502691896258f;
    unsigned short* ab = abuf[wv];
    const f32x4 cz = (f32x4)0.f;

    for (int t = 0; t < 4; ++t) {
        int tOff = wv * 64 + t * 16;

        // ---- gemm1: EE @ W0 ----
        bf16x8 aee = (rg == 0) ? *(const bf16x8*)(lds_ee + (tOff + c0) * 8) : (bf16x8)(short)0;
        f32x4 C1[4];
#pragma unroll
        for (int ct = 0; ct < 4; ++ct)
            C1[ct] = __builtin_amdgcn_mfma_f32_16x16x32_bf16(aee, w0f[ct], cz, 0, 0, 0);
#pragma unroll
        for (int ct = 0; ct < 4; ++ct)
#pragma unroll
            for (int j = 0; j < 4; ++j)
                ab[(rg * 4 + j) * 72 + ct * 16 + c0] = f2bf(silu_f(C1[ct][j]));

        // ---- gemm2: A1 @ W1 ----
        bf16x8 A10 = *(const bf16x8*)(ab + c0 * 72 + rg * 8);
        bf16x8 A11 = *(const bf16x8*)(ab + c0 * 72 + 32 + rg * 8);
        f32x4 C2[4];
#pragma unroll
        for (int ct = 0; ct < 4; ++ct) {
            f32x4 c = __builtin_amdgcn_mfma_f32_16x16x32_bf16(A10, w1f[(ct * 2 + 0) * 64 + lane], cz, 0, 0, 0);
            C2[ct]  = __builtin_amdgcn_mfma_f32_16x16x32_bf16(A11, w1f[(ct * 2 + 1) * 64 + lane], c, 0, 0, 0);
        }
#pragma unroll
        for (int ct = 0; ct < 4; ++ct)
#pragma unroll
            for (int j = 0; j < 4; ++j)
                ab[(rg * 4 + j) * 72 + ct * 16 + c0] = f2bf(silu_f(C2[ct][j]));

        // ---- gemm3: A2 @ W2 -> only the live D halves ----
        bf16x8 A20 = *(const bf16x8*)(ab + c0 * 72 + rg * 8);
        bf16x8 A21 = *(const bf16x8*)(ab + c0 * 72 + 32 + rg * 8);
        f32x4 DA[2], DB[2];   // L0: DA=d1(ct0,1) DB=d3(ct4,5); L1: DA=d1 DB=d2(ct2,3)
#pragma unroll
        for (int b = 0; b < 2; ++b) {
            int ctA = b;
            int ctB = (L == 0) ? (4 + b) : (2 + b);
            f32x4 ca = __builtin_amdgcn_mfma_f32_16x16x32_bf16(A20, w2f[(ctA * 2 + 0) * 64 + lane], cz, 0, 0, 0);
            DA[b]    = __builtin_amdgcn_mfma_f32_16x16x32_bf16(A21, w2f[(ctA * 2 + 1) * 64 + lane], ca, 0, 0, 0);
            f32x4 cb = __builtin_amdgcn_mfma_f32_16x16x32_bf16(A20, w2f[(ctB * 2 + 0) * 64 + lane], cz, 0, 0, 0);
            DB[b]    = __builtin_amdgcn_mfma_f32_16x16x32_bf16(A21, w2f[(ctB * 2 + 1) * 64 + lane], cb, 0, 0, 0);
        }

        // ---- per-lane edge data ----
        f32x4 eshv[4];
        int wr[4];
#pragma unroll
        for (int j = 0; j < 4; ++j) {
            int idx = tOff + rg * 4 + j;
            eshv[j] = lds_esh[idx];
            wr[j] = lds_wd[idx];
        }

        // ---- TP + run-length + tree-merged scatter ----
#pragma unroll
        for (int b = 0; b < 2; ++b) {
            int u = b * 16 + c0;
            float s0 = 0.f, s1 = 0.f, s2 = 0.f, s3v = 0.f;
            int curw = wr[0];
            auto emit = [&](int wrow) {
                if (L == 0) {
                    if (wrow < WROWS) {
                        float* arow = accw + wrow * WSTRIDE;
                        atomicAdd(arow + u, s0);
                        atomicAdd(arow + 64 + u, s1);
                        atomicAdd(arow + 128 + u, s2);
                        atomicAdd(arow + 192 + u, s3v);
                    } else {
                        int rvn = node_base + wrow;
                        atomicAdd(n0 + (size_t)rvn * 64 + u, s0);
                        atomicAdd(n1 + (size_t)rvn * 192 + u, s1);
                        atomicAdd(n1 + (size_t)rvn * 192 + 64 + u, s2);
                        atomicAdd(n1 + (size_t)rvn * 192 + 128 + u, s3v);
                    }
                } else {
                    if (wrow < WROWS) {
                        float* arow = accw + wrow * WSTRIDE;
                        atomicAdd(arow + u, s0);
                        atomicAdd(arow + 32 + u, s1);
                    } else {
                        int rvn = node_base + wrow;
                        atomicAdd(n0 + (size_t)rvn * 64 + u, s0);
                        atomicAdd(n0 + (size_t)rvn * 64 + 32 + u, s1);
                    }
                }
            };
#pragma unroll
            for (int j = 0; j < 4; ++j) {
                f32x4 esh = eshv[j];
                int s = __float_as_int(esh[3]);
                int wrow = wr[j];
                if (j > 0 && wrow != curw) {
                    emit(curw);
                    s0 = s1 = s2 = s3v = 0.f;
                    curw = wrow;
                }
                if (L == 0) {
                    float es = feat[(size_t)s * 128 + u * 4];   // vec parts are zero
                    float d1 = DA[b][j], d3 = DB[b][j];
                    float t3 = d3 * es;
                    s0  += d1 * es;
                    s1  += t3 * esh[0];
                    s2  += t3 * esh[1];
                    s3v += t3 * esh[2];
                } else {
                    f32x4 f4 = *(const f32x4*)(feat + (size_t)s * 128 + u * 4);
                    float d1 = DA[b][j], d2 = DB[b][j];
                    float dot = f4[1] * esh[0] + f4[2] * esh[1] + f4[3] * esh[2];
                    s0 += d1 * f4[0];
                    s1 += d2 * dot * rs3;
                }
            }
            // tree-merge final runs across the 4 rg groups
            int alive = 1;
            {
                int pw = __shfl_xor(curw, 16);
                float t0 = __shfl_xor(s0, 16), t1 = __shfl_xor(s1, 16);
                float t2 = __shfl_xor(s2, 16), t3m = __shfl_xor(s3v, 16);
                if (pw == curw) {
                    s0 += t0; s1 += t1;
                    if (L == 0) { s2 += t2; s3v += t3m; }
                    if (lane & 16) alive = 0;
                }
            }
            {
                int pw = __shfl_xor(curw, 32);
                int pal = __shfl_xor(alive, 32);
                float t0 = __shfl_xor(s0, 32), t1 = __shfl_xor(s1, 32);
                float t2 = __shfl_xor(s2, 32), t3m = __shfl_xor(s3v, 32);
                if (alive && pal && pw == curw) {
                    s0 += t0; s1 += t1;
                    if (L == 0) { s2 += t2; s3v += t3m; }
                    if (lane & 32) alive = 0;
                }
            }
            if (alive) emit(curw);
        }
    }
    __syncthreads();

    // ---- flush window ----
    int span = sh_last - node_base;
    if (span > WROWS - 1) span = WROWS - 1;
    for (int wl = 0; wl <= span; ++wl) {
        int n = node_base + wl;
        float v = accw[wl * WSTRIDE + tid];
        bool interior = (row_start[n] >= p0) && (row_start[n + 1] <= p0 + 256);
        if (L == 1) {
            if (tid < 64) {
                float* dest = n0 + (size_t)n * 64 + tid;
                if (interior) *dest = v;
                else if (v != 0.f) atomicAdd(dest, v);
            }
        } else {
            float* dest = (tid < 64) ? (n0 + (size_t)n * 64 + tid) : (n1 + (size_t)n * 192 + (tid - 64));
            if (interior) *dest = v;
            else if (v != 0.f) atomicAdd(dest, v);
        }
    }
}

// ---------------- node update (layer 0): wave-per-node, lane = channel ----------------
__global__ __launch_bounds__(256) void k_node_update(
        const int* __restrict__ species,
        const float* __restrict__ n0, const float* __restrict__ n1,
        const float* __restrict__ w_lin2_s, const float* __restrict__ w_lin2_v,
        const float* __restrict__ w_res_s, const float* __restrict__ w_res_v,
        float* __restrict__ h_s, float* __restrict__ h_v) {
    int lane = threadIdx.x & 63;
    int n = blockIdx.x * 4 + (threadIdx.x >> 6);
    n = __builtin_amdgcn_readfirstlane(n);
    if (n >= NN) return;
    int sp = __builtin_amdgcn_readfirstlane(species[n]);
    const float sc_l2 = 1.f / 128.f;
    const float rs160 = 0.07905694150420949f;

    const float* n0r = n0 + (size_t)n * 64;
    float sk = 0.f;
#pragma unroll 8
    for (int j = 0; j < 64; ++j)
        sk += n0r[j] * w_lin2_s[j * 64 + lane];
    sk *= sc_l2;
    const float* hsr = h_s + (size_t)n * 32;
#pragma unroll 8
    for (int u = 0; u < 32; ++u)
        sk += (hsr[u] * rs160) * w_res_s[(u * 5 + sp) * 64 + lane];
    float act = silu_f(sk);
    float gmine = __shfl(act, 32 + (lane & 31));

    const float* n1r = n1 + (size_t)n * 192;
    const float* hvr = h_v + (size_t)n * 96;
    int i0 = lane >> 5, v = lane & 31;
    float acc0 = 0.f, acc2 = 0.f;
#pragma unroll 8
    for (int u = 0; u < 64; ++u) {
        float wlv = w_lin2_v[u * 32 + v];
        acc0 += n1r[i0 * 64 + u] * wlv;
        acc2 += n1r[128 + u] * wlv;
    }
    acc0 *= sc_l2;
    acc2 *= sc_l2;
#pragma unroll 8
    for (int u = 0; u < 32; ++u) {
        float wrv = w_res_v[(u * 5 + sp) * 32 + v];
        acc0 += (hvr[i0 * 32 + u] * rs160) * wrv;
        acc2 += (hvr[64 + u] * rs160) * wrv;
    }
    h_v[(size_t)n * 96 + i0 * 32 + v] = acc0 * gmine;
    if (lane < 32) {
        h_v[(size_t)n * 96 + 64 + v] = acc2 * gmine;
        h_s[(size_t)n * 32 + v] = act;
    }
}

// ---------------- final node update: scalar-only + fused readout ----------------
__global__ __launch_bounds__(256) void k_node_update_last(
        const int* __restrict__ species,
        const float* __restrict__ n0,
        const float* __restrict__ w_lin2_s, const float* __restrict__ w_res_s,
        const float* __restrict__ h_s,
        const float* __restrict__ w_out1, const float* __restrict__ w_out2,
        float* __restrict__ out) {
    int lane = threadIdx.x & 63;
    int n = blockIdx.x * 4 + (threadIdx.x >> 6);
    n = __builtin_amdgcn_readfirstlane(n);
    if (n >= NN) return;
    if (lane >= 32) return;
    int sp = __builtin_amdgcn_readfirstlane(species[n]);
    const float sc_l2 = 1.f / 128.f;
    const float rs160 = 0.07905694150420949f;

    const float* n0r = n0 + (size_t)n * 64;
    float sk = 0.f;
#pragma unroll 8
    for (int j = 0; j < 64; ++j)
        sk += n0r[j] * w_lin2_s[j * 64 + lane];
    sk *= sc_l2;
    const float* hsr = h_s + (size_t)n * 32;
#pragma unroll 8
    for (int u = 0; u < 32; ++u)
        sk += (hsr[u] * rs160) * w_res_s[(u * 5 + sp) * 64 + lane];
    float act = silu_f(sk);

    // wc[v] = sum_j w_out1[v][j] * w_out2[j]
    float wc = 0.f;
#pragma unroll
    for (int j = 0; j < 16; ++j)
        wc += w_out1[lane * 16 + j] * w_out2[j];
    float e = act * wc;
    e += __shfl_xor(e, 1);
    e += __shfl_xor(e, 2);
    e += __shfl_xor(e, 4);
    e += __shfl_xor(e, 8);
    e += __shfl_xor(e, 16);
    if (lane == 0)
        out[n] = e * 0.17677669529663687f * 0.25f; // 1/sqrt(32) * 1/sqrt(16)
}

extern "C" void kernel_launch(void* const* d_in, const int* in_sizes, int n_in,
                              void* d_out, int out_size, void* d_ws, size_t ws_size,
                              hipStream_t stream) {
    const float* evec     = (const float*)d_in[0];
    const int*   species  = (const int*)d_in[1];
    const int*   senders  = (const int*)d_in[2];
    const int*   receivers= (const int*)d_in[3];
    const float* embed_w  = (const float*)d_in[4];
    const float* w_res_s  = (const float*)d_in[5];
    const float* w_res_v  = (const float*)d_in[6];
    const float* w_lin1_s = (const float*)d_in[7];
    const float* w_lin1_v = (const float*)d_in[8];
    const float* mlp_w0   = (const float*)d_in[9];
    const float* mlp_w1   = (const float*)d_in[10];
    const float* mlp_w2   = (const float*)d_in[11];
    const float* w_lin2_s = (const float*)d_in[12];
    const float* w_lin2_v = (const float*)d_in[13];
    const float* w_out1   = (const float*)d_in[14];
    const float* w_out2   = (const float*)d_in[15];

    float* ws = (float*)d_ws;
    size_t off = 0;
    auto alloc = [&](size_t n) { float* p = ws + off; off += (n + 3) & ~(size_t)3; return p; };

    float* h_s  = alloc(NN * 32);
    float* h_v  = alloc(NN * 96);
    float* feat = alloc((size_t)NN * 128);
    float* n0b  = alloc(NN * 64);      // n0b and n1b contiguous
    float* n1b  = alloc(NN * 192);
    unsigned short* w0B = (unsigned short*)alloc(512);
    unsigned short* w1B = (unsigned short*)alloc(4096);
    unsigned short* w2B = (unsigned short*)alloc(8192);
    int*   deg       = (int*)alloc(NN);
    int*   row_start = (int*)alloc(NN + 1);
    int*   cursor    = (int*)alloc(NN);
    int*   csr_edge  = (int*)alloc(EE);
    int*   csr_send  = (int*)alloc(EE);
    int*   csr_recv  = (int*)alloc(EE);
    float* ev3       = alloc((size_t)EE * 3);

    k_embed<<<(NN + 255) / 256, 256, 0, stream>>>(species, embed_w, h_s, h_v);
    k_wtransB<<<100, 256, 0, stream>>>(mlp_w0, mlp_w1, mlp_w2, w0B, w1B, w2B);

    hipMemsetAsync(deg, 0, NN * 4, stream);
    k_hist<<<(EE + 255) / 256, 256, 0, stream>>>(receivers, deg);
    k_scan<<<1, 256, 0, stream>>>(deg, row_start, cursor);
    k_fill<<<(EE + 255) / 256, 256, 0, stream>>>(receivers, cursor, csr_edge);
    k_gather<<<(EE + 255) / 256, 256, 0, stream>>>(csr_edge, senders, receivers, evec,
                                                   csr_send, csr_recv, ev3);

    // ---- layer 0 ----
    k_node_prep2<<<12500, 256, 0, stream>>>(
        h_s, h_v, w_lin1_s, w_lin1_v, feat);
    hipMemsetAsync(n0b, 0, (size_t)NN * 256 * 4, stream);   // n0b + n1b contiguous
    k_mega<0><<<EE / 256, 256, 0, stream>>>(
        csr_send, csr_recv, ev3, row_start, feat,
        w0B, w1B, w2B, n0b, n1b);
    k_node_update<<<12500, 256, 0, stream>>>(
        species, n0b, n1b, w_lin2_s, w_lin2_v,
        w_res_s, w_res_v, h_s, h_v);

    // ---- layer 1 (last): 1o output path is dead ----
    k_node_prep2<<<12500, 256, 0, stream>>>(
        h_s, h_v, w_lin1_s + 1024, w_lin1_v + 1024, feat);
    hipMemsetAsync(n0b, 0, (size_t)NN * 64 * 4, stream);
    k_mega<1><<<EE / 256, 256, 0, stream>>>(
        csr_send, csr_recv, ev3, row_start, feat,
        w0B + 512, w1B + 4096, w2B + 8192, n0b, n1b);
    k_node_update_last<<<12500, 256, 0, stream>>>(
        species, n0b, w_lin2_s + 4096, w_res_s + 10240, h_s,
        w_out1, w_out2, (float*)d_out);
}

// Round 12
// 625.348 us; speedup vs baseline: 5.7899x; 1.2107x over previous
//
#include <hip/hip_runtime.h>
#include <math.h>

#define NN 50000
#define EE 800000
#define TB 8192            // radial table bins; nodes = TB+1 over r in [0,5]

typedef float f32x2 __attribute__((ext_vector_type(2)));
typedef float f32x4  __attribute__((ext_vector_type(4)));
typedef short bf16x8 __attribute__((ext_vector_type(8)));

__device__ __forceinline__ float silu_f(float x) {
    return x / (1.f + __expf(-x));
}

// ---------------- radial MLP -> lookup table (one wave per (layer,bin)) ----------------
// tab0[bin][u] = {w[u],  w[64+u]}  (L0 needs d1,d3)
// tab1[bin][u] = {w[u],  w[32+u]}  (L1 needs d1,d2)
__global__ __launch_bounds__(256) void k_table(
        const float* __restrict__ mlp_w0, const float* __restrict__ mlp_w1,
        const float* __restrict__ mlp_w2,
        float* __restrict__ tab0, float* __restrict__ tab1) {
    __shared__ float stage[4][128];
    int wv = threadIdx.x >> 6, lane = threadIdx.x & 63;
    int wid = blockIdx.x * 4 + wv;
    if (wid > 2 * TB + 1) wid = 2 * TB + 1;   // clamp; duplicate work is benign
    int l = wid / (TB + 1);
    int bin = wid - l * (TB + 1);
    float* st = stage[wv];

    float r = 5.f * (float)bin / (float)TB;
    if (r < 1e-6f) r = 1e-6f;
    float ir = 1.f / r;
    float xx = r * 0.2f;
    float env = 0.f;
    if (xx < 1.f) {
        float x2 = xx * xx, x3 = x2 * xx, x6 = x3 * x3, x7 = x6 * xx, x8 = x7 * xx;
        env = 1.f - 28.f * x6 + 48.f * x7 - 21.f * x8;
    }
    float coef = 0.6324555320336759f * env * ir;   // sqrt(2/5)*env/r
    const float w5 = 0.6283185307179586f;          // pi/5

    // a1 for hidden channel j = lane
    float p = 0.f;
#pragma unroll
    for (int k = 0; k < 8; ++k)
        p += coef * __sinf(w5 * (float)(k + 1) * r) * mlp_w0[l * 512 + k * 64 + lane];
    float a1 = silu_f(p * 0.35355339059327373f);   // /sqrt(8)
    st[lane] = a1;
    __syncthreads();
    float q = 0.f;
    for (int j = 0; j < 64; ++j) q += st[j] * mlp_w1[l * 4096 + j * 64 + lane];
    float a2 = silu_f(q * 0.125f);                 // /sqrt(64)
    __syncthreads();
    st[lane] = a2;
    __syncthreads();
    float wlo = 0.f, whi = 0.f;
    for (int h = 0; h < 64; ++h) {
        float a = st[h];
        wlo += a * mlp_w2[l * 8192 + h * 128 + lane];
        whi += a * mlp_w2[l * 8192 + h * 128 + 64 + lane];
    }
    __syncthreads();
    st[lane] = wlo;        // w[0..63]
    st[64 + lane] = whi;   // w[64..127]
    __syncthreads();
    if (lane < 32) {
        f32x2 o;
        if (l == 0) { o[0] = st[lane]; o[1] = st[64 + lane]; ((f32x2*)tab0)[bin * 32 + lane] = o; }
        else        { o[0] = st[lane]; o[1] = st[32 + lane]; ((f32x2*)tab1)[bin * 32 + lane] = o; }
    }
}

// ---------------- layer-0 edge features: fs[sp][v] = rs5*rs32 * embed[sp] @ w_lin1_s ----
__global__ void k_fs(const float* __restrict__ embed_w, const float* __restrict__ w_lin1_s,
                     float* __restrict__ fs) {
    int t = threadIdx.x;
    if (t >= 160) return;
    int sp = t >> 5, v = t & 31;
    float acc = 0.f;
#pragma unroll
    for (int u = 0; u < 32; ++u) acc += embed_w[sp * 32 + u] * w_lin1_s[u * 32 + v];
    fs[t] = acc * 0.4472135954999579f * 0.17677669529663687f;
}

// ---------------- CSR build ----------------
__global__ void k_hist(const int* __restrict__ recv, int* __restrict__ deg) {
    int e = blockIdx.x * 256 + threadIdx.x;
    if (e < EE) atomicAdd(&deg[recv[e]], 1);
}

__global__ void k_scan(const int* __restrict__ deg, int* __restrict__ row_start,
                       int* __restrict__ cursor) {
    __shared__ int part[256];
    int t = threadIdx.x;
    int lo = t * 196, hi = lo + 196 > NN ? NN : lo + 196;
    int s = 0;
#pragma unroll 4
    for (int i = lo; i < hi; ++i) s += deg[i];
    part[t] = s;
    __syncthreads();
    int acc = 0;
    for (int i = 0; i < t; ++i) acc += part[i];
    int run = acc;
    for (int i = lo; i < hi; ++i) {
        row_start[i] = run;
        cursor[i] = run;
        run += deg[i];
    }
    if (t == 255) row_start[NN] = run;
}

__global__ void k_fill(const int* __restrict__ recv, int* __restrict__ cursor,
                       int* __restrict__ csr_edge) {
    int e = blockIdx.x * 256 + threadIdx.x;
    if (e >= EE) return;
    int p = atomicAdd(&cursor[recv[e]], 1);
    csr_edge[p] = e;
}

// ---------------- one-time gather into CSR order (+ sender species packed) ----------------
__global__ void k_gather(const int* __restrict__ csr_edge, const int* __restrict__ senders,
                         const int* __restrict__ receivers, const int* __restrict__ species,
                         const float* __restrict__ evec,
                         int* __restrict__ csr_send, int* __restrict__ csr_recv,
                         float* __restrict__ ev3) {
    int p = blockIdx.x * 256 + threadIdx.x;
    if (p >= EE) return;
    int e = csr_edge[p];
    int snd = senders[e];
    csr_send[p] = snd | (species[snd] << 24);
    csr_recv[p] = receivers[e];
    ev3[p * 3 + 0] = evec[e * 3 + 0];
    ev3[p * 3 + 1] = evec[e * 3 + 1];
    ev3[p * 3 + 2] = evec[e * 3 + 2];
}

// ---------------- lin1 -> feat[n][u][4] = {es, evx, evy, evz}; wave-per-node (L1 only) ----
__global__ __launch_bounds__(256) void k_node_prep2(
        const float* __restrict__ h_s, const float* __restrict__ h_v,
        const float* __restrict__ w_lin1_s, const float* __restrict__ w_lin1_v,
        float* __restrict__ feat) {
    int lane = threadIdx.x & 63;
    int n = blockIdx.x * 4 + (threadIdx.x >> 6);
    n = __builtin_amdgcn_readfirstlane(n);
    if (n >= NN) return;
    const float rs32 = 0.17677669529663687f;
    int half = lane >> 5, q = lane & 31;
    const float* hsr = h_s + (size_t)n * 32;
    const float* hvr = h_v + (size_t)n * 96;
    float accA = 0.f, accB = 0.f;
#pragma unroll 8
    for (int u = 0; u < 32; ++u) {
        float ws = w_lin1_s[u * 32 + q];
        float wv = w_lin1_v[u * 32 + q];
        float xs = hsr[u];
        float xx = hvr[u];
        float xy = hvr[32 + u];
        float xz = hvr[64 + u];
        float inA = half ? xy : xs;
        float wA  = half ? wv : ws;
        float inB = half ? xz : xx;
        accA += inA * wA;
        accB += inB * wv;
    }
    f32x2 o;
    o[0] = accA * rs32;
    o[1] = accB * rs32;
    *(f32x2*)(feat + (size_t)n * 128 + q * 4 + half * 2) = o;
}

// ---------------- fused table-lookup edge kernel, layer-specialized ----------------
// L=0: es from fs[species] (no feat gather); channels {n0[u], n1[u],[64+u],[128+u]}
// L=1: feat gather;                          channels {n0[u], n0[32+u]}
#define WROWS 24
#define WSTRIDE 260
template<int L>
__global__ __launch_bounds__(256) void k_mega(
    const int* __restrict__ csr_send, const int* __restrict__ csr_recv,
    const float* __restrict__ ev3, const int* __restrict__ row_start,
    const float* __restrict__ fs, const float* __restrict__ feat,
    const float* __restrict__ tab,
    float* __restrict__ n0, float* __restrict__ n1) {
    __shared__ f32x4 accw4[WROWS * WSTRIDE / 4];   // 25 KB
    __shared__ f32x4 lds_esh[256];                 // {shx,shy,shz,bitcast(packed snd)}
    __shared__ float lds_x[256];                   // r * TB/5 (bin+frac)
    __shared__ int lds_wd[256];
    __shared__ int sh_base, sh_last;
    float* accw = (float*)accw4;

    int tid = threadIdx.x;
    int p0 = blockIdx.x * 256;
    int lane = tid & 63;
    int wv = tid >> 6;
    int c0 = lane & 15;
    int rg = lane >> 4;

    for (int i = tid; i < WROWS * WSTRIDE / 4; i += 256) accw4[i] = (f32x4)0.f;

    // ---- phase 0: per-edge geometry -> LDS ----
    int sndp = csr_send[p0 + tid];
    int rv = csr_recv[p0 + tid];
    if (tid == 0)   sh_base = rv;
    if (tid == 255) sh_last = rv;
    {
        float x = ev3[(p0 + tid) * 3 + 0], y = ev3[(p0 + tid) * 3 + 1], z = ev3[(p0 + tid) * 3 + 2];
        float r = sqrtf(x * x + y * y + z * z + 1e-12f);
        float ir = 1.f / r;
        const float s3 = 1.7320508075688772f;
        f32x4 esh;
        esh[0] = s3 * x * ir;
        esh[1] = s3 * y * ir;
        esh[2] = s3 * z * ir;
        esh[3] = __int_as_float(sndp);
        lds_esh[tid] = esh;
        float xb = r * ((float)TB / 5.f);
        if (xb > (float)TB) xb = (float)TB;   // r>=5 -> lerp hits tab[TB] == 0 exactly
        lds_x[tid] = xb;
    }
    __syncthreads();
    int node_base = sh_base;
    lds_wd[tid] = rv - node_base;   // consumed only by same wave's lanes

    const f32x2* tab2 = (const f32x2*)tab;
    const f32x4* feat4 = (const f32x4*)feat;
    const float rs3 = 0.5773502691896258f;

    for (int t = 0; t < 4; ++t) {
        int tOff = wv * 64 + t * 16;

        f32x4 eshv[4];
        int wr[4];
        float xbv[4];
#pragma unroll
        for (int j = 0; j < 4; ++j) {
            int idx = tOff + rg * 4 + j;
            eshv[j] = lds_esh[idx];
            wr[j] = lds_wd[idx];
            xbv[j] = lds_x[idx];
        }

#pragma unroll
        for (int b = 0; b < 2; ++b) {
            int u = b * 16 + c0;
            float s0 = 0.f, s1 = 0.f, s2 = 0.f, s3v = 0.f;
            int curw = wr[0];
            auto emit = [&](int wrow) {
                if (L == 0) {
                    if (wrow < WROWS) {
                        float* arow = accw + wrow * WSTRIDE;
                        atomicAdd(arow + u, s0);
                        atomicAdd(arow + 64 + u, s1);
                        atomicAdd(arow + 128 + u, s2);
                        atomicAdd(arow + 192 + u, s3v);
                    } else {
                        int rvn = node_base + wrow;
                        atomicAdd(n0 + (size_t)rvn * 64 + u, s0);
                        atomicAdd(n1 + (size_t)rvn * 192 + u, s1);
                        atomicAdd(n1 + (size_t)rvn * 192 + 64 + u, s2);
                        atomicAdd(n1 + (size_t)rvn * 192 + 128 + u, s3v);
                    }
                } else {
                    if (wrow < WROWS) {
                        float* arow = accw + wrow * WSTRIDE;
                        atomicAdd(arow + u, s0);
                        atomicAdd(arow + 32 + u, s1);
                    } else {
                        int rvn = node_base + wrow;
                        atomicAdd(n0 + (size_t)rvn * 64 + u, s0);
                        atomicAdd(n0 + (size_t)rvn * 64 + 32 + u, s1);
                    }
                }
            };
#pragma unroll
            for (int j = 0; j < 4; ++j) {
                int wrow = wr[j];
                if (j > 0 && wrow != curw) {
                    emit(curw);
                    s0 = s1 = s2 = s3v = 0.f;
                    curw = wrow;
                }
                f32x4 esh = eshv[j];
                int packed = __float_as_int(esh[3]);
                float xb = xbv[j];
                int bin = (int)xb;
                if (bin >= TB) bin = TB - 1;
                float fr = xb - (float)bin;
                f32x2 wlo = tab2[bin * 32 + u];
                f32x2 whi = tab2[bin * 32 + 32 + u];   // next row, contiguous
                float dA = wlo[0] + fr * (whi[0] - wlo[0]);
                float dB = wlo[1] + fr * (whi[1] - wlo[1]);
                if (L == 0) {
                    int sp = ((unsigned)packed) >> 24;
                    float es = fs[(sp << 5) + u];
                    float t3 = dB * es;
                    s0  += dA * es;
                    s1  += t3 * esh[0];
                    s2  += t3 * esh[1];
                    s3v += t3 * esh[2];
                } else {
                    int s = packed & 0xFFFFFF;
                    f32x4 f4 = feat4[(size_t)s * 32 + u];
                    float dot = f4[1] * esh[0] + f4[2] * esh[1] + f4[3] * esh[2];
                    s0 += dA * f4[0];
                    s1 += dB * dot * rs3;
                }
            }
            // tree-merge final runs across the 4 rg groups (receiver-sorted => exact)
            int alive = 1;
            {
                int pw = __shfl_xor(curw, 16);
                float t0 = __shfl_xor(s0, 16), t1 = __shfl_xor(s1, 16);
                float t2 = __shfl_xor(s2, 16), t3m = __shfl_xor(s3v, 16);
                if (pw == curw) {
                    s0 += t0; s1 += t1;
                    if (L == 0) { s2 += t2; s3v += t3m; }
                    if (lane & 16) alive = 0;
                }
            }
            {
                int pw = __shfl_xor(curw, 32);
                int pal = __shfl_xor(alive, 32);
                float t0 = __shfl_xor(s0, 32), t1 = __shfl_xor(s1, 32);
                float t2 = __shfl_xor(s2, 32), t3m = __shfl_xor(s3v, 32);
                if (alive && pal && pw == curw) {
                    s0 += t0; s1 += t1;
                    if (L == 0) { s2 += t2; s3v += t3m; }
                    if (lane & 32) alive = 0;
                }
            }
            if (alive) emit(curw);
        }
    }
    __syncthreads();

    // ---- flush window ----
    int span = sh_last - node_base;
    if (span > WROWS - 1) span = WROWS - 1;
    for (int wl = 0; wl <= span; ++wl) {
        int n = node_base + wl;
        float v = accw[wl * WSTRIDE + tid];
        bool interior = (row_start[n] >= p0) && (row_start[n + 1] <= p0 + 256);
        if (L == 1) {
            if (tid < 64) {
                float* dest = n0 + (size_t)n * 64 + tid;
                if (interior) *dest = v;
                else if (v != 0.f) atomicAdd(dest, v);
            }
        } else {
            float* dest = (tid < 64) ? (n0 + (size_t)n * 64 + tid) : (n1 + (size_t)n * 192 + (tid - 64));
            if (interior) *dest = v;
            else if (v != 0.f) atomicAdd(dest, v);
        }
    }
}

// ---------------- node update (layer 0): h_v==0 -> residual_v == 0; h_s from embed ----
__global__ __launch_bounds__(256) void k_node_update0(
        const int* __restrict__ species,
        const float* __restrict__ n0, const float* __restrict__ n1,
        const float* __restrict__ w_lin2_s, const float* __restrict__ w_lin2_v,
        const float* __restrict__ w_res_s, const float* __restrict__ embed_w,
        float* __restrict__ h_s, float* __restrict__ h_v) {
    int lane = threadIdx.x & 63;
    int n = blockIdx.x * 4 + (threadIdx.x >> 6);
    n = __builtin_amdgcn_readfirstlane(n);
    if (n >= NN) return;
    int sp = __builtin_amdgcn_readfirstlane(species[n]);
    const float sc_l2 = 1.f / 128.f;
    const float rr = 0.07905694150420949f * 0.4472135954999579f;  // rs160 * rs5

    const float* n0r = n0 + (size_t)n * 64;
    float sk = 0.f;
#pragma unroll 8
    for (int j = 0; j < 64; ++j)
        sk += n0r[j] * w_lin2_s[j * 64 + lane];
    sk *= sc_l2;
#pragma unroll 8
    for (int u = 0; u < 32; ++u)
        sk += (embed_w[sp * 32 + u] * rr) * w_res_s[(u * 5 + sp) * 64 + lane];
    float act = silu_f(sk);
    float gmine = __shfl(act, 32 + (lane & 31));

    const float* n1r = n1 + (size_t)n * 192;
    int i0 = lane >> 5, v = lane & 31;
    float acc0 = 0.f, acc2 = 0.f;
#pragma unroll 8
    for (int u = 0; u < 64; ++u) {
        float wlv = w_lin2_v[u * 32 + v];
        acc0 += n1r[i0 * 64 + u] * wlv;
        acc2 += n1r[128 + u] * wlv;
    }
    h_v[(size_t)n * 96 + i0 * 32 + v] = acc0 * sc_l2 * gmine;
    if (lane < 32) {
        h_v[(size_t)n * 96 + 64 + v] = acc2 * sc_l2 * gmine;
        h_s[(size_t)n * 32 + v] = act;
    }
}

// ---------------- final node update: scalar-only + fused readout ----------------
__global__ __launch_bounds__(256) void k_node_update_last(
        const int* __restrict__ species,
        const float* __restrict__ n0,
        const float* __restrict__ w_lin2_s, const float* __restrict__ w_res_s,
        const float* __restrict__ h_s,
        const float* __restrict__ w_out1, const float* __restrict__ w_out2,
        float* __restrict__ out) {
    int lane = threadIdx.x & 63;
    int n = blockIdx.x * 4 + (threadIdx.x >> 6);
    n = __builtin_amdgcn_readfirstlane(n);
    if (n >= NN) return;
    if (lane >= 32) return;
    int sp = __builtin_amdgcn_readfirstlane(species[n]);
    const float sc_l2 = 1.f / 128.f;
    const float rs160 = 0.07905694150420949f;

    const float* n0r = n0 + (size_t)n * 64;
    float sk = 0.f;
#pragma unroll 8
    for (int j = 0; j < 64; ++j)
        sk += n0r[j] * w_lin2_s[j * 64 + lane];
    sk *= sc_l2;
    const float* hsr = h_s + (size_t)n * 32;
#pragma unroll 8
    for (int u = 0; u < 32; ++u)
        sk += (hsr[u] * rs160) * w_res_s[(u * 5 + sp) * 64 + lane];
    float act = silu_f(sk);

    float wc = 0.f;
#pragma unroll
    for (int j = 0; j < 16; ++j)
        wc += w_out1[lane * 16 + j] * w_out2[j];
    float e = act * wc;
    e += __shfl_xor(e, 1);
    e += __shfl_xor(e, 2);
    e += __shfl_xor(e, 4);
    e += __shfl_xor(e, 8);
    e += __shfl_xor(e, 16);
    if (lane == 0)
        out[n] = e * 0.17677669529663687f * 0.25f;
}

extern "C" void kernel_launch(void* const* d_in, const int* in_sizes, int n_in,
                              void* d_out, int out_size, void* d_ws, size_t ws_size,
                              hipStream_t stream) {
    const float* evec     = (const float*)d_in[0];
    const int*   species  = (const int*)d_in[1];
    const int*   senders  = (const int*)d_in[2];
    const int*   receivers= (const int*)d_in[3];
    const float* embed_w  = (const float*)d_in[4];
    const float* w_res_s  = (const float*)d_in[5];
    const float* w_res_v  = (const float*)d_in[6];
    const float* w_lin1_s = (const float*)d_in[7];
    const float* w_lin1_v = (const float*)d_in[8];
    const float* mlp_w0   = (const float*)d_in[9];
    const float* mlp_w1   = (const float*)d_in[10];
    const float* mlp_w2   = (const float*)d_in[11];
    const float* w_lin2_s = (const float*)d_in[12];
    const float* w_lin2_v = (const float*)d_in[13];
    const float* w_out1   = (const float*)d_in[14];
    const float* w_out2   = (const float*)d_in[15];
    (void)w_res_v;

    float* ws = (float*)d_ws;
    size_t off = 0;
    auto alloc = [&](size_t n) { float* p = ws + off; off += (n + 3) & ~(size_t)3; return p; };

    float* h_s  = alloc(NN * 32);
    float* h_v  = alloc(NN * 96);
    float* feat = alloc((size_t)NN * 128);
    float* n0b  = alloc(NN * 64);      // n0b and n1b contiguous
    float* n1b  = alloc(NN * 192);
    float* tab0 = alloc((size_t)(TB + 1) * 64);   // (TB+1) rows x 32 float2
    float* tab1 = alloc((size_t)(TB + 1) * 64);
    float* fs   = alloc(160);
    int*   deg       = (int*)alloc(NN);
    int*   row_start = (int*)alloc(NN + 1);
    int*   cursor    = (int*)alloc(NN);
    int*   csr_edge  = (int*)alloc(EE);
    int*   csr_send  = (int*)alloc(EE);
    int*   csr_recv  = (int*)alloc(EE);
    float* ev3       = alloc((size_t)EE * 3);

    k_table<<<(2 * (TB + 1) + 3) / 4, 256, 0, stream>>>(mlp_w0, mlp_w1, mlp_w2, tab0, tab1);
    k_fs<<<1, 256, 0, stream>>>(embed_w, w_lin1_s, fs);

    hipMemsetAsync(deg, 0, NN * 4, stream);
    k_hist<<<(EE + 255) / 256, 256, 0, stream>>>(receivers, deg);
    k_scan<<<1, 256, 0, stream>>>(deg, row_start, cursor);
    k_fill<<<(EE + 255) / 256, 256, 0, stream>>>(receivers, cursor, csr_edge);
    k_gather<<<(EE + 255) / 256, 256, 0, stream>>>(csr_edge, senders, receivers, species,
                                                   evec, csr_send, csr_recv, ev3);

    // ---- layer 0 (no feat gather; es from fs[species]) ----
    hipMemsetAsync(n0b, 0, (size_t)NN * 256 * 4, stream);   // n0b + n1b contiguous
    k_mega<0><<<EE / 256, 256, 0, stream>>>(
        csr_send, csr_recv, ev3, row_start, fs, feat, tab0, n0b, n1b);
    k_node_update0<<<12500, 256, 0, stream>>>(
        species, n0b, n1b, w_lin2_s, w_lin2_v, w_res_s, embed_w, h_s, h_v);

    // ---- layer 1 (last): 1o output path dead ----
    k_node_prep2<<<12500, 256, 0, stream>>>(
        h_s, h_v, w_lin1_s + 1024, w_lin1_v + 1024, feat);
    hipMemsetAsync(n0b, 0, (size_t)NN * 64 * 4, stream);
    k_mega<1><<<EE / 256, 256, 0, stream>>>(
        csr_send, csr_recv, ev3, row_start, fs, feat, tab1, n0b, n1b);
    k_node_update_last<<<12500, 256, 0, stream>>>(
        species, n0b, w_lin2_s + 4096, w_res_s + 10240, h_s,
        w_out1, w_out2, (float*)d_out);
}

// Round 13
// 569.859 us; speedup vs baseline: 6.3536x; 1.0974x over previous
//
#include <hip/hip_runtime.h>
#include <math.h>

#define NN 50000
#define EE 800000
#define TB 4096            // radial table bins; nodes = TB+1 over r in [0,5]

typedef float f32x2 __attribute__((ext_vector_type(2)));
typedef float f32x4  __attribute__((ext_vector_type(4)));

__device__ __forceinline__ float silu_f(float x) {
    return x / (1.f + __expf(-x));
}

// ---------------- radial MLP -> lookup table (one wave per (layer,bin)) ----------------
// row layout (f32x4, c0 in [0,16)): {A(c0), B(c0), A(16+c0), B(16+c0)}
// A = w[u] (d1);  B = w[64+u] (d3) for L0,  w[32+u] (d2) for L1.
__global__ __launch_bounds__(256) void k_table(
        const float* __restrict__ mlp_w0, const float* __restrict__ mlp_w1,
        const float* __restrict__ mlp_w2,
        float* __restrict__ tab0, float* __restrict__ tab1) {
    __shared__ float stage[4][128];
    int wv = threadIdx.x >> 6, lane = threadIdx.x & 63;
    int wid = blockIdx.x * 4 + wv;
    if (wid > 2 * TB + 1) wid = 2 * TB + 1;   // clamp; duplicate work benign
    int l = wid / (TB + 1);
    int bin = wid - l * (TB + 1);
    float* st = stage[wv];

    float r = 5.f * (float)bin / (float)TB;
    if (r < 1e-6f) r = 1e-6f;
    float ir = 1.f / r;
    float xx = r * 0.2f;
    float env = 0.f;
    if (xx < 1.f) {
        float x2 = xx * xx, x3 = x2 * xx, x6 = x3 * x3, x7 = x6 * xx, x8 = x7 * xx;
        env = 1.f - 28.f * x6 + 48.f * x7 - 21.f * x8;
    }
    float coef = 0.6324555320336759f * env * ir;   // sqrt(2/5)*env/r
    const float w5 = 0.6283185307179586f;          // pi/5

    float p = 0.f;
#pragma unroll
    for (int k = 0; k < 8; ++k)
        p += coef * __sinf(w5 * (float)(k + 1) * r) * mlp_w0[l * 512 + k * 64 + lane];
    float a1 = silu_f(p * 0.35355339059327373f);   // /sqrt(8)
    st[lane] = a1;
    __syncthreads();
    float q = 0.f;
    for (int j = 0; j < 64; ++j) q += st[j] * mlp_w1[l * 4096 + j * 64 + lane];
    float a2 = silu_f(q * 0.125f);                 // /sqrt(64)
    __syncthreads();
    st[lane] = a2;
    __syncthreads();
    float wlo = 0.f, whi = 0.f;
    for (int h = 0; h < 64; ++h) {
        float a = st[h];
        wlo += a * mlp_w2[l * 8192 + h * 128 + lane];
        whi += a * mlp_w2[l * 8192 + h * 128 + 64 + lane];
    }
    __syncthreads();
    st[lane] = wlo;        // w[0..63]
    st[64 + lane] = whi;   // w[64..127]
    __syncthreads();
    if (lane < 16) {
        f32x4 o;
        if (l == 0) {
            o[0] = st[lane]; o[1] = st[64 + lane];
            o[2] = st[16 + lane]; o[3] = st[80 + lane];
            ((f32x4*)tab0)[bin * 16 + lane] = o;
        } else {
            o[0] = st[lane]; o[1] = st[32 + lane];
            o[2] = st[16 + lane]; o[3] = st[48 + lane];
            ((f32x4*)tab1)[bin * 16 + lane] = o;
        }
    }
}

// ---------------- layer-0 edge features: fs[sp][v] ----------------
__global__ void k_fs(const float* __restrict__ embed_w, const float* __restrict__ w_lin1_s,
                     float* __restrict__ fs) {
    int t = threadIdx.x;
    if (t >= 160) return;
    int sp = t >> 5, v = t & 31;
    float acc = 0.f;
#pragma unroll
    for (int u = 0; u < 32; ++u) acc += embed_w[sp * 32 + u] * w_lin1_s[u * 32 + v];
    fs[t] = acc * 0.4472135954999579f * 0.17677669529663687f;
}

// ---------------- CSR build ----------------
__global__ void k_hist(const int* __restrict__ recv, int* __restrict__ deg) {
    int e = blockIdx.x * 256 + threadIdx.x;
    if (e < EE) atomicAdd(&deg[recv[e]], 1);
}

__global__ void k_scan(const int* __restrict__ deg, int* __restrict__ row_start,
                       int* __restrict__ cursor) {
    __shared__ int part[256];
    int t = threadIdx.x;
    int lo = t * 196, hi = lo + 196 > NN ? NN : lo + 196;
    int s = 0;
    for (int i = lo; i < hi; ++i) s += deg[i];
    part[t] = s;
    __syncthreads();
    // Hillis-Steele inclusive scan over part[256]
    for (int d = 1; d < 256; d <<= 1) {
        int add = (t >= d) ? part[t - d] : 0;
        __syncthreads();
        part[t] += add;
        __syncthreads();
    }
    int run = part[t] - s;   // exclusive prefix
    for (int i = lo; i < hi; ++i) {
        row_start[i] = run;
        cursor[i] = run;
        run += deg[i];
    }
    if (t == 255) row_start[NN] = run;
}

// fill + gather fused: place each edge's data directly at its CSR slot
__global__ void k_fill(const int* __restrict__ recv, const int* __restrict__ senders,
                       const int* __restrict__ species, const float* __restrict__ evec,
                       int* __restrict__ cursor,
                       int* __restrict__ csr_send, int* __restrict__ csr_recv,
                       float* __restrict__ ev3) {
    int e = blockIdx.x * 256 + threadIdx.x;
    if (e >= EE) return;
    int rv = recv[e];
    int p = atomicAdd(&cursor[rv], 1);
    int snd = senders[e];
    csr_send[p] = snd | (species[snd] << 24);
    csr_recv[p] = rv;
    ev3[p * 3 + 0] = evec[e * 3 + 0];
    ev3[p * 3 + 1] = evec[e * 3 + 1];
    ev3[p * 3 + 2] = evec[e * 3 + 2];
}

// ---------------- fused table-lookup edge kernel, layer-specialized ----------------
#define WROWS 20
#define WSTRIDE 260
template<int L>
__global__ __launch_bounds__(256) void k_mega(
    const int* __restrict__ csr_send, const int* __restrict__ csr_recv,
    const float* __restrict__ ev3, const int* __restrict__ row_start,
    const float* __restrict__ fs, const float* __restrict__ feat,
    const float* __restrict__ tab,
    float* __restrict__ n0, float* __restrict__ n1) {
    __shared__ f32x4 accw4[WROWS * WSTRIDE / 4];   // 20.8 KB
    __shared__ f32x4 lds_esh[256];                 // {shx,shy,shz,bitcast(packed snd)}
    __shared__ float lds_x[256];                   // r * TB/5
    __shared__ int lds_wd[256];
    __shared__ int sh_base, sh_last;
    float* accw = (float*)accw4;

    int tid = threadIdx.x;
    int p0 = blockIdx.x * 256;
    int lane = tid & 63;
    int wv = tid >> 6;
    int c0 = lane & 15;
    int rg = lane >> 4;

    for (int i = tid; i < WROWS * WSTRIDE / 4; i += 256) accw4[i] = (f32x4)0.f;

    int sndp = csr_send[p0 + tid];
    int rv = csr_recv[p0 + tid];
    if (tid == 0)   sh_base = rv;
    if (tid == 255) sh_last = rv;
    {
        float x = ev3[(p0 + tid) * 3 + 0], y = ev3[(p0 + tid) * 3 + 1], z = ev3[(p0 + tid) * 3 + 2];
        float r = sqrtf(x * x + y * y + z * z + 1e-12f);
        float ir = 1.f / r;
        const float s3 = 1.7320508075688772f;
        f32x4 esh;
        esh[0] = s3 * x * ir;
        esh[1] = s3 * y * ir;
        esh[2] = s3 * z * ir;
        esh[3] = __int_as_float(sndp);
        lds_esh[tid] = esh;
        float xb = r * ((float)TB / 5.f);
        if (xb > (float)TB) xb = (float)TB;   // r>=5 -> tab[TB] == 0 exactly
        lds_x[tid] = xb;
    }
    __syncthreads();
    int node_base = sh_base;
    lds_wd[tid] = rv - node_base;

    const f32x4* tabv = (const f32x4*)tab;
    const f32x4* feat4 = (const f32x4*)feat;
    const float rs3 = 0.5773502691896258f;

    for (int t = 0; t < 4; ++t) {
        int tOff = wv * 64 + t * 16;

        f32x4 eshv[4], dv[4];
        int wr[4];
        float es0[4], es1[4];
#pragma unroll
        for (int j = 0; j < 4; ++j) {
            int idx = tOff + rg * 4 + j;
            eshv[j] = lds_esh[idx];
            wr[j] = lds_wd[idx];
            float xb = lds_x[idx];
            int bin = (int)xb;
            if (bin >= TB) bin = TB - 1;
            float fr = xb - (float)bin;
            f32x4 lo = tabv[bin * 16 + c0];
            f32x4 hi = tabv[bin * 16 + 16 + c0];
            dv[j] = lo + fr * (hi - lo);
            if (L == 0) {
                int sp = ((unsigned)__float_as_int(eshv[j][3])) >> 24;
                es0[j] = fs[sp * 32 + c0];
                es1[j] = fs[sp * 32 + 16 + c0];
            }
        }

#pragma unroll
        for (int b = 0; b < 2; ++b) {
            int u = b * 16 + c0;
            float s0 = 0.f, s1 = 0.f, s2 = 0.f, s3v = 0.f;
            int curw = wr[0];
            auto emit = [&](int wrow) {
                if (L == 0) {
                    if (wrow < WROWS) {
                        float* arow = accw + wrow * WSTRIDE;
                        atomicAdd(arow + u, s0);
                        atomicAdd(arow + 64 + u, s1);
                        atomicAdd(arow + 128 + u, s2);
                        atomicAdd(arow + 192 + u, s3v);
                    } else {
                        int rvn = node_base + wrow;
                        atomicAdd(n0 + (size_t)rvn * 64 + u, s0);
                        atomicAdd(n1 + (size_t)rvn * 192 + u, s1);
                        atomicAdd(n1 + (size_t)rvn * 192 + 64 + u, s2);
                        atomicAdd(n1 + (size_t)rvn * 192 + 128 + u, s3v);
                    }
                } else {
                    if (wrow < WROWS) {
                        float* arow = accw + wrow * WSTRIDE;
                        atomicAdd(arow + u, s0);
                        atomicAdd(arow + 32 + u, s1);
                    } else {
                        int rvn = node_base + wrow;
                        atomicAdd(n0 + (size_t)rvn * 64 + u, s0);
                        atomicAdd(n0 + (size_t)rvn * 64 + 32 + u, s1);
                    }
                }
            };
#pragma unroll
            for (int j = 0; j < 4; ++j) {
                int wrow = wr[j];
                if (j > 0 && wrow != curw) {
                    emit(curw);
                    s0 = s1 = s2 = s3v = 0.f;
                    curw = wrow;
                }
                f32x4 esh = eshv[j];
                float dA = dv[j][2 * b];
                float dB = dv[j][2 * b + 1];
                if (L == 0) {
                    float es = b ? es1[j] : es0[j];
                    float t3 = dB * es;
                    s0  += dA * es;
                    s1  += t3 * esh[0];
                    s2  += t3 * esh[1];
                    s3v += t3 * esh[2];
                } else {
                    int s = __float_as_int(esh[3]) & 0xFFFFFF;
                    f32x4 f4 = feat4[(size_t)s * 32 + u];
                    float dot = f4[1] * esh[0] + f4[2] * esh[1] + f4[3] * esh[2];
                    s0 += dA * f4[0];
                    s1 += dB * dot * rs3;
                }
            }
            // tree-merge final runs across the 4 rg groups (receiver-sorted => exact)
            int alive = 1;
            {
                int pw = __shfl_xor(curw, 16);
                float t0 = __shfl_xor(s0, 16), t1 = __shfl_xor(s1, 16);
                float t2 = __shfl_xor(s2, 16), t3m = __shfl_xor(s3v, 16);
                if (pw == curw) {
                    s0 += t0; s1 += t1;
                    if (L == 0) { s2 += t2; s3v += t3m; }
                    if (lane & 16) alive = 0;
                }
            }
            {
                int pw = __shfl_xor(curw, 32);
                int pal = __shfl_xor(alive, 32);
                float t0 = __shfl_xor(s0, 32), t1 = __shfl_xor(s1, 32);
                float t2 = __shfl_xor(s2, 32), t3m = __shfl_xor(s3v, 32);
                if (alive && pal && pw == curw) {
                    s0 += t0; s1 += t1;
                    if (L == 0) { s2 += t2; s3v += t3m; }
                    if (lane & 32) alive = 0;
                }
            }
            if (alive) emit(curw);
        }
    }
    __syncthreads();

    // ---- flush window ----
    int span = sh_last - node_base;
    if (span > WROWS - 1) span = WROWS - 1;
    for (int wl = 0; wl <= span; ++wl) {
        int n = node_base + wl;
        float v = accw[wl * WSTRIDE + tid];
        bool interior = (row_start[n] >= p0) && (row_start[n + 1] <= p0 + 256);
        if (L == 1) {
            if (tid < 64) {
                float* dest = n0 + (size_t)n * 64 + tid;
                if (interior) *dest = v;
                else if (v != 0.f) atomicAdd(dest, v);
            }
        } else {
            float* dest = (tid < 64) ? (n0 + (size_t)n * 64 + tid) : (n1 + (size_t)n * 192 + (tid - 64));
            if (interior) *dest = v;
            else if (v != 0.f) atomicAdd(dest, v);
        }
    }
}

// ---------------- fused layer-0 node update + lin1 feat prep (wave-per-node) ----------
// L0 facts: h_v_in == 0 (no vector residual), n1's o1b half == 0.
__global__ __launch_bounds__(256) void k_upd0_prep(
        const int* __restrict__ species,
        const float* __restrict__ n0, const float* __restrict__ n1,
        const float* __restrict__ w_lin2_s, const float* __restrict__ w_lin2_v,
        const float* __restrict__ w_res_s, const float* __restrict__ embed_w,
        const float* __restrict__ w_lin1_s, const float* __restrict__ w_lin1_v,
        float* __restrict__ h_s, float* __restrict__ feat) {
    __shared__ float stage[4][128];   // per wave: [0..31]=h_s, [32+i*32+v]=h_v[i][v]
    int lane = threadIdx.x & 63;
    int wv = threadIdx.x >> 6;
    int n = blockIdx.x * 4 + wv;      // grid = 12500 -> n < 50000 always
    n = __builtin_amdgcn_readfirstlane(n);
    int sp = __builtin_amdgcn_readfirstlane(species[n]);
    const float sc_l2 = 1.f / 128.f;
    const float rr = 0.07905694150420949f * 0.4472135954999579f;  // rs160 * rs5

    const float* n0r = n0 + (size_t)n * 64;
    float sk = 0.f;
#pragma unroll 8
    for (int j = 0; j < 64; ++j)
        sk += n0r[j] * w_lin2_s[j * 64 + lane];
    sk *= sc_l2;
#pragma unroll 8
    for (int u = 0; u < 32; ++u)
        sk += (embed_w[sp * 32 + u] * rr) * w_res_s[(u * 5 + sp) * 64 + lane];
    float act = silu_f(sk);
    float gmine = __shfl(act, 32 + (lane & 31));

    const float* n1r = n1 + (size_t)n * 192;
    int i0 = lane >> 5, v = lane & 31;
    float acc0 = 0.f, acc2 = 0.f;
#pragma unroll 8
    for (int u = 0; u < 32; ++u) {        // o1b half of n1 is zero at L0
        float wlv = w_lin2_v[u * 32 + v];
        acc0 += n1r[i0 * 64 + u] * wlv;
        acc2 += n1r[128 + u] * wlv;
    }
    float* st = stage[wv];
    st[32 + i0 * 32 + v] = acc0 * sc_l2 * gmine;   // h_v comps 0,1
    if (lane < 32) {
        st[v] = act;                               // h_s
        st[96 + v] = acc2 * sc_l2 * gmine;         // h_v comp 2
        h_s[(size_t)n * 32 + v] = act;
    }
    __syncthreads();

    // lin1 -> feat[n][q][4] = {es, evx, evy, evz}
    const float rs32 = 0.17677669529663687f;
    float accA = 0.f, accB = 0.f;
#pragma unroll 8
    for (int u = 0; u < 32; ++u) {
        float wsv = w_lin1_s[u * 32 + v];
        float wvv = w_lin1_v[u * 32 + v];
        float xs = st[u];
        float xx = st[32 + u];
        float xy = st[64 + u];
        float xz = st[96 + u];
        float inA = i0 ? xy : xs;
        float wA  = i0 ? wvv : wsv;
        float inB = i0 ? xz : xx;
        accA += inA * wA;
        accB += inB * wvv;
    }
    f32x2 o;
    o[0] = accA * rs32;
    o[1] = accB * rs32;
    *(f32x2*)(feat + (size_t)n * 128 + v * 4 + i0 * 2) = o;
}

// ---------------- final node update: scalar-only + fused readout ----------------
__global__ __launch_bounds__(256) void k_node_update_last(
        const int* __restrict__ species,
        const float* __restrict__ n0,
        const float* __restrict__ w_lin2_s, const float* __restrict__ w_res_s,
        const float* __restrict__ h_s,
        const float* __restrict__ w_out1, const float* __restrict__ w_out2,
        float* __restrict__ out) {
    int lane = threadIdx.x & 63;
    int n = blockIdx.x * 4 + (threadIdx.x >> 6);
    n = __builtin_amdgcn_readfirstlane(n);
    if (n >= NN) return;
    if (lane >= 32) return;
    int sp = __builtin_amdgcn_readfirstlane(species[n]);
    const float sc_l2 = 1.f / 128.f;
    const float rs160 = 0.07905694150420949f;

    const float* n0r = n0 + (size_t)n * 64;
    float sk = 0.f;
#pragma unroll 8
    for (int j = 0; j < 64; ++j)
        sk += n0r[j] * w_lin2_s[j * 64 + lane];
    sk *= sc_l2;
    const float* hsr = h_s + (size_t)n * 32;
#pragma unroll 8
    for (int u = 0; u < 32; ++u)
        sk += (hsr[u] * rs160) * w_res_s[(u * 5 + sp) * 64 + lane];
    float act = silu_f(sk);

    float wc = 0.f;
#pragma unroll
    for (int j = 0; j < 16; ++j)
        wc += w_out1[lane * 16 + j] * w_out2[j];
    float e = act * wc;
    e += __shfl_xor(e, 1);
    e += __shfl_xor(e, 2);
    e += __shfl_xor(e, 4);
    e += __shfl_xor(e, 8);
    e += __shfl_xor(e, 16);
    if (lane == 0)
        out[n] = e * 0.17677669529663687f * 0.25f;
}

extern "C" void kernel_launch(void* const* d_in, const int* in_sizes, int n_in,
                              void* d_out, int out_size, void* d_ws, size_t ws_size,
                              hipStream_t stream) {
    const float* evec     = (const float*)d_in[0];
    const int*   species  = (const int*)d_in[1];
    const int*   senders  = (const int*)d_in[2];
    const int*   receivers= (const int*)d_in[3];
    const float* embed_w  = (const float*)d_in[4];
    const float* w_res_s  = (const float*)d_in[5];
    const float* w_res_v  = (const float*)d_in[6];
    const float* w_lin1_s = (const float*)d_in[7];
    const float* w_lin1_v = (const float*)d_in[8];
    const float* mlp_w0   = (const float*)d_in[9];
    const float* mlp_w1   = (const float*)d_in[10];
    const float* mlp_w2   = (const float*)d_in[11];
    const float* w_lin2_s = (const float*)d_in[12];
    const float* w_lin2_v = (const float*)d_in[13];
    const float* w_out1   = (const float*)d_in[14];
    const float* w_out2   = (const float*)d_in[15];
    (void)w_res_v;

    float* ws = (float*)d_ws;
    size_t off = 0;
    auto alloc = [&](size_t n) { float* p = ws + off; off += (n + 3) & ~(size_t)3; return p; };

    float* h_s  = alloc(NN * 32);
    float* feat = alloc((size_t)NN * 128);
    float* n0b  = alloc(NN * 64);      // n0b and n1b contiguous
    float* n1b  = alloc(NN * 192);
    float* tab0 = alloc((size_t)(TB + 1) * 64);
    float* tab1 = alloc((size_t)(TB + 1) * 64);
    float* fs   = alloc(160);
    int*   deg       = (int*)alloc(NN);
    int*   row_start = (int*)alloc(NN + 1);
    int*   cursor    = (int*)alloc(NN);
    int*   csr_send  = (int*)alloc(EE);
    int*   csr_recv  = (int*)alloc(EE);
    float* ev3       = alloc((size_t)EE * 3);

    k_table<<<(2 * (TB + 1) + 3) / 4, 256, 0, stream>>>(mlp_w0, mlp_w1, mlp_w2, tab0, tab1);
    k_fs<<<1, 256, 0, stream>>>(embed_w, w_lin1_s, fs);

    hipMemsetAsync(deg, 0, NN * 4, stream);
    k_hist<<<(EE + 255) / 256, 256, 0, stream>>>(receivers, deg);
    k_scan<<<1, 256, 0, stream>>>(deg, row_start, cursor);
    k_fill<<<(EE + 255) / 256, 256, 0, stream>>>(receivers, senders, species, evec,
                                                 cursor, csr_send, csr_recv, ev3);

    // ---- layer 0 (no feat gather; es from fs[species]) ----
    hipMemsetAsync(n0b, 0, (size_t)NN * 256 * 4, stream);   // n0b + n1b contiguous
    k_mega<0><<<EE / 256, 256, 0, stream>>>(
        csr_send, csr_recv, ev3, row_start, fs, feat, tab0, n0b, n1b);
    k_upd0_prep<<<12500, 256, 0, stream>>>(
        species, n0b, n1b, w_lin2_s, w_lin2_v, w_res_s, embed_w,
        w_lin1_s + 1024, w_lin1_v + 1024, h_s, feat);

    // ---- layer 1 (last): 1o output path dead ----
    hipMemsetAsync(n0b, 0, (size_t)NN * 64 * 4, stream);
    k_mega<1><<<EE / 256, 256, 0, stream>>>(
        csr_send, csr_recv, ev3, row_start, fs, feat, tab1, n0b, n1b);
    k_node_update_last<<<12500, 256, 0, stream>>>(
        species, n0b, w_lin2_s + 4096, w_res_s + 10240, h_s,
        w_out1, w_out2, (float*)d_out);
}

// Round 14
// 558.993 us; speedup vs baseline: 6.4772x; 1.0194x over previous
//
#include <hip/hip_runtime.h>
#include <math.h>

#define NN 50000
#define EE 800000
#define TB 4096            // radial table bins; nodes = TB+1 over r in [0,5]

typedef float f32x2 __attribute__((ext_vector_type(2)));
typedef float f32x4  __attribute__((ext_vector_type(4)));

__device__ __forceinline__ float silu_f(float x) {
    return x / (1.f + __expf(-x));
}

// ---------------- radial MLP -> lookup table (one wave per (layer,bin)) + fs ----------
// row layout (f32x4, c0 in [0,16)): {A(c0), B(c0), A(16+c0), B(16+c0)}
// A = w[u] (d1);  B = w[64+u] (d3) for L0,  w[32+u] (d2) for L1.
// Spare waves (wid >= 2*TB+2) compute fs[sp][v] (they still run the dummy table
// compute with clamped wid so block barriers stay uniform).
__global__ __launch_bounds__(256) void k_table(
        const float* __restrict__ mlp_w0, const float* __restrict__ mlp_w1,
        const float* __restrict__ mlp_w2,
        const float* __restrict__ embed_w, const float* __restrict__ w_lin1_s,
        float* __restrict__ tab0, float* __restrict__ tab1, float* __restrict__ fs) {
    __shared__ float stage[4][128];
    int wv = threadIdx.x >> 6, lane = threadIdx.x & 63;
    int wid = blockIdx.x * 4 + wv;
    int widc = wid > 2 * TB + 1 ? 2 * TB + 1 : wid;
    int l = widc / (TB + 1);
    int bin = widc - l * (TB + 1);
    float* st = stage[wv];

    float r = 5.f * (float)bin / (float)TB;
    if (r < 1e-6f) r = 1e-6f;
    float ir = 1.f / r;
    float xx = r * 0.2f;
    float env = 0.f;
    if (xx < 1.f) {
        float x2 = xx * xx, x3 = x2 * xx, x6 = x3 * x3, x7 = x6 * xx, x8 = x7 * xx;
        env = 1.f - 28.f * x6 + 48.f * x7 - 21.f * x8;
    }
    float coef = 0.6324555320336759f * env * ir;   // sqrt(2/5)*env/r
    const float w5 = 0.6283185307179586f;          // pi/5

    float p = 0.f;
#pragma unroll
    for (int k = 0; k < 8; ++k)
        p += coef * __sinf(w5 * (float)(k + 1) * r) * mlp_w0[l * 512 + k * 64 + lane];
    float a1 = silu_f(p * 0.35355339059327373f);   // /sqrt(8)
    st[lane] = a1;
    __syncthreads();
    float q = 0.f;
    for (int j = 0; j < 64; ++j) q += st[j] * mlp_w1[l * 4096 + j * 64 + lane];
    float a2 = silu_f(q * 0.125f);                 // /sqrt(64)
    __syncthreads();
    st[lane] = a2;
    __syncthreads();
    float wlo = 0.f, whi = 0.f;
    for (int h = 0; h < 64; ++h) {
        float a = st[h];
        wlo += a * mlp_w2[l * 8192 + h * 128 + lane];
        whi += a * mlp_w2[l * 8192 + h * 128 + 64 + lane];
    }
    __syncthreads();
    st[lane] = wlo;        // w[0..63]
    st[64 + lane] = whi;   // w[64..127]
    __syncthreads();
    if (wid <= 2 * TB + 1 && lane < 16) {
        f32x4 o;
        if (l == 0) {
            o[0] = st[lane]; o[1] = st[64 + lane];
            o[2] = st[16 + lane]; o[3] = st[80 + lane];
            ((f32x4*)tab0)[bin * 16 + lane] = o;
        } else {
            o[0] = st[lane]; o[1] = st[32 + lane];
            o[2] = st[16 + lane]; o[3] = st[48 + lane];
            ((f32x4*)tab1)[bin * 16 + lane] = o;
        }
    }
    // fs on spare waves
    int ft = (wid - (2 * TB + 2)) * 64 + lane;
    if (wid >= 2 * TB + 2 && ft < 160) {
        int sp = ft >> 5, v = ft & 31;
        float acc = 0.f;
#pragma unroll
        for (int u = 0; u < 32; ++u) acc += embed_w[sp * 32 + u] * w_lin1_s[u * 32 + v];
        fs[ft] = acc * 0.4472135954999579f * 0.17677669529663687f;
    }
}

// ---------------- CSR build ----------------
__global__ void k_hist(const int* __restrict__ recv, int* __restrict__ deg) {
    int e = blockIdx.x * 256 + threadIdx.x;
    if (e < EE) atomicAdd(&deg[recv[e]], 1);
}

__global__ void k_scan(const int* __restrict__ deg, int* __restrict__ row_start,
                       int* __restrict__ cursor) {
    __shared__ int part[256];
    int t = threadIdx.x;
    int lo = t * 196, hi = lo + 196 > NN ? NN : lo + 196;
    int s = 0;
    if (t < 255) {
        const int4* d4 = (const int4*)(deg + lo);
#pragma unroll 7
        for (int i = 0; i < 49; ++i) { int4 v = d4[i]; s += v.x + v.y + v.z + v.w; }
    } else {
        for (int i = lo; i < hi; ++i) s += deg[i];
    }
    part[t] = s;
    __syncthreads();
    for (int d = 1; d < 256; d <<= 1) {
        int add = (t >= d) ? part[t - d] : 0;
        __syncthreads();
        part[t] += add;
        __syncthreads();
    }
    int run = part[t] - s;   // exclusive prefix
    for (int i = lo; i < hi; ++i) {
        row_start[i] = run;
        cursor[i] = run;
        run += deg[i];
    }
    if (t == 255) row_start[NN] = run;
}

// fill + gather + geometry fused: ev4[p] = {shx, shy, shz, xb}
__global__ void k_fill(const int* __restrict__ recv, const int* __restrict__ senders,
                       const int* __restrict__ species, const float* __restrict__ evec,
                       int* __restrict__ cursor,
                       int* __restrict__ csr_send, int* __restrict__ csr_recv,
                       float* __restrict__ ev4) {
    int e = blockIdx.x * 256 + threadIdx.x;
    if (e >= EE) return;
    int rv = recv[e];
    int p = atomicAdd(&cursor[rv], 1);
    int snd = senders[e];
    csr_send[p] = snd | (species[snd] << 24);
    csr_recv[p] = rv;
    float x = evec[e * 3 + 0], y = evec[e * 3 + 1], z = evec[e * 3 + 2];
    float r = sqrtf(x * x + y * y + z * z + 1e-12f);
    float ir = 1.f / r;
    const float s3 = 1.7320508075688772f;
    float xb = r * ((float)TB / 5.f);
    if (xb > (float)TB) xb = (float)TB;   // r>=5 -> tab[TB] == 0 exactly
    f32x4 o;
    o[0] = s3 * x * ir;
    o[1] = s3 * y * ir;
    o[2] = s3 * z * ir;
    o[3] = xb;
    *(f32x4*)(ev4 + (size_t)p * 4) = o;
}

// ---------------- fused table-lookup edge kernel, layer-specialized ----------------
#define WROWS 18
#define WSTRIDE 256
template<int L>
__global__ __launch_bounds__(256) void k_mega(
    const int* __restrict__ csr_send, const int* __restrict__ csr_recv,
    const float* __restrict__ ev4, const int* __restrict__ row_start,
    const float* __restrict__ fs, const float* __restrict__ feat,
    const float* __restrict__ tab,
    float* __restrict__ n0, float* __restrict__ n1) {
    __shared__ f32x4 accw4[WROWS * WSTRIDE / 4];   // 18 KB
    __shared__ f32x4 lds_esh[256];                 // {shx,shy,shz,bitcast(packed snd)}
    __shared__ float lds_x[256];                   // table coordinate xb
    __shared__ int lds_wd[256];
    __shared__ int sh_base, sh_last;
    float* accw = (float*)accw4;

    int tid = threadIdx.x;
    int p0 = blockIdx.x * 256;
    int lane = tid & 63;
    int wv = tid >> 6;
    int c0 = lane & 15;
    int rg = lane >> 4;

    for (int i = tid; i < WROWS * WSTRIDE / 4; i += 256) accw4[i] = (f32x4)0.f;

    int sndp = csr_send[p0 + tid];
    int rv = csr_recv[p0 + tid];
    if (tid == 0)   sh_base = rv;
    if (tid == 255) sh_last = rv;
    {
        f32x4 g = *(const f32x4*)(ev4 + (size_t)(p0 + tid) * 4);
        f32x4 esh;
        esh[0] = g[0]; esh[1] = g[1]; esh[2] = g[2];
        esh[3] = __int_as_float(sndp);
        lds_esh[tid] = esh;
        lds_x[tid] = g[3];
    }
    __syncthreads();
    int node_base = sh_base;
    lds_wd[tid] = rv - node_base;

    const f32x4* tabv = (const f32x4*)tab;
    const f32x4* feat4 = (const f32x4*)feat;
    const float rs3 = 0.5773502691896258f;

    for (int t = 0; t < 4; ++t) {
        int tOff = wv * 64 + t * 16;

        f32x4 eshv[4], dv[4];
        int wr[4];
        float es0[4], es1[4];
#pragma unroll
        for (int j = 0; j < 4; ++j) {
            int idx = tOff + rg * 4 + j;
            eshv[j] = lds_esh[idx];
            wr[j] = lds_wd[idx];
            float xb = lds_x[idx];
            int bin = (int)xb;
            if (bin >= TB) bin = TB - 1;
            float fr = xb - (float)bin;
            f32x4 lo = tabv[bin * 16 + c0];
            f32x4 hi = tabv[bin * 16 + 16 + c0];
            dv[j] = lo + fr * (hi - lo);
            if (L == 0) {
                int sp = ((unsigned)__float_as_int(eshv[j][3])) >> 24;
                es0[j] = fs[sp * 32 + c0];
                es1[j] = fs[sp * 32 + 16 + c0];
            }
        }

#pragma unroll
        for (int b = 0; b < 2; ++b) {
            int u = b * 16 + c0;
            float s0 = 0.f, s1 = 0.f, s2 = 0.f, s3v = 0.f;
            int curw = wr[0];
            auto emit = [&](int wrow) {
                if (L == 0) {
                    if (wrow < WROWS) {
                        float* arow = accw + wrow * WSTRIDE;
                        atomicAdd(arow + u, s0);
                        atomicAdd(arow + 64 + u, s1);
                        atomicAdd(arow + 128 + u, s2);
                        atomicAdd(arow + 192 + u, s3v);
                    } else {
                        int rvn = node_base + wrow;
                        atomicAdd(n0 + (size_t)rvn * 64 + u, s0);
                        atomicAdd(n1 + (size_t)rvn * 192 + u, s1);
                        atomicAdd(n1 + (size_t)rvn * 192 + 64 + u, s2);
                        atomicAdd(n1 + (size_t)rvn * 192 + 128 + u, s3v);
                    }
                } else {
                    if (wrow < WROWS) {
                        float* arow = accw + wrow * WSTRIDE;
                        atomicAdd(arow + u, s0);
                        atomicAdd(arow + 32 + u, s1);
                    } else {
                        int rvn = node_base + wrow;
                        atomicAdd(n0 + (size_t)rvn * 64 + u, s0);
                        atomicAdd(n0 + (size_t)rvn * 64 + 32 + u, s1);
                    }
                }
            };
#pragma unroll
            for (int j = 0; j < 4; ++j) {
                int wrow = wr[j];
                if (j > 0 && wrow != curw) {
                    emit(curw);
                    s0 = s1 = s2 = s3v = 0.f;
                    curw = wrow;
                }
                f32x4 esh = eshv[j];
                float dA = dv[j][2 * b];
                float dB = dv[j][2 * b + 1];
                if (L == 0) {
                    float es = b ? es1[j] : es0[j];
                    float t3 = dB * es;
                    s0  += dA * es;
                    s1  += t3 * esh[0];
                    s2  += t3 * esh[1];
                    s3v += t3 * esh[2];
                } else {
                    int s = __float_as_int(esh[3]) & 0xFFFFFF;
                    f32x4 f4 = feat4[(size_t)s * 32 + u];
                    float dot = f4[1] * esh[0] + f4[2] * esh[1] + f4[3] * esh[2];
                    s0 += dA * f4[0];
                    s1 += dB * dot * rs3;
                }
            }
            // single-level (xor16) merge: pairs (rg0,rg1),(rg2,rg3). Two emitters
            // per address max -> 2-way LDS access, which is free (m136).
            {
                int pw = __shfl_xor(curw, 16);
                float t0 = __shfl_xor(s0, 16), t1 = __shfl_xor(s1, 16);
                float t2 = 0.f, t3m = 0.f;
                if (L == 0) { t2 = __shfl_xor(s2, 16); t3m = __shfl_xor(s3v, 16); }
                bool alive = true;
                if (pw == curw) {
                    s0 += t0; s1 += t1;
                    if (L == 0) { s2 += t2; s3v += t3m; }
                    if (lane & 16) alive = false;
                }
                if (alive) emit(curw);
            }
        }
    }
    __syncthreads();

    // ---- flush window ----
    int span = sh_last - node_base;
    if (span > WROWS - 1) span = WROWS - 1;
    for (int wl = 0; wl <= span; ++wl) {
        int n = node_base + wl;
        float v = accw[wl * WSTRIDE + tid];
        bool interior = (row_start[n] >= p0) && (row_start[n + 1] <= p0 + 256);
        if (L == 1) {
            if (tid < 64) {
                float* dest = n0 + (size_t)n * 64 + tid;
                if (interior) *dest = v;
                else if (v != 0.f) atomicAdd(dest, v);
            }
        } else {
            float* dest = (tid < 64) ? (n0 + (size_t)n * 64 + tid) : (n1 + (size_t)n * 192 + (tid - 64));
            if (interior) *dest = v;
            else if (v != 0.f) atomicAdd(dest, v);
        }
    }
}

// ---------------- fused layer-0 node update + lin1 feat prep (wave-per-node) ----------
__global__ __launch_bounds__(256) void k_upd0_prep(
        const int* __restrict__ species,
        const float* __restrict__ n0, const float* __restrict__ n1,
        const float* __restrict__ w_lin2_s, const float* __restrict__ w_lin2_v,
        const float* __restrict__ w_res_s, const float* __restrict__ embed_w,
        const float* __restrict__ w_lin1_s, const float* __restrict__ w_lin1_v,
        float* __restrict__ h_s, float* __restrict__ feat) {
    __shared__ float stage[4][128];
    int lane = threadIdx.x & 63;
    int wv = threadIdx.x >> 6;
    int n = blockIdx.x * 4 + wv;
    n = __builtin_amdgcn_readfirstlane(n);
    int sp = __builtin_amdgcn_readfirstlane(species[n]);
    const float sc_l2 = 1.f / 128.f;
    const float rr = 0.07905694150420949f * 0.4472135954999579f;  // rs160 * rs5

    const float* n0r = n0 + (size_t)n * 64;
    float sk = 0.f;
#pragma unroll 8
    for (int j = 0; j < 64; ++j)
        sk += n0r[j] * w_lin2_s[j * 64 + lane];
    sk *= sc_l2;
#pragma unroll 8
    for (int u = 0; u < 32; ++u)
        sk += (embed_w[sp * 32 + u] * rr) * w_res_s[(u * 5 + sp) * 64 + lane];
    float act = silu_f(sk);
    float gmine = __shfl(act, 32 + (lane & 31));

    const float* n1r = n1 + (size_t)n * 192;
    int i0 = lane >> 5, v = lane & 31;
    float acc0 = 0.f, acc2 = 0.f;
#pragma unroll 8
    for (int u = 0; u < 32; ++u) {        // o1b half of n1 is zero at L0
        float wlv = w_lin2_v[u * 32 + v];
        acc0 += n1r[i0 * 64 + u] * wlv;
        acc2 += n1r[128 + u] * wlv;
    }
    float* st = stage[wv];
    st[32 + i0 * 32 + v] = acc0 * sc_l2 * gmine;
    if (lane < 32) {
        st[v] = act;
        st[96 + v] = acc2 * sc_l2 * gmine;
        h_s[(size_t)n * 32 + v] = act;
    }
    __syncthreads();

    const float rs32 = 0.17677669529663687f;
    float accA = 0.f, accB = 0.f;
#pragma unroll 8
    for (int u = 0; u < 32; ++u) {
        float wsv = w_lin1_s[u * 32 + v];
        float wvv = w_lin1_v[u * 32 + v];
        float xs = st[u];
        float xx = st[32 + u];
        float xy = st[64 + u];
        float xz = st[96 + u];
        float inA = i0 ? xy : xs;
        float wA  = i0 ? wvv : wsv;
        float inB = i0 ? xz : xx;
        accA += inA * wA;
        accB += inB * wvv;
    }
    f32x2 o;
    o[0] = accA * rs32;
    o[1] = accB * rs32;
    *(f32x2*)(feat + (size_t)n * 128 + v * 4 + i0 * 2) = o;
}

// ---------------- final node update: scalar-only + fused readout ----------------
__global__ __launch_bounds__(256) void k_node_update_last(
        const int* __restrict__ species,
        const float* __restrict__ n0,
        const float* __restrict__ w_lin2_s, const float* __restrict__ w_res_s,
        const float* __restrict__ h_s,
        const float* __restrict__ w_out1, const float* __restrict__ w_out2,
        float* __restrict__ out) {
    int lane = threadIdx.x & 63;
    int n = blockIdx.x * 4 + (threadIdx.x >> 6);
    n = __builtin_amdgcn_readfirstlane(n);
    if (lane >= 32) return;
    int sp = __builtin_amdgcn_readfirstlane(species[n]);
    const float sc_l2 = 1.f / 128.f;
    const float rs160 = 0.07905694150420949f;

    const float* n0r = n0 + (size_t)n * 64;
    float sk = 0.f;
#pragma unroll 8
    for (int j = 0; j < 64; ++j)
        sk += n0r[j] * w_lin2_s[j * 64 + lane];
    sk *= sc_l2;
    const float* hsr = h_s + (size_t)n * 32;
#pragma unroll 8
    for (int u = 0; u < 32; ++u)
        sk += (hsr[u] * rs160) * w_res_s[(u * 5 + sp) * 64 + lane];
    float act = silu_f(sk);

    float wc = 0.f;
#pragma unroll
    for (int j = 0; j < 16; ++j)
        wc += w_out1[lane * 16 + j] * w_out2[j];
    float e = act * wc;
    e += __shfl_xor(e, 1);
    e += __shfl_xor(e, 2);
    e += __shfl_xor(e, 4);
    e += __shfl_xor(e, 8);
    e += __shfl_xor(e, 16);
    if (lane == 0)
        out[n] = e * 0.17677669529663687f * 0.25f;
}

extern "C" void kernel_launch(void* const* d_in, const int* in_sizes, int n_in,
                              void* d_out, int out_size, void* d_ws, size_t ws_size,
                              hipStream_t stream) {
    const float* evec     = (const float*)d_in[0];
    const int*   species  = (const int*)d_in[1];
    const int*   senders  = (const int*)d_in[2];
    const int*   receivers= (const int*)d_in[3];
    const float* embed_w  = (const float*)d_in[4];
    const float* w_res_s  = (const float*)d_in[5];
    const float* w_res_v  = (const float*)d_in[6];
    const float* w_lin1_s = (const float*)d_in[7];
    const float* w_lin1_v = (const float*)d_in[8];
    const float* mlp_w0   = (const float*)d_in[9];
    const float* mlp_w1   = (const float*)d_in[10];
    const float* mlp_w2   = (const float*)d_in[11];
    const float* w_lin2_s = (const float*)d_in[12];
    const float* w_lin2_v = (const float*)d_in[13];
    const float* w_out1   = (const float*)d_in[14];
    const float* w_out2   = (const float*)d_in[15];
    (void)w_res_v;

    float* ws = (float*)d_ws;
    size_t off = 0;
    auto alloc = [&](size_t n) { float* p = ws + off; off += (n + 3) & ~(size_t)3; return p; };

    float* h_s  = alloc(NN * 32);
    float* feat = alloc((size_t)NN * 128);
    float* n0b  = alloc(NN * 64);          // n0b, n1b, deg contiguous: one memset
    float* n1b  = alloc(NN * 192);
    int*   deg  = (int*)alloc(NN);
    float* tab0 = alloc((size_t)(TB + 1) * 64);
    float* tab1 = alloc((size_t)(TB + 1) * 64);
    float* fs   = alloc(160);
    int*   row_start = (int*)alloc(NN + 1);
    int*   cursor    = (int*)alloc(NN);
    int*   csr_send  = (int*)alloc(EE);
    int*   csr_recv  = (int*)alloc(EE);
    float* ev4       = alloc((size_t)EE * 4);

    // zero n0b + n1b + deg in one shot (contiguous)
    hipMemsetAsync(n0b, 0, (size_t)NN * 257 * 4, stream);
    // table (2*(TB+1) waves) + fs (3 spare waves)
    k_table<<<(2 * (TB + 1) + 3 + 3) / 4, 256, 0, stream>>>(
        mlp_w0, mlp_w1, mlp_w2, embed_w, w_lin1_s, tab0, tab1, fs);
    k_hist<<<(EE + 255) / 256, 256, 0, stream>>>(receivers, deg);
    k_scan<<<1, 256, 0, stream>>>(deg, row_start, cursor);
    k_fill<<<(EE + 255) / 256, 256, 0, stream>>>(receivers, senders, species, evec,
                                                 cursor, csr_send, csr_recv, ev4);

    // ---- layer 0 ----
    k_mega<0><<<EE / 256, 256, 0, stream>>>(
        csr_send, csr_recv, ev4, row_start, fs, feat, tab0, n0b, n1b);
    k_upd0_prep<<<12500, 256, 0, stream>>>(
        species, n0b, n1b, w_lin2_s, w_lin2_v, w_res_s, embed_w,
        w_lin1_s + 1024, w_lin1_v + 1024, h_s, feat);

    // ---- layer 1 (last) ----
    hipMemsetAsync(n0b, 0, (size_t)NN * 64 * 4, stream);
    k_mega<1><<<EE / 256, 256, 0, stream>>>(
        csr_send, csr_recv, ev4, row_start, fs, feat, tab1, n0b, n1b);
    k_node_update_last<<<12500, 256, 0, stream>>>(
        species, n0b, w_lin2_s + 4096, w_res_s + 10240, h_s,
        w_out1, w_out2, (float*)d_out);
}

// Round 15
// 551.769 us; speedup vs baseline: 6.5620x; 1.0131x over previous
//
#include <hip/hip_runtime.h>
#include <math.h>

#define NN 50000
#define EE 800000
#define TB 4096            // radial table bins; nodes = TB+1 over r in [0,5]

typedef float f32x2 __attribute__((ext_vector_type(2)));
typedef float f32x4  __attribute__((ext_vector_type(4)));

__device__ __forceinline__ float silu_f(float x) {
    return x / (1.f + __expf(-x));
}

// ---------------- radial MLP -> lookup table (one wave per (layer,bin)) + fs ----------
__global__ __launch_bounds__(256) void k_table(
        const float* __restrict__ mlp_w0, const float* __restrict__ mlp_w1,
        const float* __restrict__ mlp_w2,
        const float* __restrict__ embed_w, const float* __restrict__ w_lin1_s,
        float* __restrict__ tab0, float* __restrict__ tab1, float* __restrict__ fs) {
    __shared__ float stage[4][128];
    int wv = threadIdx.x >> 6, lane = threadIdx.x & 63;
    int wid = blockIdx.x * 4 + wv;
    int widc = wid > 2 * TB + 1 ? 2 * TB + 1 : wid;
    int l = widc / (TB + 1);
    int bin = widc - l * (TB + 1);
    float* st = stage[wv];

    float r = 5.f * (float)bin / (float)TB;
    if (r < 1e-6f) r = 1e-6f;
    float ir = 1.f / r;
    float xx = r * 0.2f;
    float env = 0.f;
    if (xx < 1.f) {
        float x2 = xx * xx, x3 = x2 * xx, x6 = x3 * x3, x7 = x6 * xx, x8 = x7 * xx;
        env = 1.f - 28.f * x6 + 48.f * x7 - 21.f * x8;
    }
    float coef = 0.6324555320336759f * env * ir;   // sqrt(2/5)*env/r
    const float w5 = 0.6283185307179586f;          // pi/5

    float p = 0.f;
#pragma unroll
    for (int k = 0; k < 8; ++k)
        p += coef * __sinf(w5 * (float)(k + 1) * r) * mlp_w0[l * 512 + k * 64 + lane];
    float a1 = silu_f(p * 0.35355339059327373f);   // /sqrt(8)
    st[lane] = a1;
    __syncthreads();
    float q = 0.f;
    for (int j = 0; j < 64; ++j) q += st[j] * mlp_w1[l * 4096 + j * 64 + lane];
    float a2 = silu_f(q * 0.125f);                 // /sqrt(64)
    __syncthreads();
    st[lane] = a2;
    __syncthreads();
    float wlo = 0.f, whi = 0.f;
    for (int h = 0; h < 64; ++h) {
        float a = st[h];
        wlo += a * mlp_w2[l * 8192 + h * 128 + lane];
        whi += a * mlp_w2[l * 8192 + h * 128 + 64 + lane];
    }
    __syncthreads();
    st[lane] = wlo;        // w[0..63]
    st[64 + lane] = whi;   // w[64..127]
    __syncthreads();
    if (wid <= 2 * TB + 1 && lane < 16) {
        f32x4 o;
        if (l == 0) {
            o[0] = st[lane]; o[1] = st[64 + lane];
            o[2] = st[16 + lane]; o[3] = st[80 + lane];
            ((f32x4*)tab0)[bin * 16 + lane] = o;
        } else {
            o[0] = st[lane]; o[1] = st[32 + lane];
            o[2] = st[16 + lane]; o[3] = st[48 + lane];
            ((f32x4*)tab1)[bin * 16 + lane] = o;
        }
    }
    int ft = (wid - (2 * TB + 2)) * 64 + lane;
    if (wid >= 2 * TB + 2 && ft < 160) {
        int sp = ft >> 5, v = ft & 31;
        float acc = 0.f;
#pragma unroll
        for (int u = 0; u < 32; ++u) acc += embed_w[sp * 32 + u] * w_lin1_s[u * 32 + v];
        fs[ft] = acc * 0.4472135954999579f * 0.17677669529663687f;
    }
}

// ---------------- CSR build ----------------
__global__ void k_hist(const int* __restrict__ recv, int* __restrict__ deg) {
    int e = blockIdx.x * 256 + threadIdx.x;
    if (e < EE) atomicAdd(&deg[recv[e]], 1);
}

__global__ __launch_bounds__(1024) void k_scan(
        const int* __restrict__ deg, int* __restrict__ row_start,
        int* __restrict__ cursor) {
    __shared__ int part[1024];
    int t = threadIdx.x;
    int lo = t * 49, hi = lo + 49;
    if (hi > NN) hi = NN;
    if (lo > NN) lo = NN;
    int s = 0;
    for (int i = lo; i < hi; ++i) s += deg[i];
    part[t] = s;
    __syncthreads();
    for (int d = 1; d < 1024; d <<= 1) {
        int add = (t >= d) ? part[t - d] : 0;
        __syncthreads();
        part[t] += add;
        __syncthreads();
    }
    int run = part[t] - s;   // exclusive prefix
    for (int i = lo; i < hi; ++i) {
        row_start[i] = run;
        cursor[i] = run;
        run += deg[i];
    }
    if (t == 1023) row_start[NN] = run;
}

// fill + gather + geometry fused: ev4[p] = {shx, shy, shz, xb}
__global__ void k_fill(const int* __restrict__ recv, const int* __restrict__ senders,
                       const int* __restrict__ species, const float* __restrict__ evec,
                       int* __restrict__ cursor,
                       int* __restrict__ csr_send, int* __restrict__ csr_recv,
                       float* __restrict__ ev4) {
    int e = blockIdx.x * 256 + threadIdx.x;
    if (e >= EE) return;
    int rv = recv[e];
    int p = atomicAdd(&cursor[rv], 1);
    int snd = senders[e];
    csr_send[p] = snd | (species[snd] << 24);
    csr_recv[p] = rv;
    float x = evec[e * 3 + 0], y = evec[e * 3 + 1], z = evec[e * 3 + 2];
    float r = sqrtf(x * x + y * y + z * z + 1e-12f);
    float ir = 1.f / r;
    const float s3 = 1.7320508075688772f;
    float xb = r * ((float)TB / 5.f);
    if (xb > (float)TB) xb = (float)TB;   // r>=5 -> tab[TB] == 0 exactly
    f32x4 o;
    o[0] = s3 * x * ir;
    o[1] = s3 * y * ir;
    o[2] = s3 * z * ir;
    o[3] = xb;
    *(f32x4*)(ev4 + (size_t)p * 4) = o;
}

// ---------------- fused table-lookup edge kernel, minimal-LDS version ----------------
// Only LDS object is the scatter window. Per-edge data comes from global via
// same-address vector loads (memory pipe). Channel-sparse init/flush.
#define WROWS 20
#define WSTRIDE 260
template<int L>
__global__ __launch_bounds__(256) void k_mega(
    const int* __restrict__ csr_send, const int* __restrict__ csr_recv,
    const float* __restrict__ ev4, const int* __restrict__ row_start,
    const float* __restrict__ fs, const float* __restrict__ feat,
    const float* __restrict__ tab,
    float* __restrict__ n0, float* __restrict__ n1) {
    __shared__ float accw[WROWS * WSTRIDE];   // 20.8 KB
    int tid = threadIdx.x;
    int p0 = blockIdx.x * 256;
    int lane = tid & 63;
    int wv = tid >> 6;
    int c0 = lane & 15;
    int rg = lane >> 4;

    int node_base = __builtin_amdgcn_readfirstlane(csr_recv[p0]);
    int last_rv   = __builtin_amdgcn_readfirstlane(csr_recv[p0 + 255]);

    // zero only channel-chunks the emits touch (L0: 32 chunks/row, L1: 16)
    const int NCH4 = (L == 0) ? 32 : 16;
    for (int i = tid; i < WROWS * NCH4; i += 256) {
        int row = i / NCH4, k = i - row * NCH4;
        int chunk = (L == 0) ? ((k >> 3) * 16 + (k & 7)) : k;
        *(f32x4*)&accw[row * WSTRIDE + chunk * 4] = (f32x4)0.f;
    }
    __syncthreads();

    const f32x4* tabv = (const f32x4*)tab;
    const f32x4* feat4 = (const f32x4*)feat;
    const float rs3 = 0.5773502691896258f;

    for (int t = 0; t < 4; ++t) {
        int tOff = wv * 64 + t * 16;
        f32x4 eshv[4], dv[4];
        int wr[4], snd[4];
        float es0[4], es1[4];
#pragma unroll
        for (int j = 0; j < 4; ++j) {
            int gidx = p0 + tOff + rg * 4 + j;   // same addr across the 16 c0 lanes
            f32x4 g = *(const f32x4*)(ev4 + (size_t)gidx * 4);
            snd[j] = csr_send[gidx];
            wr[j] = csr_recv[gidx] - node_base;
            eshv[j] = g;
            float xb = g[3];
            int bin = (int)xb;
            if (bin >= TB) bin = TB - 1;
            float fr = xb - (float)bin;
            f32x4 lo = tabv[bin * 16 + c0];
            f32x4 hi = tabv[bin * 16 + 16 + c0];
            dv[j] = lo + fr * (hi - lo);
            if (L == 0) {
                int spp = ((unsigned)snd[j]) >> 24;
                es0[j] = fs[spp * 32 + c0];
                es1[j] = fs[spp * 32 + 16 + c0];
            }
        }

#pragma unroll
        for (int b = 0; b < 2; ++b) {
            int u = b * 16 + c0;
            float s0 = 0.f, s1 = 0.f, s2 = 0.f, s3v = 0.f;
            int curw = wr[0];
            auto emit = [&](int wrow) {
                if (L == 0) {
                    if (wrow < WROWS) {
                        float* arow = accw + wrow * WSTRIDE;
                        atomicAdd(arow + u, s0);
                        atomicAdd(arow + 64 + u, s1);
                        atomicAdd(arow + 128 + u, s2);
                        atomicAdd(arow + 192 + u, s3v);
                    } else {
                        int rvn = node_base + wrow;
                        atomicAdd(n0 + (size_t)rvn * 64 + u, s0);
                        atomicAdd(n1 + (size_t)rvn * 192 + u, s1);
                        atomicAdd(n1 + (size_t)rvn * 192 + 64 + u, s2);
                        atomicAdd(n1 + (size_t)rvn * 192 + 128 + u, s3v);
                    }
                } else {
                    if (wrow < WROWS) {
                        float* arow = accw + wrow * WSTRIDE;
                        atomicAdd(arow + u, s0);
                        atomicAdd(arow + 32 + u, s1);
                    } else {
                        int rvn = node_base + wrow;
                        atomicAdd(n0 + (size_t)rvn * 64 + u, s0);
                        atomicAdd(n0 + (size_t)rvn * 64 + 32 + u, s1);
                    }
                }
            };
#pragma unroll
            for (int j = 0; j < 4; ++j) {
                int wrow = wr[j];
                if (j > 0 && wrow != curw) {
                    emit(curw);
                    s0 = s1 = s2 = s3v = 0.f;
                    curw = wrow;
                }
                f32x4 esh = eshv[j];
                float dA = dv[j][2 * b];
                float dB = dv[j][2 * b + 1];
                if (L == 0) {
                    float es = b ? es1[j] : es0[j];
                    float t3 = dB * es;
                    s0  += dA * es;
                    s1  += t3 * esh[0];
                    s2  += t3 * esh[1];
                    s3v += t3 * esh[2];
                } else {
                    int s = snd[j] & 0xFFFFFF;
                    f32x4 f4 = feat4[(size_t)s * 32 + u];
                    float dot = f4[1] * esh[0] + f4[2] * esh[1] + f4[3] * esh[2];
                    s0 += dA * f4[0];
                    s1 += dB * dot * rs3;
                }
            }
            // tree-merge final runs across the 4 rg groups (receiver-sorted => exact)
            int alive = 1;
            {
                int pw = __shfl_xor(curw, 16);
                float t0 = __shfl_xor(s0, 16), t1 = __shfl_xor(s1, 16);
                float t2 = 0.f, t3m = 0.f;
                if (L == 0) { t2 = __shfl_xor(s2, 16); t3m = __shfl_xor(s3v, 16); }
                if (pw == curw) {
                    s0 += t0; s1 += t1;
                    if (L == 0) { s2 += t2; s3v += t3m; }
                    if (lane & 16) alive = 0;
                }
            }
            {
                int pw = __shfl_xor(curw, 32);
                int pal = __shfl_xor(alive, 32);
                float t0 = __shfl_xor(s0, 32), t1 = __shfl_xor(s1, 32);
                float t2 = 0.f, t3m = 0.f;
                if (L == 0) { t2 = __shfl_xor(s2, 32); t3m = __shfl_xor(s3v, 32); }
                if (alive && pal && pw == curw) {
                    s0 += t0; s1 += t1;
                    if (L == 0) { s2 += t2; s3v += t3m; }
                    if (lane & 32) alive = 0;
                }
            }
            if (alive) emit(curw);
        }
    }
    __syncthreads();

    // ---- channel-sparse vectorized flush ----
    int span = last_rv - node_base;
    if (span > WROWS - 1) span = WROWS - 1;
    if (L == 0) {
        // 8 rows/pass; 32 threads per row cover the 32 used chunks
        int rsub = tid >> 5;
        int k = tid & 31;
        int chunk = (k >> 3) * 16 + (k & 7);
        int seg = k >> 3;              // 0: n0; 1..3: n1 comp seg-1
        int u4 = (k & 7) * 4;
        for (int wl0 = 0; wl0 <= span; wl0 += 8) {
            int wl = wl0 + rsub;
            if (wl > span) continue;
            int n = node_base + wl;
            f32x4 v = *(f32x4*)&accw[wl * WSTRIDE + chunk * 4];
            bool interior = (row_start[n] >= p0) && (row_start[n + 1] <= p0 + 256);
            float* dest = (seg == 0) ? (n0 + (size_t)n * 64 + u4)
                                     : (n1 + (size_t)n * 192 + (seg - 1) * 64 + u4);
            if (interior) {
                *(f32x4*)dest = v;
            } else {
                if (v[0] != 0.f) atomicAdd(dest + 0, v[0]);
                if (v[1] != 0.f) atomicAdd(dest + 1, v[1]);
                if (v[2] != 0.f) atomicAdd(dest + 2, v[2]);
                if (v[3] != 0.f) atomicAdd(dest + 3, v[3]);
            }
        }
    } else {
        // 16 rows/pass; 16 threads per row cover channels 0..63
        int rsub = tid >> 4;
        int k = tid & 15;
        for (int wl0 = 0; wl0 <= span; wl0 += 16) {
            int wl = wl0 + rsub;
            if (wl > span) continue;
            int n = node_base + wl;
            f32x4 v = *(f32x4*)&accw[wl * WSTRIDE + k * 4];
            bool interior = (row_start[n] >= p0) && (row_start[n + 1] <= p0 + 256);
            float* dest = n0 + (size_t)n * 64 + k * 4;
            if (interior) {
                *(f32x4*)dest = v;
            } else {
                if (v[0] != 0.f) atomicAdd(dest + 0, v[0]);
                if (v[1] != 0.f) atomicAdd(dest + 1, v[1]);
                if (v[2] != 0.f) atomicAdd(dest + 2, v[2]);
                if (v[3] != 0.f) atomicAdd(dest + 3, v[3]);
            }
        }
    }
}

// ---------------- fused layer-0 node update + lin1 feat prep (wave-per-node) ----------
__global__ __launch_bounds__(256) void k_upd0_prep(
        const int* __restrict__ species,
        const float* __restrict__ n0, const float* __restrict__ n1,
        const float* __restrict__ w_lin2_s, const float* __restrict__ w_lin2_v,
        const float* __restrict__ w_res_s, const float* __restrict__ embed_w,
        const float* __restrict__ w_lin1_s, const float* __restrict__ w_lin1_v,
        float* __restrict__ h_s, float* __restrict__ feat) {
    __shared__ float stage[4][128];
    int lane = threadIdx.x & 63;
    int wv = threadIdx.x >> 6;
    int n = blockIdx.x * 4 + wv;
    n = __builtin_amdgcn_readfirstlane(n);
    int sp = __builtin_amdgcn_readfirstlane(species[n]);
    const float sc_l2 = 1.f / 128.f;
    const float rr = 0.07905694150420949f * 0.4472135954999579f;  // rs160 * rs5

    const float* n0r = n0 + (size_t)n * 64;
    float sk = 0.f;
#pragma unroll 8
    for (int j = 0; j < 64; ++j)
        sk += n0r[j] * w_lin2_s[j * 64 + lane];
    sk *= sc_l2;
#pragma unroll 8
    for (int u = 0; u < 32; ++u)
        sk += (embed_w[sp * 32 + u] * rr) * w_res_s[(u * 5 + sp) * 64 + lane];
    float act = silu_f(sk);
    float gmine = __shfl(act, 32 + (lane & 31));

    const float* n1r = n1 + (size_t)n * 192;
    int i0 = lane >> 5, v = lane & 31;
    float acc0 = 0.f, acc2 = 0.f;
#pragma unroll 8
    for (int u = 0; u < 32; ++u) {        // o1b half of n1 is zero at L0
        float wlv = w_lin2_v[u * 32 + v];
        acc0 += n1r[i0 * 64 + u] * wlv;
        acc2 += n1r[128 + u] * wlv;
    }
    float* st = stage[wv];
    st[32 + i0 * 32 + v] = acc0 * sc_l2 * gmine;
    if (lane < 32) {
        st[v] = act;
        st[96 + v] = acc2 * sc_l2 * gmine;
        h_s[(size_t)n * 32 + v] = act;
    }
    __syncthreads();

    const float rs32 = 0.17677669529663687f;
    float accA = 0.f, accB = 0.f;
#pragma unroll 8
    for (int u = 0; u < 32; ++u) {
        float wsv = w_lin1_s[u * 32 + v];
        float wvv = w_lin1_v[u * 32 + v];
        float xs = st[u];
        float xx = st[32 + u];
        float xy = st[64 + u];
        float xz = st[96 + u];
        float inA = i0 ? xy : xs;
        float wA  = i0 ? wvv : wsv;
        float inB = i0 ? xz : xx;
        accA += inA * wA;
        accB += inB * wvv;
    }
    f32x2 o;
    o[0] = accA * rs32;
    o[1] = accB * rs32;
    *(f32x2*)(feat + (size_t)n * 128 + v * 4 + i0 * 2) = o;
}

// ---------------- final node update: scalar-only + fused readout ----------------
__global__ __launch_bounds__(256) void k_node_update_last(
        const int* __restrict__ species,
        const float* __restrict__ n0,
        const float* __restrict__ w_lin2_s, const float* __restrict__ w_res_s,
        const float* __restrict__ h_s,
        const float* __restrict__ w_out1, const float* __restrict__ w_out2,
        float* __restrict__ out) {
    int lane = threadIdx.x & 63;
    int n = blockIdx.x * 4 + (threadIdx.x >> 6);
    n = __builtin_amdgcn_readfirstlane(n);
    if (lane >= 32) return;
    int sp = __builtin_amdgcn_readfirstlane(species[n]);
    const float sc_l2 = 1.f / 128.f;
    const float rs160 = 0.07905694150420949f;

    const float* n0r = n0 + (size_t)n * 64;
    float sk = 0.f;
#pragma unroll 8
    for (int j = 0; j < 64; ++j)
        sk += n0r[j] * w_lin2_s[j * 64 + lane];
    sk *= sc_l2;
    const float* hsr = h_s + (size_t)n * 32;
#pragma unroll 8
    for (int u = 0; u < 32; ++u)
        sk += (hsr[u] * rs160) * w_res_s[(u * 5 + sp) * 64 + lane];
    float act = silu_f(sk);

    float wc = 0.f;
#pragma unroll
    for (int j = 0; j < 16; ++j)
        wc += w_out1[lane * 16 + j] * w_out2[j];
    float e = act * wc;
    e += __shfl_xor(e, 1);
    e += __shfl_xor(e, 2);
    e += __shfl_xor(e, 4);
    e += __shfl_xor(e, 8);
    e += __shfl_xor(e, 16);
    if (lane == 0)
        out[n] = e * 0.17677669529663687f * 0.25f;
}

extern "C" void kernel_launch(void* const* d_in, const int* in_sizes, int n_in,
                              void* d_out, int out_size, void* d_ws, size_t ws_size,
                              hipStream_t stream) {
    const float* evec     = (const float*)d_in[0];
    const int*   species  = (const int*)d_in[1];
    const int*   senders  = (const int*)d_in[2];
    const int*   receivers= (const int*)d_in[3];
    const float* embed_w  = (const float*)d_in[4];
    const float* w_res_s  = (const float*)d_in[5];
    const float* w_res_v  = (const float*)d_in[6];
    const float* w_lin1_s = (const float*)d_in[7];
    const float* w_lin1_v = (const float*)d_in[8];
    const float* mlp_w0   = (const float*)d_in[9];
    const float* mlp_w1   = (const float*)d_in[10];
    const float* mlp_w2   = (const float*)d_in[11];
    const float* w_lin2_s = (const float*)d_in[12];
    const float* w_lin2_v = (const float*)d_in[13];
    const float* w_out1   = (const float*)d_in[14];
    const float* w_out2   = (const float*)d_in[15];
    (void)w_res_v;

    float* ws = (float*)d_ws;
    size_t off = 0;
    auto alloc = [&](size_t n) { float* p = ws + off; off += (n + 3) & ~(size_t)3; return p; };

    float* h_s  = alloc(NN * 32);
    float* feat = alloc((size_t)NN * 128);
    float* n0b  = alloc(NN * 64);          // n0b, n1b, deg contiguous: one memset
    float* n1b  = alloc(NN * 192);
    int*   deg  = (int*)alloc(NN);
    float* tab0 = alloc((size_t)(TB + 1) * 64);
    float* tab1 = alloc((size_t)(TB + 1) * 64);
    float* fs   = alloc(160);
    int*   row_start = (int*)alloc(NN + 1);
    int*   cursor    = (int*)alloc(NN);
    int*   csr_send  = (int*)alloc(EE);
    int*   csr_recv  = (int*)alloc(EE);
    float* ev4       = alloc((size_t)EE * 4);

    hipMemsetAsync(n0b, 0, (size_t)NN * 257 * 4, stream);   // n0b + n1b + deg
    k_table<<<(2 * (TB + 1) + 3 + 3) / 4, 256, 0, stream>>>(
        mlp_w0, mlp_w1, mlp_w2, embed_w, w_lin1_s, tab0, tab1, fs);
    k_hist<<<(EE + 255) / 256, 256, 0, stream>>>(receivers, deg);
    k_scan<<<1, 1024, 0, stream>>>(deg, row_start, cursor);
    k_fill<<<(EE + 255) / 256, 256, 0, stream>>>(receivers, senders, species, evec,
                                                 cursor, csr_send, csr_recv, ev4);

    // ---- layer 0 ----
    k_mega<0><<<EE / 256, 256, 0, stream>>>(
        csr_send, csr_recv, ev4, row_start, fs, feat, tab0, n0b, n1b);
    k_upd0_prep<<<12500, 256, 0, stream>>>(
        species, n0b, n1b, w_lin2_s, w_lin2_v, w_res_s, embed_w,
        w_lin1_s + 1024, w_lin1_v + 1024, h_s, feat);

    // ---- layer 1 (last) ----
    hipMemsetAsync(n0b, 0, (size_t)NN * 64 * 4, stream);
    k_mega<1><<<EE / 256, 256, 0, stream>>>(
        csr_send, csr_recv, ev4, row_start, fs, feat, tab1, n0b, n1b);
    k_node_update_last<<<12500, 256, 0, stream>>>(
        species, n0b, w_lin2_s + 4096, w_res_s + 10240, h_s,
        w_out1, w_out2, (float*)d_out);
}

// Round 16
// 551.549 us; speedup vs baseline: 6.5646x; 1.0004x over previous
//
#include <hip/hip_runtime.h>
#include <math.h>

#define NN 50000
#define EE 800000
#define TB 4096            // radial table bins; nodes = TB+1 over r in [0,5]

typedef float f32x2 __attribute__((ext_vector_type(2)));
typedef float f32x4  __attribute__((ext_vector_type(4)));

__device__ __forceinline__ float silu_f(float x) {
    return x / (1.f + __expf(-x));
}

// ---------------- radial MLP -> lookup table (one wave per (layer,bin)) + fs ----------
__global__ __launch_bounds__(256) void k_table(
        const float* __restrict__ mlp_w0, const float* __restrict__ mlp_w1,
        const float* __restrict__ mlp_w2,
        const float* __restrict__ embed_w, const float* __restrict__ w_lin1_s,
        float* __restrict__ tab0, float* __restrict__ tab1, float* __restrict__ fs) {
    __shared__ float stage[4][128];
    int wv = threadIdx.x >> 6, lane = threadIdx.x & 63;
    int wid = blockIdx.x * 4 + wv;
    int widc = wid > 2 * TB + 1 ? 2 * TB + 1 : wid;
    int l = widc / (TB + 1);
    int bin = widc - l * (TB + 1);
    float* st = stage[wv];

    float r = 5.f * (float)bin / (float)TB;
    if (r < 1e-6f) r = 1e-6f;
    float ir = 1.f / r;
    float xx = r * 0.2f;
    float env = 0.f;
    if (xx < 1.f) {
        float x2 = xx * xx, x3 = x2 * xx, x6 = x3 * x3, x7 = x6 * xx, x8 = x7 * xx;
        env = 1.f - 28.f * x6 + 48.f * x7 - 21.f * x8;
    }
    float coef = 0.6324555320336759f * env * ir;   // sqrt(2/5)*env/r
    const float w5 = 0.6283185307179586f;          // pi/5

    float p = 0.f;
#pragma unroll
    for (int k = 0; k < 8; ++k)
        p += coef * __sinf(w5 * (float)(k + 1) * r) * mlp_w0[l * 512 + k * 64 + lane];
    float a1 = silu_f(p * 0.35355339059327373f);   // /sqrt(8)
    st[lane] = a1;
    __syncthreads();
    float q = 0.f;
    for (int j = 0; j < 64; ++j) q += st[j] * mlp_w1[l * 4096 + j * 64 + lane];
    float a2 = silu_f(q * 0.125f);                 // /sqrt(64)
    __syncthreads();
    st[lane] = a2;
    __syncthreads();
    float wlo = 0.f, whi = 0.f;
    for (int h = 0; h < 64; ++h) {
        float a = st[h];
        wlo += a * mlp_w2[l * 8192 + h * 128 + lane];
        whi += a * mlp_w2[l * 8192 + h * 128 + 64 + lane];
    }
    __syncthreads();
    st[lane] = wlo;        // w[0..63]
    st[64 + lane] = whi;   // w[64..127]
    __syncthreads();
    if (wid <= 2 * TB + 1 && lane < 16) {
        f32x4 o;
        if (l == 0) {
            o[0] = st[lane]; o[1] = st[64 + lane];
            o[2] = st[16 + lane]; o[3] = st[80 + lane];
            ((f32x4*)tab0)[bin * 16 + lane] = o;
        } else {
            o[0] = st[lane]; o[1] = st[32 + lane];
            o[2] = st[16 + lane]; o[3] = st[48 + lane];
            ((f32x4*)tab1)[bin * 16 + lane] = o;
        }
    }
    int ft = (wid - (2 * TB + 2)) * 64 + lane;
    if (wid >= 2 * TB + 2 && ft < 160) {
        int sp = ft >> 5, v = ft & 31;
        float acc = 0.f;
#pragma unroll
        for (int u = 0; u < 32; ++u) acc += embed_w[sp * 32 + u] * w_lin1_s[u * 32 + v];
        fs[ft] = acc * 0.4472135954999579f * 0.17677669529663687f;
    }
}

// ---------------- CSR build ----------------
__global__ void k_hist(const int* __restrict__ recv, int* __restrict__ deg) {
    int e = blockIdx.x * 256 + threadIdx.x;
    if (e < EE) atomicAdd(&deg[recv[e]], 1);
}

__global__ __launch_bounds__(1024) void k_scan(
        const int* __restrict__ deg, int* __restrict__ row_start,
        int* __restrict__ cursor) {
    __shared__ int part[1024];
    int t = threadIdx.x;
    int lo = t * 49, hi = lo + 49;
    if (hi > NN) hi = NN;
    if (lo > NN) lo = NN;
    int s = 0;
    for (int i = lo; i < hi; ++i) s += deg[i];
    part[t] = s;
    __syncthreads();
    for (int d = 1; d < 1024; d <<= 1) {
        int add = (t >= d) ? part[t - d] : 0;
        __syncthreads();
        part[t] += add;
        __syncthreads();
    }
    int run = part[t] - s;   // exclusive prefix
    for (int i = lo; i < hi; ++i) {
        row_start[i] = run;
        cursor[i] = run;
        run += deg[i];
    }
    if (t == 1023) row_start[NN] = run;
}

// fill + gather + geometry fused: ev4[p] = {shx, shy, shz, xb}
__global__ void k_fill(const int* __restrict__ recv, const int* __restrict__ senders,
                       const int* __restrict__ species, const float* __restrict__ evec,
                       int* __restrict__ cursor,
                       int* __restrict__ csr_send, int* __restrict__ csr_recv,
                       float* __restrict__ ev4) {
    int e = blockIdx.x * 256 + threadIdx.x;
    if (e >= EE) return;
    int rv = recv[e];
    int p = atomicAdd(&cursor[rv], 1);
    int snd = senders[e];
    csr_send[p] = snd | (species[snd] << 24);
    csr_recv[p] = rv;
    float x = evec[e * 3 + 0], y = evec[e * 3 + 1], z = evec[e * 3 + 2];
    float r = sqrtf(x * x + y * y + z * z + 1e-12f);
    float ir = 1.f / r;
    const float s3 = 1.7320508075688772f;
    float xb = r * ((float)TB / 5.f);
    if (xb > (float)TB) xb = (float)TB;   // r>=5 -> tab[TB] == 0 exactly
    f32x4 o;
    o[0] = s3 * x * ir;
    o[1] = s3 * y * ir;
    o[2] = s3 * z * ir;
    o[3] = xb;
    *(f32x4*)(ev4 + (size_t)p * 4) = o;
}

// ---------------- fused table-lookup edge kernel, minimal-LDS version ----------------
// Only LDS object is the scatter window. Per-edge data comes from global via
// same-address vector loads (memory pipe). Channel-sparse init/flush.
#define WROWS 20
#define WSTRIDE 260
template<int L>
__global__ __launch_bounds__(256) void k_mega(
    const int* __restrict__ csr_send, const int* __restrict__ csr_recv,
    const float* __restrict__ ev4, const int* __restrict__ row_start,
    const float* __restrict__ fs, const float* __restrict__ feat,
    const float* __restrict__ tab,
    float* __restrict__ n0, float* __restrict__ n1) {
    __shared__ float accw[WROWS * WSTRIDE];   // 20.8 KB
    int tid = threadIdx.x;
    int p0 = blockIdx.x * 256;
    int lane = tid & 63;
    int wv = tid >> 6;
    int c0 = lane & 15;
    int rg = lane >> 4;

    int node_base = __builtin_amdgcn_readfirstlane(csr_recv[p0]);
    int last_rv   = __builtin_amdgcn_readfirstlane(csr_recv[p0 + 255]);

    // zero only channel-chunks the emits touch (L0: 32 chunks/row, L1: 16)
    const int NCH4 = (L == 0) ? 32 : 16;
    for (int i = tid; i < WROWS * NCH4; i += 256) {
        int row = i / NCH4, k = i - row * NCH4;
        int chunk = (L == 0) ? ((k >> 3) * 16 + (k & 7)) : k;
        *(f32x4*)&accw[row * WSTRIDE + chunk * 4] = (f32x4)0.f;
    }
    __syncthreads();

    const f32x4* tabv = (const f32x4*)tab;
    const f32x4* feat4 = (const f32x4*)feat;
    const float rs3 = 0.5773502691896258f;

    for (int t = 0; t < 4; ++t) {
        int tOff = wv * 64 + t * 16;
        f32x4 eshv[4], dv[4];
        int wr[4], snd[4];
        float es0[4], es1[4];
#pragma unroll
        for (int j = 0; j < 4; ++j) {
            int gidx = p0 + tOff + rg * 4 + j;   // same addr across the 16 c0 lanes
            f32x4 g = *(const f32x4*)(ev4 + (size_t)gidx * 4);
            snd[j] = csr_send[gidx];
            wr[j] = csr_recv[gidx] - node_base;
            eshv[j] = g;
            float xb = g[3];
            int bin = (int)xb;
            if (bin >= TB) bin = TB - 1;
            float fr = xb - (float)bin;
            f32x4 lo = tabv[bin * 16 + c0];
            f32x4 hi = tabv[bin * 16 + 16 + c0];
            dv[j] = lo + fr * (hi - lo);
            if (L == 0) {
                int spp = ((unsigned)snd[j]) >> 24;
                es0[j] = fs[spp * 32 + c0];
                es1[j] = fs[spp * 32 + 16 + c0];
            }
        }

#pragma unroll
        for (int b = 0; b < 2; ++b) {
            int u = b * 16 + c0;
            float s0 = 0.f, s1 = 0.f, s2 = 0.f, s3v = 0.f;
            int curw = wr[0];
            auto emit = [&](int wrow) {
                if (L == 0) {
                    if (wrow < WROWS) {
                        float* arow = accw + wrow * WSTRIDE;
                        atomicAdd(arow + u, s0);
                        atomicAdd(arow + 64 + u, s1);
                        atomicAdd(arow + 128 + u, s2);
                        atomicAdd(arow + 192 + u, s3v);
                    } else {
                        int rvn = node_base + wrow;
                        atomicAdd(n0 + (size_t)rvn * 64 + u, s0);
                        atomicAdd(n1 + (size_t)rvn * 192 + u, s1);
                        atomicAdd(n1 + (size_t)rvn * 192 + 64 + u, s2);
                        atomicAdd(n1 + (size_t)rvn * 192 + 128 + u, s3v);
                    }
                } else {
                    if (wrow < WROWS) {
                        float* arow = accw + wrow * WSTRIDE;
                        atomicAdd(arow + u, s0);
                        atomicAdd(arow + 32 + u, s1);
                    } else {
                        int rvn = node_base + wrow;
                        atomicAdd(n0 + (size_t)rvn * 64 + u, s0);
                        atomicAdd(n0 + (size_t)rvn * 64 + 32 + u, s1);
                    }
                }
            };
#pragma unroll
            for (int j = 0; j < 4; ++j) {
                int wrow = wr[j];
                if (j > 0 && wrow != curw) {
                    emit(curw);
                    s0 = s1 = s2 = s3v = 0.f;
                    curw = wrow;
                }
                f32x4 esh = eshv[j];
                float dA = dv[j][2 * b];
                float dB = dv[j][2 * b + 1];
                if (L == 0) {
                    float es = b ? es1[j] : es0[j];
                    float t3 = dB * es;
                    s0  += dA * es;
                    s1  += t3 * esh[0];
                    s2  += t3 * esh[1];
                    s3v += t3 * esh[2];
                } else {
                    int s = snd[j] & 0xFFFFFF;
                    f32x4 f4 = feat4[(size_t)s * 32 + u];
                    float dot = f4[1] * esh[0] + f4[2] * esh[1] + f4[3] * esh[2];
                    s0 += dA * f4[0];
                    s1 += dB * dot * rs3;
                }
            }
            // tree-merge final runs across the 4 rg groups (receiver-sorted => exact)
            int alive = 1;
            {
                int pw = __shfl_xor(curw, 16);
                float t0 = __shfl_xor(s0, 16), t1 = __shfl_xor(s1, 16);
                float t2 = 0.f, t3m = 0.f;
                if (L == 0) { t2 = __shfl_xor(s2, 16); t3m = __shfl_xor(s3v, 16); }
                if (pw == curw) {
                    s0 += t0; s1 += t1;
                    if (L == 0) { s2 += t2; s3v += t3m; }
                    if (lane & 16) alive = 0;
                }
            }
            {
                int pw = __shfl_xor(curw, 32);
                int pal = __shfl_xor(alive, 32);
                float t0 = __shfl_xor(s0, 32), t1 = __shfl_xor(s1, 32);
                float t2 = 0.f, t3m = 0.f;
                if (L == 0) { t2 = __shfl_xor(s2, 32); t3m = __shfl_xor(s3v, 32); }
                if (alive && pal && pw == curw) {
                    s0 += t0; s1 += t1;
                    if (L == 0) { s2 += t2; s3v += t3m; }
                    if (lane & 32) alive = 0;
                }
            }
            if (alive) emit(curw);
        }
    }
    __syncthreads();

    // ---- channel-sparse vectorized flush ----
    int span = last_rv - node_base;
    if (span > WROWS - 1) span = WROWS - 1;
    if (L == 0) {
        // 8 rows/pass; 32 threads per row cover the 32 used chunks
        int rsub = tid >> 5;
        int k = tid & 31;
        int chunk = (k >> 3) * 16 + (k & 7);
        int seg = k >> 3;              // 0: n0; 1..3: n1 comp seg-1
        int u4 = (k & 7) * 4;
        for (int wl0 = 0; wl0 <= span; wl0 += 8) {
            int wl = wl0 + rsub;
            if (wl > span) continue;
            int n = node_base + wl;
            f32x4 v = *(f32x4*)&accw[wl * WSTRIDE + chunk * 4];
            bool interior = (row_start[n] >= p0) && (row_start[n + 1] <= p0 + 256);
            float* dest = (seg == 0) ? (n0 + (size_t)n * 64 + u4)
                                     : (n1 + (size_t)n * 192 + (seg - 1) * 64 + u4);
            if (interior) {
                *(f32x4*)dest = v;
            } else {
                if (v[0] != 0.f) atomicAdd(dest + 0, v[0]);
                if (v[1] != 0.f) atomicAdd(dest + 1, v[1]);
                if (v[2] != 0.f) atomicAdd(dest + 2, v[2]);
                if (v[3] != 0.f) atomicAdd(dest + 3, v[3]);
            }
        }
    } else {
        // 16 rows/pass; 16 threads per row cover channels 0..63
        int rsub = tid >> 4;
        int k = tid & 15;
        for (int wl0 = 0; wl0 <= span; wl0 += 16) {
            int wl = wl0 + rsub;
            if (wl > span) continue;
            int n = node_base + wl;
            f32x4 v = *(f32x4*)&accw[wl * WSTRIDE + k * 4];
            bool interior = (row_start[n] >= p0) && (row_start[n + 1] <= p0 + 256);
            float* dest = n0 + (size_t)n * 64 + k * 4;
            if (interior) {
                *(f32x4*)dest = v;
            } else {
                if (v[0] != 0.f) atomicAdd(dest + 0, v[0]);
                if (v[1] != 0.f) atomicAdd(dest + 1, v[1]);
                if (v[2] != 0.f) atomicAdd(dest + 2, v[2]);
                if (v[3] != 0.f) atomicAdd(dest + 3, v[3]);
            }
        }
    }
}

// ---------------- fused layer-0 node update + lin1 feat prep (wave-per-node) ----------
__global__ __launch_bounds__(256) void k_upd0_prep(
        const int* __restrict__ species,
        const float* __restrict__ n0, const float* __restrict__ n1,
        const float* __restrict__ w_lin2_s, const float* __restrict__ w_lin2_v,
        const float* __restrict__ w_res_s, const float* __restrict__ embed_w,
        const float* __restrict__ w_lin1_s, const float* __restrict__ w_lin1_v,
        float* __restrict__ h_s, float* __restrict__ feat) {
    __shared__ float stage[4][128];
    int lane = threadIdx.x & 63;
    int wv = threadIdx.x >> 6;
    int n = blockIdx.x * 4 + wv;
    n = __builtin_amdgcn_readfirstlane(n);
    int sp = __builtin_amdgcn_readfirstlane(species[n]);
    const float sc_l2 = 1.f / 128.f;
    const float rr = 0.07905694150420949f * 0.4472135954999579f;  // rs160 * rs5

    const float* n0r = n0 + (size_t)n * 64;
    float sk = 0.f;
#pragma unroll 8
    for (int j = 0; j < 64; ++j)
        sk += n0r[j] * w_lin2_s[j * 64 + lane];
    sk *= sc_l2;
#pragma unroll 8
    for (int u = 0; u < 32; ++u)
        sk += (embed_w[sp * 32 + u] * rr) * w_res_s[(u * 5 + sp) * 64 + lane];
    float act = silu_f(sk);
    float gmine = __shfl(act, 32 + (lane & 31));

    const float* n1r = n1 + (size_t)n * 192;
    int i0 = lane >> 5, v = lane & 31;
    float acc0 = 0.f, acc2 = 0.f;
#pragma unroll 8
    for (int u = 0; u < 32; ++u) {        // o1b half of n1 is zero at L0
        float wlv = w_lin2_v[u * 32 + v];
        acc0 += n1r[i0 * 64 + u] * wlv;
        acc2 += n1r[128 + u] * wlv;
    }
    float* st = stage[wv];
    st[32 + i0 * 32 + v] = acc0 * sc_l2 * gmine;
    if (lane < 32) {
        st[v] = act;
        st[96 + v] = acc2 * sc_l2 * gmine;
        h_s[(size_t)n * 32 + v] = act;
    }
    __syncthreads();

    const float rs32 = 0.17677669529663687f;
    float accA = 0.f, accB = 0.f;
#pragma unroll 8
    for (int u = 0; u < 32; ++u) {
        float wsv = w_lin1_s[u * 32 + v];
        float wvv = w_lin1_v[u * 32 + v];
        float xs = st[u];
        float xx = st[32 + u];
        float xy = st[64 + u];
        float xz = st[96 + u];
        float inA = i0 ? xy : xs;
        float wA  = i0 ? wvv : wsv;
        float inB = i0 ? xz : xx;
        accA += inA * wA;
        accB += inB * wvv;
    }
    f32x2 o;
    o[0] = accA * rs32;
    o[1] = accB * rs32;
    *(f32x2*)(feat + (size_t)n * 128 + v * 4 + i0 * 2) = o;
}

// ---------------- final node update: scalar-only + fused readout ----------------
__global__ __launch_bounds__(256) void k_node_update_last(
        const int* __restrict__ species,
        const float* __restrict__ n0,
        const float* __restrict__ w_lin2_s, const float* __restrict__ w_res_s,
        const float* __restrict__ h_s,
        const float* __restrict__ w_out1, const float* __restrict__ w_out2,
        float* __restrict__ out) {
    int lane = threadIdx.x & 63;
    int n = blockIdx.x * 4 + (threadIdx.x >> 6);
    n = __builtin_amdgcn_readfirstlane(n);
    if (lane >= 32) return;
    int sp = __builtin_amdgcn_readfirstlane(species[n]);
    const float sc_l2 = 1.f / 128.f;
    const float rs160 = 0.07905694150420949f;

    const float* n0r = n0 + (size_t)n * 64;
    float sk = 0.f;
#pragma unroll 8
    for (int j = 0; j < 64; ++j)
        sk += n0r[j] * w_lin2_s[j * 64 + lane];
    sk *= sc_l2;
    const float* hsr = h_s + (size_t)n * 32;
#pragma unroll 8
    for (int u = 0; u < 32; ++u)
        sk += (hsr[u] * rs160) * w_res_s[(u * 5 + sp) * 64 + lane];
    float act = silu_f(sk);

    float wc = 0.f;
#pragma unroll
    for (int j = 0; j < 16; ++j)
        wc += w_out1[lane * 16 + j] * w_out2[j];
    float e = act * wc;
    e += __shfl_xor(e, 1);
    e += __shfl_xor(e, 2);
    e += __shfl_xor(e, 4);
    e += __shfl_xor(e, 8);
    e += __shfl_xor(e, 16);
    if (lane == 0)
        out[n] = e * 0.17677669529663687f * 0.25f;
}

extern "C" void kernel_launch(void* const* d_in, const int* in_sizes, int n_in,
                              void* d_out, int out_size, void* d_ws, size_t ws_size,
                              hipStream_t stream) {
    const float* evec     = (const float*)d_in[0];
    const int*   species  = (const int*)d_in[1];
    const int*   senders  = (const int*)d_in[2];
    const int*   receivers= (const int*)d_in[3];
    const float* embed_w  = (const float*)d_in[4];
    const float* w_res_s  = (const float*)d_in[5];
    const float* w_res_v  = (const float*)d_in[6];
    const float* w_lin1_s = (const float*)d_in[7];
    const float* w_lin1_v = (const float*)d_in[8];
    const float* mlp_w0   = (const float*)d_in[9];
    const float* mlp_w1   = (const float*)d_in[10];
    const float* mlp_w2   = (const float*)d_in[11];
    const float* w_lin2_s = (const float*)d_in[12];
    const float* w_lin2_v = (const float*)d_in[13];
    const float* w_out1   = (const float*)d_in[14];
    const float* w_out2   = (const float*)d_in[15];
    (void)w_res_v;

    float* ws = (float*)d_ws;
    size_t off = 0;
    auto alloc = [&](size_t n) { float* p = ws + off; off += (n + 3) & ~(size_t)3; return p; };

    float* h_s  = alloc(NN * 32);
    float* feat = alloc((size_t)NN * 128);
    float* n0b  = alloc(NN * 64);          // n0b, n1b, deg contiguous: one memset
    float* n1b  = alloc(NN * 192);
    int*   deg  = (int*)alloc(NN);
    float* tab0 = alloc((size_t)(TB + 1) * 64);
    float* tab1 = alloc((size_t)(TB + 1) * 64);
    float* fs   = alloc(160);
    int*   row_start = (int*)alloc(NN + 1);
    int*   cursor    = (int*)alloc(NN);
    int*   csr_send  = (int*)alloc(EE);
    int*   csr_recv  = (int*)alloc(EE);
    float* ev4       = alloc((size_t)EE * 4);

    hipMemsetAsync(n0b, 0, (size_t)NN * 257 * 4, stream);   // n0b + n1b + deg
    k_table<<<(2 * (TB + 1) + 3 + 3) / 4, 256, 0, stream>>>(
        mlp_w0, mlp_w1, mlp_w2, embed_w, w_lin1_s, tab0, tab1, fs);
    k_hist<<<(EE + 255) / 256, 256, 0, stream>>>(receivers, deg);
    k_scan<<<1, 1024, 0, stream>>>(deg, row_start, cursor);
    k_fill<<<(EE + 255) / 256, 256, 0, stream>>>(receivers, senders, species, evec,
                                                 cursor, csr_send, csr_recv, ev4);

    // ---- layer 0 ----
    k_mega<0><<<EE / 256, 256, 0, stream>>>(
        csr_send, csr_recv, ev4, row_start, fs, feat, tab0, n0b, n1b);
    k_upd0_prep<<<12500, 256, 0, stream>>>(
        species, n0b, n1b, w_lin2_s, w_lin2_v, w_res_s, embed_w,
        w_lin1_s + 1024, w_lin1_v + 1024, h_s, feat);

    // ---- layer 1 (last) ----
    hipMemsetAsync(n0b, 0, (size_t)NN * 64 * 4, stream);
    k_mega<1><<<EE / 256, 256, 0, stream>>>(
        csr_send, csr_recv, ev4, row_start, fs, feat, tab1, n0b, n1b);
    k_node_update_last<<<12500, 256, 0, stream>>>(
        species, n0b, w_lin2_s + 4096, w_res_s + 10240, h_s,
        w_out1, w_out2, (float*)d_out);
}